// Round 11
// baseline (748.496 us; speedup 1.0000x reference)
//
#include <hip/hip_runtime.h>
#include <hip/hip_bf16.h>
#include <math.h>

constexpr int T_ = 1024;
constexpr int HDIM = 2048;
constexpr int NH = 16;
constexpr int QKD = 96;
constexpr int VD = 64;
constexpr int MAXTILES = 32;   // <=24 expert tiles + 8 shared tiles
constexpr float EPSF = 1e-6f;

using f32x4 = __attribute__((ext_vector_type(4))) float;
using s16x8 = __attribute__((ext_vector_type(8))) short;
using s16x4 = __attribute__((ext_vector_type(4))) short;

// ---------------- workspace layout (float offsets; ws is ~1 GB) ----------------
constexpr size_t OF_CATH  = 0;                 // bf16 T*4096
constexpr size_t OF_CATL  = 2097152;
constexpr size_t OF_GACT  = 0;                 // bf16 3072*2048 (alias cat planes; disjoint lifetime)
constexpr size_t OF_X0    = 4194304;           // f32 T*2048
constexpr size_t OF_MACT  = 6291456;           // bf16 3072*1024
constexpr size_t OF_HH    = 8388608;           // bf16 T*2048
constexpr size_t OF_HL    = 9437184;
constexpr size_t OF_QRAW  = 10485760;          // f32 T*512
constexpr size_t OF_QBUF  = 11010048;          // f32 T*1536
constexpr size_t OF_KVA   = 12582912;          // f32 T*288
constexpr size_t OF_KVBUF = 12877824;          // f32 T*2048
constexpr size_t OF_QAH   = 14974976;          // bf16 T*512
constexpr size_t OF_QAL   = 15237120;
constexpr size_t OF_KVCNH = 15499264;          // bf16 T*256
constexpr size_t OF_KVCNL = 15630336;
constexpr size_t OF_QFH   = 15761408;          // bf16 T*1536
constexpr size_t OF_QFL   = 16547840;
constexpr size_t OF_KFH   = 17334272;
constexpr size_t OF_KFL   = 18120704;
constexpr size_t OF_VBH   = 18907136;          // bf16 T*1024
constexpr size_t OF_VBL   = 19431424;
constexpr size_t OF_OBH   = 19955712;          // bf16 T*1024
constexpr size_t OF_OBL   = 20480000;
constexpr size_t OF_ATT   = 21004288;          // f32 T*2048
constexpr size_t OF_H2BF  = 23101440;          // bf16 T*2048
constexpr size_t OF_ROUT  = 24674304;          // ints
// weight planes (bf16)
constexpr size_t OF_EHTH  = 24682752;          // [2048][4096]
constexpr size_t OF_EHTL  = 28877056;
constexpr size_t OF_QATH  = 33071360;          // [512][2048]
constexpr size_t OF_QATL  = 33595648;
constexpr size_t OF_QBTH  = 34119936;          // [1536][512]
constexpr size_t OF_QBTL  = 34513152;
constexpr size_t OF_KVATH = 34906368;          // [320][2048] (288 used)
constexpr size_t OF_KVATL = 35234048;
constexpr size_t OF_KVBTH = 35561728;          // [2048][256]
constexpr size_t OF_KVBTL = 35823872;
constexpr size_t OF_OWTH  = 36086016;          // [2048][1024]
constexpr size_t OF_OWTL  = 37134592;
constexpr size_t OF_MD    = 38183168;          // f32 3072*2048
constexpr size_t OF_EGT   = 44474624;          // bf16 [9][1024][2048]
constexpr size_t OF_EUT   = 53911808;          // bf16 [9][1024][2048]
constexpr size_t OF_EDT   = 63348992;          // bf16 [9][2048][1024]  (ends 72786176 floats = 291 MB)

// ---------------- helpers ----------------
__device__ __forceinline__ short f2bf(float f) {
    union { float f; unsigned u; } x; x.f = f;
    unsigned r = x.u + 0x7fffu + ((x.u >> 16) & 1u);
    return (short)(r >> 16);
}
__device__ __forceinline__ float bf2f(short h) {
    union { unsigned u; float f; } x; x.u = ((unsigned)(unsigned short)h) << 16; return x.f;
}
// LDS swizzle (plane GEMM): row stride 64 shorts; chunk ^= row&7
__device__ __forceinline__ int swz(int r, int k) {
    return (r << 6) + ((((k >> 3) ^ (r & 7)) << 3) | (k & 7));
}
// async global->LDS, 16 B per lane; LDS dest = wave-uniform base + lane*16
__device__ __forceinline__ void gload16(const void* g, void* l) {
    __builtin_amdgcn_global_load_lds((__attribute__((address_space(1))) void*)g,
                                     (__attribute__((address_space(3))) void*)l, 16, 0, 0);
}

__device__ __forceinline__ float block_sum(float v) {
    __shared__ float sbuf[9];
    int lane = threadIdx.x & 63;
    int wid  = threadIdx.x >> 6;
#pragma unroll
    for (int off = 32; off > 0; off >>= 1) v += __shfl_down(v, off);
    __syncthreads();
    if (lane == 0) sbuf[wid] = v;
    __syncthreads();
    if (threadIdx.x == 0) {
        float s = 0.f;
        int nw = blockDim.x >> 6;
        for (int i = 0; i < nw; i++) s += sbuf[i];
        sbuf[8] = s;
    }
    __syncthreads();
    return sbuf[8];
}

// ---------------- weight transpose + split (batched over blockIdx.z) ----------------
__global__ void transpose_split_kernel(const float* __restrict__ W, short* __restrict__ Whi,
                                       short* __restrict__ Wlo, int K, int N, int split) {
    const float* Wz = W + (size_t)blockIdx.z * K * N;
    short* WhiZ = Whi + (size_t)blockIdx.z * N * K;
    __shared__ float tile[64][65];
    int k0 = blockIdx.x * 64, n0 = blockIdx.y * 64;
    int tn = threadIdx.x & 63;
    int tk4 = threadIdx.x >> 6;
#pragma unroll 4
    for (int i = 0; i < 16; i++) {
        int kk = tk4 * 16 + i;
        int gn = n0 + tn;
        tile[kk][tn] = (gn < N) ? Wz[(size_t)(k0 + kk) * N + gn] : 0.f;
    }
    __syncthreads();
    int on = threadIdx.x >> 2;
    int oc = threadIdx.x & 3;
#pragma unroll 4
    for (int i = 0; i < 16; i++) {
        int kk = oc * 16 + i;
        float v = tile[kk][on];
        short hh = f2bf(v);
        size_t o = (size_t)(n0 + on) * K + k0 + kk;
        WhiZ[o] = hh;
        if (split) (Wlo + (size_t)blockIdx.z * N * K)[o] = f2bf(v - bf2f(hh));
    }
}

// ---------------- embedding + rmsnorm + concat -> split planes ----------------
__global__ void embed_cat_kernel(const int* __restrict__ ids, const float* __restrict__ embed,
                                 const float* __restrict__ enorm, const float* __restrict__ prev,
                                 const float* __restrict__ hnorm, short* __restrict__ ch,
                                 short* __restrict__ cl) {
    int t = blockIdx.x;
    const float* e = embed + (size_t)ids[t] * HDIM;
    float ss = 0.f;
    for (int i = threadIdx.x; i < HDIM; i += blockDim.x) { float v = e[i]; ss += v * v; }
    float r = rsqrtf(block_sum(ss) / HDIM + EPSF);
    for (int i = threadIdx.x; i < HDIM; i += blockDim.x) {
        float v = e[i] * r * enorm[i];
        short hh = f2bf(v);
        ch[(size_t)t * 4096 + i] = hh;
        cl[(size_t)t * 4096 + i] = f2bf(v - bf2f(hh));
    }
    const float* p = prev + (size_t)t * HDIM;
    ss = 0.f;
    for (int i = threadIdx.x; i < HDIM; i += blockDim.x) { float v = p[i]; ss += v * v; }
    r = rsqrtf(block_sum(ss) / HDIM + EPSF);
    for (int i = threadIdx.x; i < HDIM; i += blockDim.x) {
        float v = p[i] * r * hnorm[i];
        short hh = f2bf(v);
        ch[(size_t)t * 4096 + 2048 + i] = hh;
        cl[(size_t)t * 4096 + 2048 + i] = f2bf(v - bf2f(hh));
    }
}

// ---------------- rmsnorm (f32 / hi / lo outputs) ----------------
__global__ void rmsnorm_kernel(const float* __restrict__ in, int in_stride, int width,
                               const float* __restrict__ w, float* __restrict__ outf,
                               short* __restrict__ outh, short* __restrict__ outl, int out_stride) {
    int t = blockIdx.x;
    const float* x = in + (size_t)t * in_stride;
    float ss = 0.f;
    for (int i = threadIdx.x; i < width; i += blockDim.x) { float v = x[i]; ss += v * v; }
    float r = rsqrtf(block_sum(ss) / width + EPSF);
    size_t ob = (size_t)t * out_stride;
    for (int i = threadIdx.x; i < width; i += blockDim.x) {
        float v = x[i] * r * w[i];
        if (outf) outf[ob + i] = v;
        if (outh) {
            short hh = f2bf(v);
            outh[ob + i] = hh;
            if (outl) outl[ob + i] = f2bf(v - bf2f(hh));
        }
    }
}

// =====================================================================
// Plane GEMM (round-10 verified): BM=128 BN=64 BK=64, gload16 staging
// with inverse-swizzled global source, swizzled LDS reads.
// =====================================================================
template<bool SPLIT>
__global__ __launch_bounds__(256) void gemm_planes(const short* __restrict__ Ahi, const short* __restrict__ Alo,
                                                   const short* __restrict__ Bhi, const short* __restrict__ Blo,
                                                   float* __restrict__ C, int M, int N, int K) {
    __shared__ short As[SPLIT ? 2 : 1][128 * 64];
    __shared__ short Bs[SPLIT ? 2 : 1][64 * 64];
    const int tid = threadIdx.x;
    const int lane = tid & 63, wid = tid >> 6;
    const int g = lane >> 4, li = lane & 15;
    const int wm = wid >> 1, wn = wid & 1;
    const int row0 = blockIdx.y * 128, col0 = blockIdx.x * 64;

    f32x4 acc[4][2];
#pragma unroll
    for (int mi = 0; mi < 4; mi++)
#pragma unroll
        for (int ni = 0; ni < 2; ni++)
#pragma unroll
            for (int r = 0; r < 4; r++) acc[mi][ni][r] = 0.f;

    for (int k0 = 0; k0 < K; k0 += 64) {
#pragma unroll
        for (int j = 0; j < 4; j++) {
            int blkI = wid * 4 + j;
            int cid = blkI * 64 + lane;
            int r = cid >> 3, c = (cid & 7) ^ (r & 7);
            gload16(&Ahi[(size_t)(row0 + r) * K + k0 + c * 8], &As[0][blkI * 512]);
            if constexpr (SPLIT)
                gload16(&Alo[(size_t)(row0 + r) * K + k0 + c * 8], &As[1][blkI * 512]);
        }
#pragma unroll
        for (int j = 0; j < 2; j++) {
            int blkI = wid * 2 + j;
            int cid = blkI * 64 + lane;
            int r = cid >> 3, c = (cid & 7) ^ (r & 7);
            gload16(&Bhi[(size_t)(col0 + r) * K + k0 + c * 8], &Bs[0][blkI * 512]);
            if constexpr (SPLIT)
                gload16(&Blo[(size_t)(col0 + r) * K + k0 + c * 8], &Bs[1][blkI * 512]);
        }
        __syncthreads();
#pragma unroll
        for (int kk = 0; kk < 64; kk += 32) {
            s16x8 ah[4], bh[2];
#pragma unroll
            for (int mi = 0; mi < 4; mi++) ah[mi] = *(const s16x8*)&As[0][swz(wm * 64 + mi * 16 + li, kk + g * 8)];
#pragma unroll
            for (int ni = 0; ni < 2; ni++) bh[ni] = *(const s16x8*)&Bs[0][swz(wn * 32 + ni * 16 + li, kk + g * 8)];
            if constexpr (SPLIT) {
                s16x8 al[4], bl[2];
#pragma unroll
                for (int mi = 0; mi < 4; mi++) al[mi] = *(const s16x8*)&As[1][swz(wm * 64 + mi * 16 + li, kk + g * 8)];
#pragma unroll
                for (int ni = 0; ni < 2; ni++) bl[ni] = *(const s16x8*)&Bs[1][swz(wn * 32 + ni * 16 + li, kk + g * 8)];
#pragma unroll
                for (int mi = 0; mi < 4; mi++)
#pragma unroll
                    for (int ni = 0; ni < 2; ni++) {
                        acc[mi][ni] = __builtin_amdgcn_mfma_f32_16x16x32_bf16(ah[mi], bh[ni], acc[mi][ni], 0, 0, 0);
                        acc[mi][ni] = __builtin_amdgcn_mfma_f32_16x16x32_bf16(al[mi], bh[ni], acc[mi][ni], 0, 0, 0);
                        acc[mi][ni] = __builtin_amdgcn_mfma_f32_16x16x32_bf16(ah[mi], bl[ni], acc[mi][ni], 0, 0, 0);
                    }
            } else {
#pragma unroll
                for (int mi = 0; mi < 4; mi++)
#pragma unroll
                    for (int ni = 0; ni < 2; ni++)
                        acc[mi][ni] = __builtin_amdgcn_mfma_f32_16x16x32_bf16(ah[mi], bh[ni], acc[mi][ni], 0, 0, 0);
            }
        }
        __syncthreads();
    }
#pragma unroll
    for (int mi = 0; mi < 4; mi++)
#pragma unroll
        for (int ni = 0; ni < 2; ni++) {
            int gc = col0 + wn * 32 + ni * 16 + li;
            if (gc < N) {
#pragma unroll
                for (int r = 0; r < 4; r++) {
                    int gr = row0 + wm * 64 + mi * 16 + g * 4 + r;
                    C[(size_t)gr * N + gc] = acc[mi][ni][r];
                }
            }
        }
}

// =====================================================================
// MoE gate+up GEMM + silu epilogue; B^T bf16 planes [9][N][K], tm.x=0..8.
// Plane staging (gload16 + swizzle), clone of gemm_planes machinery.
// A rows >= nrows read in-bounds garbage (allocation has 3072 rows);
// their MFMA output rows are masked at the C-write (rows independent).
// =====================================================================
__global__ __launch_bounds__(256) void moe_gateup(const short* __restrict__ Abase, const short* __restrict__ BgT,
                                                  const short* __restrict__ BuT, short* __restrict__ Cact,
                                                  const int4* __restrict__ tilemap, int K, int N) {
    int4 tm = tilemap[blockIdx.y];
    int nrows = tm.z;
    if (nrows == 0) return;
    const short* A  = Abase + (size_t)tm.y * K;
    const short* Bg = BgT + (size_t)tm.x * (size_t)N * K;
    const short* Bu = BuT + (size_t)tm.x * (size_t)N * K;

    __shared__ short As[128 * 64];
    __shared__ short Bgs[64 * 64];
    __shared__ short Bus[64 * 64];
    const int tid = threadIdx.x;
    const int lane = tid & 63, wid = tid >> 6;
    const int g = lane >> 4, li = lane & 15;
    const int wm = wid >> 1, wn = wid & 1;
    const int col0 = blockIdx.x * 64;

    f32x4 accg[4][2], accu[4][2];
#pragma unroll
    for (int mi = 0; mi < 4; mi++)
#pragma unroll
        for (int ni = 0; ni < 2; ni++)
#pragma unroll
            for (int r = 0; r < 4; r++) { accg[mi][ni][r] = 0.f; accu[mi][ni][r] = 0.f; }

    for (int k0 = 0; k0 < K; k0 += 64) {
#pragma unroll
        for (int j = 0; j < 4; j++) {
            int blkI = wid * 4 + j;
            int cid = blkI * 64 + lane;
            int r = cid >> 3, c = (cid & 7) ^ (r & 7);
            gload16(&A[(size_t)r * K + k0 + c * 8], &As[blkI * 512]);
        }
#pragma unroll
        for (int j = 0; j < 2; j++) {
            int blkI = wid * 2 + j;
            int cid = blkI * 64 + lane;
            int r = cid >> 3, c = (cid & 7) ^ (r & 7);
            gload16(&Bg[(size_t)(col0 + r) * K + k0 + c * 8], &Bgs[blkI * 512]);
            gload16(&Bu[(size_t)(col0 + r) * K + k0 + c * 8], &Bus[blkI * 512]);
        }
        __syncthreads();
#pragma unroll
        for (int kk = 0; kk < 64; kk += 32) {
            s16x8 a[4], bg2[2], bu2[2];
#pragma unroll
            for (int mi = 0; mi < 4; mi++) a[mi] = *(const s16x8*)&As[swz(wm * 64 + mi * 16 + li, kk + g * 8)];
#pragma unroll
            for (int ni = 0; ni < 2; ni++) {
                bg2[ni] = *(const s16x8*)&Bgs[swz(wn * 32 + ni * 16 + li, kk + g * 8)];
                bu2[ni] = *(const s16x8*)&Bus[swz(wn * 32 + ni * 16 + li, kk + g * 8)];
            }
#pragma unroll
            for (int mi = 0; mi < 4; mi++)
#pragma unroll
                for (int ni = 0; ni < 2; ni++) {
                    accg[mi][ni] = __builtin_amdgcn_mfma_f32_16x16x32_bf16(a[mi], bg2[ni], accg[mi][ni], 0, 0, 0);
                    accu[mi][ni] = __builtin_amdgcn_mfma_f32_16x16x32_bf16(a[mi], bu2[ni], accu[mi][ni], 0, 0, 0);
                }
        }
        __syncthreads();
    }
#pragma unroll
    for (int mi = 0; mi < 4; mi++)
#pragma unroll
        for (int ni = 0; ni < 2; ni++) {
            int gc = col0 + wn * 32 + ni * 16 + li;
#pragma unroll
            for (int r = 0; r < 4; r++) {
                int gr = wm * 64 + mi * 16 + g * 4 + r;
                if (gr < nrows) {
                    float x = accg[mi][ni][r], u = accu[mi][ni][r];
                    Cact[(size_t)(tm.y + gr) * N + gc] = f2bf((x / (1.f + expf(-x))) * u);
                }
            }
        }
}

// =====================================================================
// MoE down GEMM; B^T bf16 planes [9][N][K], tm.x=0..8; out md f32.
// =====================================================================
__global__ __launch_bounds__(256) void moe_down(const short* __restrict__ Abase, const short* __restrict__ BdT,
                                                float* __restrict__ Cbase, const int4* __restrict__ tilemap,
                                                int K, int N) {
    int4 tm = tilemap[blockIdx.y];
    int nrows = tm.z;
    if (nrows == 0) return;
    const short* A = Abase + (size_t)tm.y * K;
    float* C = Cbase + (size_t)tm.y * N;
    const short* B = BdT + (size_t)tm.x * (size_t)N * K;

    __shared__ short As[128 * 64];
    __shared__ short Bs[64 * 64];
    const int tid = threadIdx.x;
    const int lane = tid & 63, wid = tid >> 6;
    const int g = lane >> 4, li = lane & 15;
    const int wm = wid >> 1, wn = wid & 1;
    const int col0 = blockIdx.x * 64;

    f32x4 acc[4][2];
#pragma unroll
    for (int mi = 0; mi < 4; mi++)
#pragma unroll
        for (int ni = 0; ni < 2; ni++)
#pragma unroll
            for (int r = 0; r < 4; r++) acc[mi][ni][r] = 0.f;

    for (int k0 = 0; k0 < K; k0 += 64) {
#pragma unroll
        for (int j = 0; j < 4; j++) {
            int blkI = wid * 4 + j;
            int cid = blkI * 64 + lane;
            int r = cid >> 3, c = (cid & 7) ^ (r & 7);
            gload16(&A[(size_t)r * K + k0 + c * 8], &As[blkI * 512]);
        }
#pragma unroll
        for (int j = 0; j < 2; j++) {
            int blkI = wid * 2 + j;
            int cid = blkI * 64 + lane;
            int r = cid >> 3, c = (cid & 7) ^ (r & 7);
            gload16(&B[(size_t)(col0 + r) * K + k0 + c * 8], &Bs[blkI * 512]);
        }
        __syncthreads();
#pragma unroll
        for (int kk = 0; kk < 64; kk += 32) {
            s16x8 a[4], b[2];
#pragma unroll
            for (int mi = 0; mi < 4; mi++) a[mi] = *(const s16x8*)&As[swz(wm * 64 + mi * 16 + li, kk + g * 8)];
#pragma unroll
            for (int ni = 0; ni < 2; ni++) b[ni] = *(const s16x8*)&Bs[swz(wn * 32 + ni * 16 + li, kk + g * 8)];
#pragma unroll
            for (int mi = 0; mi < 4; mi++)
#pragma unroll
                for (int ni = 0; ni < 2; ni++)
                    acc[mi][ni] = __builtin_amdgcn_mfma_f32_16x16x32_bf16(a[mi], b[ni], acc[mi][ni], 0, 0, 0);
        }
        __syncthreads();
    }
#pragma unroll
    for (int mi = 0; mi < 4; mi++)
#pragma unroll
        for (int ni = 0; ni < 2; ni++) {
            int gc = col0 + wn * 32 + ni * 16 + li;
#pragma unroll
            for (int r = 0; r < 4; r++) {
                int gr = wm * 64 + mi * 16 + g * 4 + r;
                if (gr < nrows) C[(size_t)gr * N + gc] = acc[mi][ni][r];
            }
        }
}

// ---------------- RoPE + build qf/kf/v as split planes ----------------
__global__ void prep_qkv_kernel(const float* __restrict__ q, const float* __restrict__ kva,
                                const float* __restrict__ kv, const int* __restrict__ positions,
                                short* __restrict__ qfh, short* __restrict__ qfl,
                                short* __restrict__ kfh, short* __restrict__ kfl,
                                short* __restrict__ vbh, short* __restrict__ vbl) {
    int t = blockIdx.x;
    __shared__ float cs[16], sn[16];
    if (threadIdx.x < 16) {
        float invf = powf(10000.f, -(float)(2 * threadIdx.x) / 32.f);
        float fr = (float)positions[t] * invf;
        cs[threadIdx.x] = cosf(fr);
        sn[threadIdx.x] = sinf(fr);
    }
    __syncthreads();
    for (int i = threadIdx.x; i < NH * QKD; i += blockDim.x) {
        int h = i / QKD, d = i % QKD;
        float val;
        if (d < 64) val = q[(size_t)t * 1536 + h * QKD + d];
        else {
            int r = d - 64, pr = r >> 1;
            float x1 = q[(size_t)t * 1536 + h * QKD + 64 + 2 * pr];
            float x2 = q[(size_t)t * 1536 + h * QKD + 64 + 2 * pr + 1];
            val = (r & 1) ? (x1 * sn[pr] + x2 * cs[pr]) : (x1 * cs[pr] - x2 * sn[pr]);
        }
        short hh = f2bf(val);
        qfh[(size_t)t * 1536 + i] = hh;
        qfl[(size_t)t * 1536 + i] = f2bf(val - bf2f(hh));
    }
    for (int i = threadIdx.x; i < NH * QKD; i += blockDim.x) {
        int h = i / QKD, d = i % QKD;
        float val;
        if (d < 64) val = kv[(size_t)t * 2048 + h * 128 + d];
        else {
            int r = d - 64, pr = r >> 1;
            float x1 = kva[(size_t)t * 288 + 256 + 2 * pr];
            float x2 = kva[(size_t)t * 288 + 256 + 2 * pr + 1];
            val = (r & 1) ? (x1 * sn[pr] + x2 * cs[pr]) : (x1 * cs[pr] - x2 * sn[pr]);
        }
        short hh = f2bf(val);
        kfh[(size_t)t * 1536 + i] = hh;
        kfl[(size_t)t * 1536 + i] = f2bf(val - bf2f(hh));
    }
    for (int i = threadIdx.x; i < NH * VD; i += blockDim.x) {
        int h = i / VD, d = i % VD;
        float val = kv[(size_t)t * 2048 + h * 128 + 64 + d];
        short hh = f2bf(val);
        vbh[(size_t)t * 1024 + i] = hh;
        vbl[(size_t)t * 1024 + i] = f2bf(val - bf2f(hh));
    }
}

// =====================================================================
// MFMA flash attention (verified; reads/writes bf16 planes)
// =====================================================================
__global__ __launch_bounds__(256) void attn_mfma_kernel(const short* __restrict__ qfh, const short* __restrict__ qfl,
                                                        const short* __restrict__ kfh, const short* __restrict__ kfl,
                                                        const short* __restrict__ vbh, const short* __restrict__ vbl,
                                                        short* __restrict__ obh, short* __restrict__ obl) {
    __shared__ short K_hi[64][104], K_lo[64][104];
    __shared__ short Vt_hi[64][72], Vt_lo[64][72];
    __shared__ short P_hi[4][16][72], P_lo[4][16][72];
    const int qt = blockIdx.x, h = blockIdx.y;
    const int tid = threadIdx.x, lane = tid & 63, w = tid >> 6;
    const int g = lane >> 4, li = lane & 15;

    s16x8 q_hi[3], q_lo[3];
    {
        const short* qb_h = qfh + (size_t)(qt * 64 + w * 16 + li) * 1536 + h * QKD;
        const short* qb_l = qfl + (size_t)(qt * 64 + w * 16 + li) * 1536 + h * QKD;
#pragma unroll
        for (int ks = 0; ks < 3; ks++) {
            q_hi[ks] = *(const s16x8*)(qb_h + ks * 32 + g * 8);
            q_lo[ks] = *(const s16x8*)(qb_l + ks * 32 + g * 8);
        }
    }

    f32x4 acc_o[4];
#pragma unroll
    for (int nc = 0; nc < 4; nc++)
#pragma unroll
        for (int r = 0; r < 4; r++) acc_o[nc][r] = 0.f;
    float m4[4] = {-1e30f, -1e30f, -1e30f, -1e30f};
    float l4[4] = {0.f, 0.f, 0.f, 0.f};
    const float scale = 0.102062072616f;

    for (int kt = 0; kt <= qt; kt++) {
#pragma unroll
        for (int it = 0; it < 3; it++) {
            int cid = it * 256 + tid;
            int key = cid / 12, c = cid % 12;
            *(s16x8*)&K_hi[key][c * 8] = *(const s16x8*)&kfh[(size_t)(kt * 64 + key) * 1536 + h * QKD + c * 8];
            *(s16x8*)&K_lo[key][c * 8] = *(const s16x8*)&kfl[(size_t)(kt * 64 + key) * 1536 + h * QKD + c * 8];
        }
#pragma unroll
        for (int it = 0; it < 2; it++) {
            int cid = it * 256 + tid;
            int key = cid >> 3, vc = cid & 7;
            s16x8 vh = *(const s16x8*)&vbh[(size_t)(kt * 64 + key) * 1024 + h * VD + vc * 8];
            s16x8 vl = *(const s16x8*)&vbl[(size_t)(kt * 64 + key) * 1024 + h * VD + vc * 8];
#pragma unroll
            for (int j = 0; j < 8; j++) {
                Vt_hi[vc * 8 + j][key] = vh[j];
                Vt_lo[vc * 8 + j][key] = vl[j];
            }
        }
        __syncthreads();

        f32x4 acc_s[4];
#pragma unroll
        for (int kc = 0; kc < 4; kc++)
#pragma unroll
            for (int r = 0; r < 4; r++) acc_s[kc][r] = 0.f;
#pragma unroll
        for (int ks = 0; ks < 3; ks++) {
#pragma unroll
            for (int kc = 0; kc < 4; kc++) {
                s16x8 kh = *(const s16x8*)&K_hi[kc * 16 + li][ks * 32 + g * 8];
                s16x8 kl = *(const s16x8*)&K_lo[kc * 16 + li][ks * 32 + g * 8];
                acc_s[kc] = __builtin_amdgcn_mfma_f32_16x16x32_bf16(q_hi[ks], kh, acc_s[kc], 0, 0, 0);
                acc_s[kc] = __builtin_amdgcn_mfma_f32_16x16x32_bf16(q_lo[ks], kh, acc_s[kc], 0, 0, 0);
                acc_s[kc] = __builtin_amdgcn_mfma_f32_16x16x32_bf16(q_hi[ks], kl, acc_s[kc], 0, 0, 0);
            }
        }
#pragma unroll
        for (int kc = 0; kc < 4; kc++)
#pragma unroll
            for (int r = 0; r < 4; r++) acc_s[kc][r] *= scale;
        if (kt == qt) {
#pragma unroll
            for (int kc = 0; kc < 4; kc++) {
                int key = kt * 64 + kc * 16 + li;
#pragma unroll
                for (int r = 0; r < 4; r++) {
                    int qr = qt * 64 + w * 16 + g * 4 + r;
                    if (key > qr) acc_s[kc][r] = -1e30f;
                }
            }
        }
        float tm4[4];
#pragma unroll
        for (int r = 0; r < 4; r++)
            tm4[r] = fmaxf(fmaxf(acc_s[0][r], acc_s[1][r]), fmaxf(acc_s[2][r], acc_s[3][r]));
#pragma unroll
        for (int off = 1; off < 16; off <<= 1)
#pragma unroll
            for (int r = 0; r < 4; r++) tm4[r] = fmaxf(tm4[r], __shfl_xor(tm4[r], off));
        float alpha[4];
#pragma unroll
        for (int r = 0; r < 4; r++) {
            float mn = fmaxf(m4[r], tm4[r]);
            alpha[r] = __expf(m4[r] - mn);
            m4[r] = mn;
        }
        float rs[4] = {0.f, 0.f, 0.f, 0.f};
#pragma unroll
        for (int kc = 0; kc < 4; kc++)
#pragma unroll
            for (int r = 0; r < 4; r++) {
                float p = __expf(acc_s[kc][r] - m4[r]);
                rs[r] += p;
                short hh = f2bf(p);
                P_hi[w][g * 4 + r][kc * 16 + li] = hh;
                P_lo[w][g * 4 + r][kc * 16 + li] = f2bf(p - bf2f(hh));
            }
#pragma unroll
        for (int off = 1; off < 16; off <<= 1)
#pragma unroll
            for (int r = 0; r < 4; r++) rs[r] += __shfl_xor(rs[r], off);
#pragma unroll
        for (int r = 0; r < 4; r++) l4[r] = l4[r] * alpha[r] + rs[r];
#pragma unroll
        for (int nc = 0; nc < 4; nc++)
#pragma unroll
            for (int r = 0; r < 4; r++) acc_o[nc][r] *= alpha[r];
#pragma unroll
        for (int ks = 0; ks < 2; ks++) {
            s16x8 ph = *(const s16x8*)&P_hi[w][li][ks * 32 + g * 8];
            s16x8 pl = *(const s16x8*)&P_lo[w][li][ks * 32 + g * 8];
#pragma unroll
            for (int nc = 0; nc < 4; nc++) {
                s16x8 vh = *(const s16x8*)&Vt_hi[nc * 16 + li][ks * 32 + g * 8];
                s16x8 vl = *(const s16x8*)&Vt_lo[nc * 16 + li][ks * 32 + g * 8];
                acc_o[nc] = __builtin_amdgcn_mfma_f32_16x16x32_bf16(ph, vh, acc_o[nc], 0, 0, 0);
                acc_o[nc] = __builtin_amdgcn_mfma_f32_16x16x32_bf16(pl, vh, acc_o[nc], 0, 0, 0);
                acc_o[nc] = __builtin_amdgcn_mfma_f32_16x16x32_bf16(ph, vl, acc_o[nc], 0, 0, 0);
            }
        }
        __syncthreads();
    }
    float inv[4];
#pragma unroll
    for (int r = 0; r < 4; r++) inv[r] = 1.f / l4[r];
#pragma unroll
    for (int nc = 0; nc < 4; nc++)
#pragma unroll
        for (int r = 0; r < 4; r++) {
            float o = acc_o[nc][r] * inv[r];
            size_t idx = (size_t)(qt * 64 + w * 16 + g * 4 + r) * 1024 + h * VD + nc * 16 + li;
            short hh = f2bf(o);
            obh[idx] = hh;
            obl[idx] = f2bf(o - bf2f(hh));
        }
}

// ---------------- fused resid-add + post-rmsnorm + routing ----------------
__global__ __launch_bounds__(256) void fused_post_attn(float* __restrict__ x0, const float* __restrict__ att,
                                                       const float* __restrict__ w, const float* __restrict__ gate_w,
                                                       const float* __restrict__ gate_bias,
                                                       short* __restrict__ h2bf, int* __restrict__ topidx,
                                                       float* __restrict__ topw) {
    int t = blockIdx.x;
    float resid[8];
    float ss = 0.f;
#pragma unroll
    for (int j = 0; j < 8; j++) {
        int i = threadIdx.x + j * 256;
        float v = x0[(size_t)t * HDIM + i] + att[(size_t)t * HDIM + i];
        resid[j] = v;
        x0[(size_t)t * HDIM + i] = v;
        ss += v * v;
    }
    float r = rsqrtf(block_sum(ss) / HDIM + EPSF);
    float acc[8] = {0.f, 0.f, 0.f, 0.f, 0.f, 0.f, 0.f, 0.f};
#pragma unroll
    for (int j = 0; j < 8; j++) {
        int i = threadIdx.x + j * 256;
        float v = resid[j] * r * w[i];
        h2bf[(size_t)t * HDIM + i] = f2bf(v);
        const float* gw = gate_w + (size_t)i * 8;
        float4 g0 = *(const float4*)gw;
        float4 g1 = *(const float4*)(gw + 4);
        acc[0] = fmaf(v, g0.x, acc[0]); acc[1] = fmaf(v, g0.y, acc[1]);
        acc[2] = fmaf(v, g0.z, acc[2]); acc[3] = fmaf(v, g0.w, acc[3]);
        acc[4] = fmaf(v, g1.x, acc[4]); acc[5] = fmaf(v, g1.y, acc[5]);
        acc[6] = fmaf(v, g1.z, acc[6]); acc[7] = fmaf(v, g1.w, acc[7]);
    }
    __shared__ float logits[8];
    for (int e = 0; e < 8; e++) {
        float s = block_sum(acc[e]);
        if (threadIdx.x == 0) logits[e] = s;
    }
    __syncthreads();
    if (threadIdx.x == 0) {
        float sig[8], sc[8];
        for (int e = 0; e < 8; e++) {
            sig[e] = 1.f / (1.f + expf(-logits[e]));
            sc[e] = sig[e] + gate_bias[e];
        }
        int i0 = 0;
        for (int e = 1; e < 8; e++) if (sc[e] > sc[i0]) i0 = e;
        int i1 = -1;
        for (int e = 0; e < 8; e++) if (e != i0 && (i1 < 0 || sc[e] > sc[i1])) i1 = e;
        float w0 = sig[i0], w1 = sig[i1], s = w0 + w1 + 1e-20f;
        topidx[t * 2 + 0] = i0; topidx[t * 2 + 1] = i1;
        topw[t * 2 + 0] = w0 / s; topw[t * 2 + 1] = w1 / s;
    }
}

// ---------------- counting sort + tile map (+8 shared tiles) ----------------
__global__ void sort_kernel(const int* __restrict__ topidx, int* __restrict__ sorted_t,
                            int* __restrict__ slotpos, int4* __restrict__ tilemap) {
    __shared__ int counts[8], offs[9];
    int wid = threadIdx.x >> 6, lane = threadIdx.x & 63;
    int cnt = 0;
    for (int base = 0; base < 2 * T_; base += 64) {
        int e = topidx[base + lane];
        unsigned long long m = __ballot(e == wid);
        cnt += __popcll(m);
    }
    if (lane == 0) counts[wid] = cnt;
    __syncthreads();
    if (threadIdx.x == 0) {
        offs[0] = 0;
        for (int e = 0; e < 8; e++) offs[e + 1] = offs[e] + counts[e];
    }
    __syncthreads();
    int pos = offs[wid];
    for (int base = 0; base < 2 * T_; base += 64) {
        int sl = base + lane;
        int e = topidx[sl];
        bool match = (e == wid);
        unsigned long long m = __ballot(match);
        if (match) {
            int before = __popcll(m & ((1ull << lane) - 1ull));
            int pp = pos + before;
            sorted_t[pp] = sl >> 1;
            slotpos[sl] = pp;
        }
        pos += __popcll(m);
    }
    __syncthreads();
    if (threadIdx.x == 0) {
        int nt = 0;
        for (int e = 0; e < 8; e++) {
            int c = counts[e], o = offs[e];
            for (int r = 0; r < c; r += 128) {
                tilemap[nt] = make_int4(e, o + r, min(128, c - r), 0);
                nt++;
            }
        }
        for (int r = 0; r < 8; r++) {             // shared MLP as expert 8
            tilemap[nt] = make_int4(8, 2048 + r * 128, 128, 0);
            nt++;
        }
        for (int i = nt; i < MAXTILES; i++) tilemap[i] = make_int4(0, 0, 0, 0);
    }
}

// ---------------- gather h2bf rows (slots 2048+ are identity tokens) ----------------
__global__ void gather_bf16_kernel(const short* __restrict__ h2bf, const int* __restrict__ sorted_t,
                                   short* __restrict__ gout) {
    int pp = blockIdx.x;
    int t = (pp < 2048) ? sorted_t[pp] : (pp - 2048);
    const s16x8* src = (const s16x8*)(h2bf + (size_t)t * HDIM);
    s16x8* dst = (s16x8*)(gout + (size_t)pp * HDIM);
    dst[threadIdx.x] = src[threadIdx.x];
}

// ---------------- final combine -> f32 out ----------------
__global__ void final_kernel(const float* __restrict__ resid, const float* __restrict__ md,
                             const int* __restrict__ slotpos, const float* __restrict__ topw,
                             float* __restrict__ out) {
    int t = blockIdx.x;
    int p0 = slotpos[t * 2 + 0], p1 = slotpos[t * 2 + 1];
    float w0 = topw[t * 2 + 0] * 2.5f, w1 = topw[t * 2 + 1] * 2.5f;
    const float* mds = md + (size_t)(2048 + t) * HDIM;
    for (int c = threadIdx.x; c < HDIM; c += blockDim.x) {
        float v = resid[(size_t)t * HDIM + c] + mds[c]
                + w0 * md[(size_t)p0 * HDIM + c] + w1 * md[(size_t)p1 * HDIM + c];
        out[(size_t)t * HDIM + c] = v;
    }
}

// ---------------- launcher ----------------
extern "C" void kernel_launch(void* const* d_in, const int* in_sizes, int n_in,
                              void* d_out, int out_size, void* d_ws, size_t ws_size,
                              hipStream_t stream) {
    (void)in_sizes; (void)n_in; (void)out_size; (void)ws_size;
    const int*   input_ids = (const int*)d_in[0];
    const int*   positions = (const int*)d_in[1];
    const float* prev      = (const float*)d_in[2];
    const float* embed     = (const float*)d_in[3];
    const float* enorm_w   = (const float*)d_in[4];
    const float* hnorm_w   = (const float*)d_in[5];
    const float* eh_proj_w = (const float*)d_in[6];
    const float* in_ln_w   = (const float*)d_in[7];
    const float* post_ln_w = (const float*)d_in[8];
    const float* q_a_w     = (const float*)d_in[9];
    const float* q_a_ln_w  = (const float*)d_in[10];
    const float* q_b_w     = (const float*)d_in[11];
    const float* kv_a_w    = (const float*)d_in[12];
    const float* kv_a_ln_w = (const float*)d_in[13];
    const float* kv_b_w    = (const float*)d_in[14];
    const float* o_w       = (const float*)d_in[15];
    const float* gate_w    = (const float*)d_in[16];
    const float* gate_bias = (const float*)d_in[17];
    const float* exp_g     = (const float*)d_in[18];
    const float* exp_u     = (const float*)d_in[19];
    const float* exp_d     = (const float*)d_in[20];
    const float* sh_g      = (const float*)d_in[21];
    const float* sh_u      = (const float*)d_in[22];
    const float* sh_d      = (const float*)d_in[23];
    float* out = (float*)d_out;

    float* ws = (float*)d_ws;
    short* catH  = (short*)(ws + OF_CATH);
    short* catL  = (short*)(ws + OF_CATL);
    short* gact  = (short*)(ws + OF_GACT);
    float* x0    = ws + OF_X0;
    short* mact  = (short*)(ws + OF_MACT);
    short* hH    = (short*)(ws + OF_HH);
    short* hL    = (short*)(ws + OF_HL);
    float* qraw  = ws + OF_QRAW;
    float* qbuf  = ws + OF_QBUF;
    float* kva   = ws + OF_KVA;
    float* kvbuf = ws + OF_KVBUF;
    short* qaH   = (short*)(ws + OF_QAH);
    short* qaL   = (short*)(ws + OF_QAL);
    short* kvcnH = (short*)(ws + OF_KVCNH);
    short* kvcnL = (short*)(ws + OF_KVCNL);
    short* qfH   = (short*)(ws + OF_QFH);
    short* qfL   = (short*)(ws + OF_QFL);
    short* kfH   = (short*)(ws + OF_KFH);
    short* kfL   = (short*)(ws + OF_KFL);
    short* vbH   = (short*)(ws + OF_VBH);
    short* vbL   = (short*)(ws + OF_VBL);
    short* obH   = (short*)(ws + OF_OBH);
    short* obL   = (short*)(ws + OF_OBL);
    float* att   = ws + OF_ATT;
    short* h2bf  = (short*)(ws + OF_H2BF);
    float* md    = ws + OF_MD;
    short* egT   = (short*)(ws + OF_EGT);
    short* euT   = (short*)(ws + OF_EUT);
    short* edT   = (short*)(ws + OF_EDT);
    int*   ri       = (int*)(ws + OF_ROUT);
    int*   topidx   = ri;
    int*   sorted_t = ri + 2048;
    int*   slotpos  = ri + 4096;
    int4*  tilemap  = (int4*)(ri + 6144);
    float* topw     = (float*)(ri + 6144 + 4 * MAXTILES);
    short* ehTH  = (short*)(ws + OF_EHTH);
    short* ehTL  = (short*)(ws + OF_EHTL);
    short* qaTH  = (short*)(ws + OF_QATH);
    short* qaTL  = (short*)(ws + OF_QATL);
    short* qbTH  = (short*)(ws + OF_QBTH);
    short* qbTL  = (short*)(ws + OF_QBTL);
    short* kvaTH = (short*)(ws + OF_KVATH);
    short* kvaTL = (short*)(ws + OF_KVATL);
    short* kvbTH = (short*)(ws + OF_KVBTH);
    short* kvbTL = (short*)(ws + OF_KVBTL);
    short* owTH  = (short*)(ws + OF_OWTH);
    short* owTL  = (short*)(ws + OF_OWTL);

    dim3 blk(256);

    // 0. weight transpose+split
    transpose_split_kernel<<<dim3(64, 32), blk, 0, stream>>>(eh_proj_w, ehTH, ehTL, 4096, 2048, 1);
    transpose_split_kernel<<<dim3(32, 8), blk, 0, stream>>>(q_a_w, qaTH, qaTL, 2048, 512, 1);
    transpose_split_kernel<<<dim3(8, 24), blk, 0, stream>>>(q_b_w, qbTH, qbTL, 512, 1536, 1);
    transpose_split_kernel<<<dim3(32, 5), blk, 0, stream>>>(kv_a_w, kvaTH, kvaTL, 2048, 288, 1);
    transpose_split_kernel<<<dim3(4, 32), blk, 0, stream>>>(kv_b_w, kvbTH, kvbTL, 256, 2048, 1);
    transpose_split_kernel<<<dim3(16, 32), blk, 0, stream>>>(o_w, owTH, owTL, 1024, 2048, 1);
    // 0b. MoE + shared weights -> bf16 B^T planes [9][N][K]
    transpose_split_kernel<<<dim3(32, 16, 8), blk, 0, stream>>>(exp_g, egT, nullptr, 2048, 1024, 0);
    transpose_split_kernel<<<dim3(32, 16), blk, 0, stream>>>(sh_g, egT + (size_t)8 * 1024 * 2048, nullptr, 2048, 1024, 0);
    transpose_split_kernel<<<dim3(32, 16, 8), blk, 0, stream>>>(exp_u, euT, nullptr, 2048, 1024, 0);
    transpose_split_kernel<<<dim3(32, 16), blk, 0, stream>>>(sh_u, euT + (size_t)8 * 1024 * 2048, nullptr, 2048, 1024, 0);
    transpose_split_kernel<<<dim3(16, 32, 8), blk, 0, stream>>>(exp_d, edT, nullptr, 1024, 2048, 0);
    transpose_split_kernel<<<dim3(16, 32), blk, 0, stream>>>(sh_d, edT + (size_t)8 * 2048 * 1024, nullptr, 1024, 2048, 0);

    // 1. embed + rmsnorm + concat
    embed_cat_kernel<<<T_, blk, 0, stream>>>(input_ids, embed, enorm_w, prev, hnorm_w, catH, catL);
    // 2. x0 = cat @ eh_proj
    gemm_planes<true><<<dim3(32, 8), blk, 0, stream>>>(catH, catL, ehTH, ehTL, x0, T_, 2048, 4096);
    // 3. h = rmsnorm(x0)
    rmsnorm_kernel<<<T_, blk, 0, stream>>>(x0, 2048, 2048, in_ln_w, nullptr, hH, hL, 2048);
    // 4. q_a
    gemm_planes<true><<<dim3(8, 8), blk, 0, stream>>>(hH, hL, qaTH, qaTL, qraw, T_, 512, 2048);
    rmsnorm_kernel<<<T_, blk, 0, stream>>>(qraw, 512, 512, q_a_ln_w, nullptr, qaH, qaL, 512);
    // 5. q = qa @ q_b
    gemm_planes<true><<<dim3(24, 8), blk, 0, stream>>>(qaH, qaL, qbTH, qbTL, qbuf, T_, 1536, 512);
    // 6. kva = h @ kv_a
    gemm_planes<true><<<dim3(5, 8), blk, 0, stream>>>(hH, hL, kvaTH, kvaTL, kva, T_, 288, 2048);
    // 7. kvcn
    rmsnorm_kernel<<<T_, blk, 0, stream>>>(kva, 288, 256, kv_a_ln_w, nullptr, kvcnH, kvcnL, 256);
    // 8. kv = kvcn @ kv_b
    gemm_planes<true><<<dim3(32, 8), blk, 0, stream>>>(kvcnH, kvcnL, kvbTH, kvbTL, kvbuf, T_, 2048, 256);
    // 9. rope + planes
    prep_qkv_kernel<<<T_, blk, 0, stream>>>(qbuf, kva, kvbuf, positions, qfH, qfL, kfH, kfL, vbH, vbL);
    // 10. flash attention
    attn_mfma_kernel<<<dim3(T_ / 64, NH), blk, 0, stream>>>(qfH, qfL, kfH, kfL, vbH, vbL, obH, obL);
    // 11. attn_out = ob @ o_w
    gemm_planes<true><<<dim3(32, 8), blk, 0, stream>>>(obH, obL, owTH, owTL, att, T_, 2048, 1024);
    // 12-14. fused resid + rmsnorm + routing
    fused_post_attn<<<T_, blk, 0, stream>>>(x0, att, post_ln_w, gate_w, gate_bias, h2bf, topidx, topw);
    // 15. sort (+shared tiles)
    sort_kernel<<<1, 512, 0, stream>>>(topidx, sorted_t, slotpos, tilemap);
    // 16. gather (bf16; slots 2048+ identity)
    gather_bf16_kernel<<<3 * T_, blk, 0, stream>>>(h2bf, sorted_t, gact);
    // 17+18. MoE gate+up fused with silu -> mact (experts + shared), plane B
    moe_gateup<<<dim3(16, MAXTILES), blk, 0, stream>>>(gact, egT, euT, mact, tilemap, 2048, 1024);
    // 19. MoE down (experts + shared), plane B
    moe_down<<<dim3(32, MAXTILES), blk, 0, stream>>>(mact, edT, md, tilemap, 1024, 2048);
    // 20. final combine (shared = md slot 2048+t)
    final_kernel<<<T_, blk, 0, stream>>>(x0, md, slotpos, topw, out);
}

// Round 12
// 608.713 us; speedup vs baseline: 1.2296x; 1.2296x over previous
//
#include <hip/hip_runtime.h>
#include <hip/hip_bf16.h>
#include <math.h>

constexpr int T_ = 1024;
constexpr int HDIM = 2048;
constexpr int NH = 16;
constexpr int QKD = 96;
constexpr int VD = 64;
constexpr int MAXTILES = 32;   // <=24 expert tiles + 8 shared tiles
constexpr float EPSF = 1e-6f;

using f32x4 = __attribute__((ext_vector_type(4))) float;
using s16x8 = __attribute__((ext_vector_type(8))) short;
using s16x4 = __attribute__((ext_vector_type(4))) short;

// ---------------- workspace layout (float offsets; ws is ~1 GB) ----------------
constexpr size_t OF_CATH  = 0;                 // bf16 T*4096
constexpr size_t OF_CATL  = 2097152;
constexpr size_t OF_GACT  = 0;                 // bf16 3072*2048 (alias cat planes; disjoint lifetime)
constexpr size_t OF_X0    = 4194304;           // f32 T*2048
constexpr size_t OF_MACT  = 6291456;           // bf16 3072*1024
constexpr size_t OF_HH    = 8388608;           // bf16 T*2048
constexpr size_t OF_HL    = 9437184;
constexpr size_t OF_QRAW  = 10485760;          // f32 T*512
constexpr size_t OF_QBUF  = 11010048;          // f32 T*1536
constexpr size_t OF_KVA   = 12582912;          // f32 T*288
constexpr size_t OF_KVBUF = 12877824;          // f32 T*2048
constexpr size_t OF_QAH   = 14974976;          // bf16 T*512
constexpr size_t OF_QAL   = 15237120;
constexpr size_t OF_KVCNH = 15499264;          // bf16 T*256
constexpr size_t OF_KVCNL = 15630336;
constexpr size_t OF_QFH   = 15761408;          // bf16 T*1536
constexpr size_t OF_QFL   = 16547840;
constexpr size_t OF_KFH   = 17334272;
constexpr size_t OF_KFL   = 18120704;
constexpr size_t OF_VBH   = 18907136;          // bf16 T*1024
constexpr size_t OF_VBL   = 19431424;
constexpr size_t OF_OBH   = 19955712;          // bf16 T*1024
constexpr size_t OF_OBL   = 20480000;
constexpr size_t OF_ATT   = 21004288;          // f32 T*2048
constexpr size_t OF_H2BF  = 23101440;          // bf16 T*2048
constexpr size_t OF_ROUT  = 24674304;          // ints
// weight planes (bf16)
constexpr size_t OF_EHTH  = 24682752;          // [2048][4096]
constexpr size_t OF_EHTL  = 28877056;
constexpr size_t OF_QATH  = 33071360;          // [512][2048]
constexpr size_t OF_QATL  = 33595648;
constexpr size_t OF_QBTH  = 34119936;          // [1536][512]
constexpr size_t OF_QBTL  = 34513152;
constexpr size_t OF_KVATH = 34906368;          // [320][2048] (288 used)
constexpr size_t OF_KVATL = 35234048;
constexpr size_t OF_KVBTH = 35561728;          // [2048][256]
constexpr size_t OF_KVBTL = 35823872;
constexpr size_t OF_OWTH  = 36086016;          // [2048][1024]
constexpr size_t OF_OWTL  = 37134592;
constexpr size_t OF_MD    = 38183168;          // f32 3072*2048

// ---------------- helpers ----------------
__device__ __forceinline__ short f2bf(float f) {
    union { float f; unsigned u; } x; x.f = f;
    unsigned r = x.u + 0x7fffu + ((x.u >> 16) & 1u);
    return (short)(r >> 16);
}
__device__ __forceinline__ float bf2f(short h) {
    union { unsigned u; float f; } x; x.u = ((unsigned)(unsigned short)h) << 16; return x.f;
}
// LDS swizzle (plane GEMM): row stride 64 shorts; chunk ^= row&7
__device__ __forceinline__ int swz(int r, int k) {
    return (r << 6) + ((((k >> 3) ^ (r & 7)) << 3) | (k & 7));
}
// async global->LDS, 16 B per lane; LDS dest = wave-uniform base + lane*16
__device__ __forceinline__ void gload16(const void* g, void* l) {
    __builtin_amdgcn_global_load_lds((__attribute__((address_space(1))) void*)g,
                                     (__attribute__((address_space(3))) void*)l, 16, 0, 0);
}

__device__ __forceinline__ float block_sum(float v) {
    __shared__ float sbuf[9];
    int lane = threadIdx.x & 63;
    int wid  = threadIdx.x >> 6;
#pragma unroll
    for (int off = 32; off > 0; off >>= 1) v += __shfl_down(v, off);
    __syncthreads();
    if (lane == 0) sbuf[wid] = v;
    __syncthreads();
    if (threadIdx.x == 0) {
        float s = 0.f;
        int nw = blockDim.x >> 6;
        for (int i = 0; i < nw; i++) s += sbuf[i];
        sbuf[8] = s;
    }
    __syncthreads();
    return sbuf[8];
}

// ---------------- weight transpose + split ----------------
__global__ void transpose_split_kernel(const float* __restrict__ W, short* __restrict__ Whi,
                                       short* __restrict__ Wlo, int K, int N, int split) {
    __shared__ float tile[64][65];
    int k0 = blockIdx.x * 64, n0 = blockIdx.y * 64;
    int tn = threadIdx.x & 63;
    int tk4 = threadIdx.x >> 6;
#pragma unroll 4
    for (int i = 0; i < 16; i++) {
        int kk = tk4 * 16 + i;
        int gn = n0 + tn;
        tile[kk][tn] = (gn < N) ? W[(size_t)(k0 + kk) * N + gn] : 0.f;
    }
    __syncthreads();
    int on = threadIdx.x >> 2;
    int oc = threadIdx.x & 3;
#pragma unroll 4
    for (int i = 0; i < 16; i++) {
        int kk = oc * 16 + i;
        float v = tile[kk][on];
        short hh = f2bf(v);
        size_t o = (size_t)(n0 + on) * K + k0 + kk;
        Whi[o] = hh;
        if (split) Wlo[o] = f2bf(v - bf2f(hh));
    }
}

// ---------------- embedding + rmsnorm + concat -> split planes ----------------
__global__ void embed_cat_kernel(const int* __restrict__ ids, const float* __restrict__ embed,
                                 const float* __restrict__ enorm, const float* __restrict__ prev,
                                 const float* __restrict__ hnorm, short* __restrict__ ch,
                                 short* __restrict__ cl) {
    int t = blockIdx.x;
    const float* e = embed + (size_t)ids[t] * HDIM;
    float ss = 0.f;
    for (int i = threadIdx.x; i < HDIM; i += blockDim.x) { float v = e[i]; ss += v * v; }
    float r = rsqrtf(block_sum(ss) / HDIM + EPSF);
    for (int i = threadIdx.x; i < HDIM; i += blockDim.x) {
        float v = e[i] * r * enorm[i];
        short hh = f2bf(v);
        ch[(size_t)t * 4096 + i] = hh;
        cl[(size_t)t * 4096 + i] = f2bf(v - bf2f(hh));
    }
    const float* p = prev + (size_t)t * HDIM;
    ss = 0.f;
    for (int i = threadIdx.x; i < HDIM; i += blockDim.x) { float v = p[i]; ss += v * v; }
    r = rsqrtf(block_sum(ss) / HDIM + EPSF);
    for (int i = threadIdx.x; i < HDIM; i += blockDim.x) {
        float v = p[i] * r * hnorm[i];
        short hh = f2bf(v);
        ch[(size_t)t * 4096 + 2048 + i] = hh;
        cl[(size_t)t * 4096 + 2048 + i] = f2bf(v - bf2f(hh));
    }
}

// ---------------- rmsnorm (f32 / hi / lo outputs) ----------------
__global__ void rmsnorm_kernel(const float* __restrict__ in, int in_stride, int width,
                               const float* __restrict__ w, float* __restrict__ outf,
                               short* __restrict__ outh, short* __restrict__ outl, int out_stride) {
    int t = blockIdx.x;
    const float* x = in + (size_t)t * in_stride;
    float ss = 0.f;
    for (int i = threadIdx.x; i < width; i += blockDim.x) { float v = x[i]; ss += v * v; }
    float r = rsqrtf(block_sum(ss) / width + EPSF);
    size_t ob = (size_t)t * out_stride;
    for (int i = threadIdx.x; i < width; i += blockDim.x) {
        float v = x[i] * r * w[i];
        if (outf) outf[ob + i] = v;
        if (outh) {
            short hh = f2bf(v);
            outh[ob + i] = hh;
            if (outl) outl[ob + i] = f2bf(v - bf2f(hh));
        }
    }
}

// =====================================================================
// Plane GEMM (round-10 verified): BM=128 BN=64 BK=64, gload16 staging
// with inverse-swizzled global source, swizzled LDS reads.
// =====================================================================
template<bool SPLIT>
__global__ __launch_bounds__(256) void gemm_planes(const short* __restrict__ Ahi, const short* __restrict__ Alo,
                                                   const short* __restrict__ Bhi, const short* __restrict__ Blo,
                                                   float* __restrict__ C, int M, int N, int K) {
    __shared__ short As[SPLIT ? 2 : 1][128 * 64];
    __shared__ short Bs[SPLIT ? 2 : 1][64 * 64];
    const int tid = threadIdx.x;
    const int lane = tid & 63, wid = tid >> 6;
    const int g = lane >> 4, li = lane & 15;
    const int wm = wid >> 1, wn = wid & 1;
    const int row0 = blockIdx.y * 128, col0 = blockIdx.x * 64;

    f32x4 acc[4][2];
#pragma unroll
    for (int mi = 0; mi < 4; mi++)
#pragma unroll
        for (int ni = 0; ni < 2; ni++)
#pragma unroll
            for (int r = 0; r < 4; r++) acc[mi][ni][r] = 0.f;

    for (int k0 = 0; k0 < K; k0 += 64) {
#pragma unroll
        for (int j = 0; j < 4; j++) {
            int blkI = wid * 4 + j;
            int cid = blkI * 64 + lane;
            int r = cid >> 3, c = (cid & 7) ^ (r & 7);
            gload16(&Ahi[(size_t)(row0 + r) * K + k0 + c * 8], &As[0][blkI * 512]);
            if constexpr (SPLIT)
                gload16(&Alo[(size_t)(row0 + r) * K + k0 + c * 8], &As[1][blkI * 512]);
        }
#pragma unroll
        for (int j = 0; j < 2; j++) {
            int blkI = wid * 2 + j;
            int cid = blkI * 64 + lane;
            int r = cid >> 3, c = (cid & 7) ^ (r & 7);
            gload16(&Bhi[(size_t)(col0 + r) * K + k0 + c * 8], &Bs[0][blkI * 512]);
            if constexpr (SPLIT)
                gload16(&Blo[(size_t)(col0 + r) * K + k0 + c * 8], &Bs[1][blkI * 512]);
        }
        __syncthreads();
#pragma unroll
        for (int kk = 0; kk < 64; kk += 32) {
            s16x8 ah[4], bh[2];
#pragma unroll
            for (int mi = 0; mi < 4; mi++) ah[mi] = *(const s16x8*)&As[0][swz(wm * 64 + mi * 16 + li, kk + g * 8)];
#pragma unroll
            for (int ni = 0; ni < 2; ni++) bh[ni] = *(const s16x8*)&Bs[0][swz(wn * 32 + ni * 16 + li, kk + g * 8)];
            if constexpr (SPLIT) {
                s16x8 al[4], bl[2];
#pragma unroll
                for (int mi = 0; mi < 4; mi++) al[mi] = *(const s16x8*)&As[1][swz(wm * 64 + mi * 16 + li, kk + g * 8)];
#pragma unroll
                for (int ni = 0; ni < 2; ni++) bl[ni] = *(const s16x8*)&Bs[1][swz(wn * 32 + ni * 16 + li, kk + g * 8)];
#pragma unroll
                for (int mi = 0; mi < 4; mi++)
#pragma unroll
                    for (int ni = 0; ni < 2; ni++) {
                        acc[mi][ni] = __builtin_amdgcn_mfma_f32_16x16x32_bf16(ah[mi], bh[ni], acc[mi][ni], 0, 0, 0);
                        acc[mi][ni] = __builtin_amdgcn_mfma_f32_16x16x32_bf16(al[mi], bh[ni], acc[mi][ni], 0, 0, 0);
                        acc[mi][ni] = __builtin_amdgcn_mfma_f32_16x16x32_bf16(ah[mi], bl[ni], acc[mi][ni], 0, 0, 0);
                    }
            } else {
#pragma unroll
                for (int mi = 0; mi < 4; mi++)
#pragma unroll
                    for (int ni = 0; ni < 2; ni++)
                        acc[mi][ni] = __builtin_amdgcn_mfma_f32_16x16x32_bf16(ah[mi], bh[ni], acc[mi][ni], 0, 0, 0);
            }
        }
        __syncthreads();
    }
#pragma unroll
    for (int mi = 0; mi < 4; mi++)
#pragma unroll
        for (int ni = 0; ni < 2; ni++) {
            int gc = col0 + wn * 32 + ni * 16 + li;
            if (gc < N) {
#pragma unroll
                for (int r = 0; r < 4; r++) {
                    int gr = row0 + wm * 64 + mi * 16 + g * 4 + r;
                    C[(size_t)gr * N + gc] = acc[mi][ni][r];
                }
            }
        }
}

// =====================================================================
// MoE gate+up GEMM + silu epilogue; A bf16 via gload16 (unguarded:
// allocation has 3072 rows, C-write masks gr>=nrows); B f32->bf16 staged.
// =====================================================================
__global__ __launch_bounds__(256) void moe_gateup(const short* __restrict__ Abase, const float* __restrict__ Wg,
                                                  const float* __restrict__ Wu, const float* __restrict__ Sg,
                                                  const float* __restrict__ Su, short* __restrict__ Cact,
                                                  const int4* __restrict__ tilemap, int K, int N) {
    int4 tm = tilemap[blockIdx.y];
    int nrows = tm.z;
    if (nrows == 0) return;
    const short* A = Abase + (size_t)tm.y * K;
    const float* Bg = (tm.x < 8) ? Wg + (size_t)tm.x * K * N : Sg;
    const float* Bu = (tm.x < 8) ? Wu + (size_t)tm.x * K * N : Su;

    __shared__ short As[128 * 64];
    alignas(16) __shared__ short Bgs[64][72];
    alignas(16) __shared__ short Bus[64][72];
    const int tid = threadIdx.x;
    const int lane = tid & 63, wid = tid >> 6;
    const int g = lane >> 4, li = lane & 15;
    const int wm = wid >> 1, wn = wid & 1;
    const int col0 = blockIdx.x * 64;

    f32x4 accg[4][2], accu[4][2];
#pragma unroll
    for (int mi = 0; mi < 4; mi++)
#pragma unroll
        for (int ni = 0; ni < 2; ni++)
#pragma unroll
            for (int r = 0; r < 4; r++) { accg[mi][ni][r] = 0.f; accu[mi][ni][r] = 0.f; }

    const int skb = (tid >> 4) << 2, snb = (tid & 15) << 2;

    for (int k0 = 0; k0 < K; k0 += 64) {
        // stage A via gload16 (linear dest, inverse-swizzled source)
#pragma unroll
        for (int j = 0; j < 4; j++) {
            int blkI = wid * 4 + j;
            int cid = blkI * 64 + lane;
            int r = cid >> 3, c = (cid & 7) ^ (r & 7);
            gload16(&A[(size_t)r * K + k0 + c * 8], &As[blkI * 512]);
        }
        // stage both B tiles (f32 -> bf16)
        {
            float4 rg[4], ru[4];
#pragma unroll
            for (int kk = 0; kk < 4; kk++) {
                rg[kk] = *(const float4*)(Bg + (size_t)(k0 + skb + kk) * N + col0 + snb);
                ru[kk] = *(const float4*)(Bu + (size_t)(k0 + skb + kk) * N + col0 + snb);
            }
#pragma unroll
            for (int n = 0; n < 4; n++) {
                s16x4 wg4, wu4;
                wg4[0] = f2bf((&rg[0].x)[n]); wg4[1] = f2bf((&rg[1].x)[n]);
                wg4[2] = f2bf((&rg[2].x)[n]); wg4[3] = f2bf((&rg[3].x)[n]);
                wu4[0] = f2bf((&ru[0].x)[n]); wu4[1] = f2bf((&ru[1].x)[n]);
                wu4[2] = f2bf((&ru[2].x)[n]); wu4[3] = f2bf((&ru[3].x)[n]);
                *(s16x4*)&Bgs[snb + n][skb] = wg4;
                *(s16x4*)&Bus[snb + n][skb] = wu4;
            }
        }
        __syncthreads();
#pragma unroll
        for (int kk = 0; kk < 64; kk += 32) {
            s16x8 a[4], bg2[2], bu2[2];
#pragma unroll
            for (int mi = 0; mi < 4; mi++) a[mi] = *(const s16x8*)&As[swz(wm * 64 + mi * 16 + li, kk + g * 8)];
#pragma unroll
            for (int ni = 0; ni < 2; ni++) {
                bg2[ni] = *(const s16x8*)&Bgs[wn * 32 + ni * 16 + li][kk + g * 8];
                bu2[ni] = *(const s16x8*)&Bus[wn * 32 + ni * 16 + li][kk + g * 8];
            }
#pragma unroll
            for (int mi = 0; mi < 4; mi++)
#pragma unroll
                for (int ni = 0; ni < 2; ni++) {
                    accg[mi][ni] = __builtin_amdgcn_mfma_f32_16x16x32_bf16(a[mi], bg2[ni], accg[mi][ni], 0, 0, 0);
                    accu[mi][ni] = __builtin_amdgcn_mfma_f32_16x16x32_bf16(a[mi], bu2[ni], accu[mi][ni], 0, 0, 0);
                }
        }
        __syncthreads();
    }
#pragma unroll
    for (int mi = 0; mi < 4; mi++)
#pragma unroll
        for (int ni = 0; ni < 2; ni++) {
            int gc = col0 + wn * 32 + ni * 16 + li;
#pragma unroll
            for (int r = 0; r < 4; r++) {
                int gr = wm * 64 + mi * 16 + g * 4 + r;
                if (gr < nrows) {
                    float x = accg[mi][ni][r], u = accu[mi][ni][r];
                    Cact[(size_t)(tm.y + gr) * N + gc] = f2bf((x / (1.f + expf(-x))) * u);
                }
            }
        }
}

// =====================================================================
// MoE down GEMM; A bf16 (mact) via gload16; B f32->bf16 staged; out md f32.
// =====================================================================
__global__ __launch_bounds__(256) void moe_down(const short* __restrict__ Abase, const float* __restrict__ Wall,
                                                const float* __restrict__ Sd, float* __restrict__ Cbase,
                                                const int4* __restrict__ tilemap, int K, int N) {
    int4 tm = tilemap[blockIdx.y];
    int nrows = tm.z;
    if (nrows == 0) return;
    const short* A = Abase + (size_t)tm.y * K;
    float* C = Cbase + (size_t)tm.y * N;
    const float* B = (tm.x < 8) ? Wall + (size_t)tm.x * K * N : Sd;

    __shared__ short As[128 * 64];
    alignas(16) __shared__ short Bs[64][72];
    const int tid = threadIdx.x;
    const int lane = tid & 63, wid = tid >> 6;
    const int g = lane >> 4, li = lane & 15;
    const int wm = wid >> 1, wn = wid & 1;
    const int col0 = blockIdx.x * 64;

    f32x4 acc[4][2];
#pragma unroll
    for (int mi = 0; mi < 4; mi++)
#pragma unroll
        for (int ni = 0; ni < 2; ni++)
#pragma unroll
            for (int r = 0; r < 4; r++) acc[mi][ni][r] = 0.f;

    const int skb = (tid >> 4) << 2, snb = (tid & 15) << 2;

    for (int k0 = 0; k0 < K; k0 += 64) {
#pragma unroll
        for (int j = 0; j < 4; j++) {
            int blkI = wid * 4 + j;
            int cid = blkI * 64 + lane;
            int r = cid >> 3, c = (cid & 7) ^ (r & 7);
            gload16(&A[(size_t)r * K + k0 + c * 8], &As[blkI * 512]);
        }
        {
            float4 r4[4];
#pragma unroll
            for (int kk = 0; kk < 4; kk++)
                r4[kk] = *(const float4*)(B + (size_t)(k0 + skb + kk) * N + col0 + snb);
#pragma unroll
            for (int n = 0; n < 4; n++) {
                s16x4 w;
                w[0] = f2bf((&r4[0].x)[n]); w[1] = f2bf((&r4[1].x)[n]);
                w[2] = f2bf((&r4[2].x)[n]); w[3] = f2bf((&r4[3].x)[n]);
                *(s16x4*)&Bs[snb + n][skb] = w;
            }
        }
        __syncthreads();
#pragma unroll
        for (int kk = 0; kk < 64; kk += 32) {
            s16x8 a[4], b[2];
#pragma unroll
            for (int mi = 0; mi < 4; mi++) a[mi] = *(const s16x8*)&As[swz(wm * 64 + mi * 16 + li, kk + g * 8)];
#pragma unroll
            for (int ni = 0; ni < 2; ni++) b[ni] = *(const s16x8*)&Bs[wn * 32 + ni * 16 + li][kk + g * 8];
#pragma unroll
            for (int mi = 0; mi < 4; mi++)
#pragma unroll
                for (int ni = 0; ni < 2; ni++)
                    acc[mi][ni] = __builtin_amdgcn_mfma_f32_16x16x32_bf16(a[mi], b[ni], acc[mi][ni], 0, 0, 0);
        }
        __syncthreads();
    }
#pragma unroll
    for (int mi = 0; mi < 4; mi++)
#pragma unroll
        for (int ni = 0; ni < 2; ni++) {
            int gc = col0 + wn * 32 + ni * 16 + li;
#pragma unroll
            for (int r = 0; r < 4; r++) {
                int gr = wm * 64 + mi * 16 + g * 4 + r;
                if (gr < nrows) C[(size_t)gr * N + gc] = acc[mi][ni][r];
            }
        }
}

// ---------------- RoPE + build qf/kf/v as split planes ----------------
__global__ void prep_qkv_kernel(const float* __restrict__ q, const float* __restrict__ kva,
                                const float* __restrict__ kv, const int* __restrict__ positions,
                                short* __restrict__ qfh, short* __restrict__ qfl,
                                short* __restrict__ kfh, short* __restrict__ kfl,
                                short* __restrict__ vbh, short* __restrict__ vbl) {
    int t = blockIdx.x;
    __shared__ float cs[16], sn[16];
    if (threadIdx.x < 16) {
        float invf = powf(10000.f, -(float)(2 * threadIdx.x) / 32.f);
        float fr = (float)positions[t] * invf;
        cs[threadIdx.x] = cosf(fr);
        sn[threadIdx.x] = sinf(fr);
    }
    __syncthreads();
    for (int i = threadIdx.x; i < NH * QKD; i += blockDim.x) {
        int h = i / QKD, d = i % QKD;
        float val;
        if (d < 64) val = q[(size_t)t * 1536 + h * QKD + d];
        else {
            int r = d - 64, pr = r >> 1;
            float x1 = q[(size_t)t * 1536 + h * QKD + 64 + 2 * pr];
            float x2 = q[(size_t)t * 1536 + h * QKD + 64 + 2 * pr + 1];
            val = (r & 1) ? (x1 * sn[pr] + x2 * cs[pr]) : (x1 * cs[pr] - x2 * sn[pr]);
        }
        short hh = f2bf(val);
        qfh[(size_t)t * 1536 + i] = hh;
        qfl[(size_t)t * 1536 + i] = f2bf(val - bf2f(hh));
    }
    for (int i = threadIdx.x; i < NH * QKD; i += blockDim.x) {
        int h = i / QKD, d = i % QKD;
        float val;
        if (d < 64) val = kv[(size_t)t * 2048 + h * 128 + d];
        else {
            int r = d - 64, pr = r >> 1;
            float x1 = kva[(size_t)t * 288 + 256 + 2 * pr];
            float x2 = kva[(size_t)t * 288 + 256 + 2 * pr + 1];
            val = (r & 1) ? (x1 * sn[pr] + x2 * cs[pr]) : (x1 * cs[pr] - x2 * sn[pr]);
        }
        short hh = f2bf(val);
        kfh[(size_t)t * 1536 + i] = hh;
        kfl[(size_t)t * 1536 + i] = f2bf(val - bf2f(hh));
    }
    for (int i = threadIdx.x; i < NH * VD; i += blockDim.x) {
        int h = i / VD, d = i % VD;
        float val = kv[(size_t)t * 2048 + h * 128 + 64 + d];
        short hh = f2bf(val);
        vbh[(size_t)t * 1024 + i] = hh;
        vbl[(size_t)t * 1024 + i] = f2bf(val - bf2f(hh));
    }
}

// =====================================================================
// MFMA flash attention (verified; reads/writes bf16 planes)
// =====================================================================
__global__ __launch_bounds__(256) void attn_mfma_kernel(const short* __restrict__ qfh, const short* __restrict__ qfl,
                                                        const short* __restrict__ kfh, const short* __restrict__ kfl,
                                                        const short* __restrict__ vbh, const short* __restrict__ vbl,
                                                        short* __restrict__ obh, short* __restrict__ obl) {
    __shared__ short K_hi[64][104], K_lo[64][104];
    __shared__ short Vt_hi[64][72], Vt_lo[64][72];
    __shared__ short P_hi[4][16][72], P_lo[4][16][72];
    const int qt = blockIdx.x, h = blockIdx.y;
    const int tid = threadIdx.x, lane = tid & 63, w = tid >> 6;
    const int g = lane >> 4, li = lane & 15;

    s16x8 q_hi[3], q_lo[3];
    {
        const short* qb_h = qfh + (size_t)(qt * 64 + w * 16 + li) * 1536 + h * QKD;
        const short* qb_l = qfl + (size_t)(qt * 64 + w * 16 + li) * 1536 + h * QKD;
#pragma unroll
        for (int ks = 0; ks < 3; ks++) {
            q_hi[ks] = *(const s16x8*)(qb_h + ks * 32 + g * 8);
            q_lo[ks] = *(const s16x8*)(qb_l + ks * 32 + g * 8);
        }
    }

    f32x4 acc_o[4];
#pragma unroll
    for (int nc = 0; nc < 4; nc++)
#pragma unroll
        for (int r = 0; r < 4; r++) acc_o[nc][r] = 0.f;
    float m4[4] = {-1e30f, -1e30f, -1e30f, -1e30f};
    float l4[4] = {0.f, 0.f, 0.f, 0.f};
    const float scale = 0.102062072616f;

    for (int kt = 0; kt <= qt; kt++) {
#pragma unroll
        for (int it = 0; it < 3; it++) {
            int cid = it * 256 + tid;
            int key = cid / 12, c = cid % 12;
            *(s16x8*)&K_hi[key][c * 8] = *(const s16x8*)&kfh[(size_t)(kt * 64 + key) * 1536 + h * QKD + c * 8];
            *(s16x8*)&K_lo[key][c * 8] = *(const s16x8*)&kfl[(size_t)(kt * 64 + key) * 1536 + h * QKD + c * 8];
        }
#pragma unroll
        for (int it = 0; it < 2; it++) {
            int cid = it * 256 + tid;
            int key = cid >> 3, vc = cid & 7;
            s16x8 vh = *(const s16x8*)&vbh[(size_t)(kt * 64 + key) * 1024 + h * VD + vc * 8];
            s16x8 vl = *(const s16x8*)&vbl[(size_t)(kt * 64 + key) * 1024 + h * VD + vc * 8];
#pragma unroll
            for (int j = 0; j < 8; j++) {
                Vt_hi[vc * 8 + j][key] = vh[j];
                Vt_lo[vc * 8 + j][key] = vl[j];
            }
        }
        __syncthreads();

        f32x4 acc_s[4];
#pragma unroll
        for (int kc = 0; kc < 4; kc++)
#pragma unroll
            for (int r = 0; r < 4; r++) acc_s[kc][r] = 0.f;
#pragma unroll
        for (int ks = 0; ks < 3; ks++) {
#pragma unroll
            for (int kc = 0; kc < 4; kc++) {
                s16x8 kh = *(const s16x8*)&K_hi[kc * 16 + li][ks * 32 + g * 8];
                s16x8 kl = *(const s16x8*)&K_lo[kc * 16 + li][ks * 32 + g * 8];
                acc_s[kc] = __builtin_amdgcn_mfma_f32_16x16x32_bf16(q_hi[ks], kh, acc_s[kc], 0, 0, 0);
                acc_s[kc] = __builtin_amdgcn_mfma_f32_16x16x32_bf16(q_lo[ks], kh, acc_s[kc], 0, 0, 0);
                acc_s[kc] = __builtin_amdgcn_mfma_f32_16x16x32_bf16(q_hi[ks], kl, acc_s[kc], 0, 0, 0);
            }
        }
#pragma unroll
        for (int kc = 0; kc < 4; kc++)
#pragma unroll
            for (int r = 0; r < 4; r++) acc_s[kc][r] *= scale;
        if (kt == qt) {
#pragma unroll
            for (int kc = 0; kc < 4; kc++) {
                int key = kt * 64 + kc * 16 + li;
#pragma unroll
                for (int r = 0; r < 4; r++) {
                    int qr = qt * 64 + w * 16 + g * 4 + r;
                    if (key > qr) acc_s[kc][r] = -1e30f;
                }
            }
        }
        float tm4[4];
#pragma unroll
        for (int r = 0; r < 4; r++)
            tm4[r] = fmaxf(fmaxf(acc_s[0][r], acc_s[1][r]), fmaxf(acc_s[2][r], acc_s[3][r]));
#pragma unroll
        for (int off = 1; off < 16; off <<= 1)
#pragma unroll
            for (int r = 0; r < 4; r++) tm4[r] = fmaxf(tm4[r], __shfl_xor(tm4[r], off));
        float alpha[4];
#pragma unroll
        for (int r = 0; r < 4; r++) {
            float mn = fmaxf(m4[r], tm4[r]);
            alpha[r] = __expf(m4[r] - mn);
            m4[r] = mn;
        }
        float rs[4] = {0.f, 0.f, 0.f, 0.f};
#pragma unroll
        for (int kc = 0; kc < 4; kc++)
#pragma unroll
            for (int r = 0; r < 4; r++) {
                float p = __expf(acc_s[kc][r] - m4[r]);
                rs[r] += p;
                short hh = f2bf(p);
                P_hi[w][g * 4 + r][kc * 16 + li] = hh;
                P_lo[w][g * 4 + r][kc * 16 + li] = f2bf(p - bf2f(hh));
            }
#pragma unroll
        for (int off = 1; off < 16; off <<= 1)
#pragma unroll
            for (int r = 0; r < 4; r++) rs[r] += __shfl_xor(rs[r], off);
#pragma unroll
        for (int r = 0; r < 4; r++) l4[r] = l4[r] * alpha[r] + rs[r];
#pragma unroll
        for (int nc = 0; nc < 4; nc++)
#pragma unroll
            for (int r = 0; r < 4; r++) acc_o[nc][r] *= alpha[r];
#pragma unroll
        for (int ks = 0; ks < 2; ks++) {
            s16x8 ph = *(const s16x8*)&P_hi[w][li][ks * 32 + g * 8];
            s16x8 pl = *(const s16x8*)&P_lo[w][li][ks * 32 + g * 8];
#pragma unroll
            for (int nc = 0; nc < 4; nc++) {
                s16x8 vh = *(const s16x8*)&Vt_hi[nc * 16 + li][ks * 32 + g * 8];
                s16x8 vl = *(const s16x8*)&Vt_lo[nc * 16 + li][ks * 32 + g * 8];
                acc_o[nc] = __builtin_amdgcn_mfma_f32_16x16x32_bf16(ph, vh, acc_o[nc], 0, 0, 0);
                acc_o[nc] = __builtin_amdgcn_mfma_f32_16x16x32_bf16(pl, vh, acc_o[nc], 0, 0, 0);
                acc_o[nc] = __builtin_amdgcn_mfma_f32_16x16x32_bf16(ph, vl, acc_o[nc], 0, 0, 0);
            }
        }
        __syncthreads();
    }
    float inv[4];
#pragma unroll
    for (int r = 0; r < 4; r++) inv[r] = 1.f / l4[r];
#pragma unroll
    for (int nc = 0; nc < 4; nc++)
#pragma unroll
        for (int r = 0; r < 4; r++) {
            float o = acc_o[nc][r] * inv[r];
            size_t idx = (size_t)(qt * 64 + w * 16 + g * 4 + r) * 1024 + h * VD + nc * 16 + li;
            short hh = f2bf(o);
            obh[idx] = hh;
            obl[idx] = f2bf(o - bf2f(hh));
        }
}

// ---------------- fused resid-add + post-rmsnorm + routing ----------------
__global__ __launch_bounds__(256) void fused_post_attn(float* __restrict__ x0, const float* __restrict__ att,
                                                       const float* __restrict__ w, const float* __restrict__ gate_w,
                                                       const float* __restrict__ gate_bias,
                                                       short* __restrict__ h2bf, int* __restrict__ topidx,
                                                       float* __restrict__ topw) {
    int t = blockIdx.x;
    float resid[8];
    float ss = 0.f;
#pragma unroll
    for (int j = 0; j < 8; j++) {
        int i = threadIdx.x + j * 256;
        float v = x0[(size_t)t * HDIM + i] + att[(size_t)t * HDIM + i];
        resid[j] = v;
        x0[(size_t)t * HDIM + i] = v;
        ss += v * v;
    }
    float r = rsqrtf(block_sum(ss) / HDIM + EPSF);
    float acc[8] = {0.f, 0.f, 0.f, 0.f, 0.f, 0.f, 0.f, 0.f};
#pragma unroll
    for (int j = 0; j < 8; j++) {
        int i = threadIdx.x + j * 256;
        float v = resid[j] * r * w[i];
        h2bf[(size_t)t * HDIM + i] = f2bf(v);
        const float* gw = gate_w + (size_t)i * 8;
        float4 g0 = *(const float4*)gw;
        float4 g1 = *(const float4*)(gw + 4);
        acc[0] = fmaf(v, g0.x, acc[0]); acc[1] = fmaf(v, g0.y, acc[1]);
        acc[2] = fmaf(v, g0.z, acc[2]); acc[3] = fmaf(v, g0.w, acc[3]);
        acc[4] = fmaf(v, g1.x, acc[4]); acc[5] = fmaf(v, g1.y, acc[5]);
        acc[6] = fmaf(v, g1.z, acc[6]); acc[7] = fmaf(v, g1.w, acc[7]);
    }
    __shared__ float logits[8];
    for (int e = 0; e < 8; e++) {
        float s = block_sum(acc[e]);
        if (threadIdx.x == 0) logits[e] = s;
    }
    __syncthreads();
    if (threadIdx.x == 0) {
        float sig[8], sc[8];
        for (int e = 0; e < 8; e++) {
            sig[e] = 1.f / (1.f + expf(-logits[e]));
            sc[e] = sig[e] + gate_bias[e];
        }
        int i0 = 0;
        for (int e = 1; e < 8; e++) if (sc[e] > sc[i0]) i0 = e;
        int i1 = -1;
        for (int e = 0; e < 8; e++) if (e != i0 && (i1 < 0 || sc[e] > sc[i1])) i1 = e;
        float w0 = sig[i0], w1 = sig[i1], s = w0 + w1 + 1e-20f;
        topidx[t * 2 + 0] = i0; topidx[t * 2 + 1] = i1;
        topw[t * 2 + 0] = w0 / s; topw[t * 2 + 1] = w1 / s;
    }
}

// ---------------- counting sort + tile map (+8 shared tiles) ----------------
__global__ void sort_kernel(const int* __restrict__ topidx, int* __restrict__ sorted_t,
                            int* __restrict__ slotpos, int4* __restrict__ tilemap) {
    __shared__ int counts[8], offs[9];
    int wid = threadIdx.x >> 6, lane = threadIdx.x & 63;
    int cnt = 0;
    for (int base = 0; base < 2 * T_; base += 64) {
        int e = topidx[base + lane];
        unsigned long long m = __ballot(e == wid);
        cnt += __popcll(m);
    }
    if (lane == 0) counts[wid] = cnt;
    __syncthreads();
    if (threadIdx.x == 0) {
        offs[0] = 0;
        for (int e = 0; e < 8; e++) offs[e + 1] = offs[e] + counts[e];
    }
    __syncthreads();
    int pos = offs[wid];
    for (int base = 0; base < 2 * T_; base += 64) {
        int sl = base + lane;
        int e = topidx[sl];
        bool match = (e == wid);
        unsigned long long m = __ballot(match);
        if (match) {
            int before = __popcll(m & ((1ull << lane) - 1ull));
            int pp = pos + before;
            sorted_t[pp] = sl >> 1;
            slotpos[sl] = pp;
        }
        pos += __popcll(m);
    }
    __syncthreads();
    if (threadIdx.x == 0) {
        int nt = 0;
        for (int e = 0; e < 8; e++) {
            int c = counts[e], o = offs[e];
            for (int r = 0; r < c; r += 128) {
                tilemap[nt] = make_int4(e, o + r, min(128, c - r), 0);
                nt++;
            }
        }
        for (int r = 0; r < 8; r++) {             // shared MLP as expert 8
            tilemap[nt] = make_int4(8, 2048 + r * 128, 128, 0);
            nt++;
        }
        for (int i = nt; i < MAXTILES; i++) tilemap[i] = make_int4(0, 0, 0, 0);
    }
}

// ---------------- gather h2bf rows (slots 2048+ are identity tokens) ----------------
__global__ void gather_bf16_kernel(const short* __restrict__ h2bf, const int* __restrict__ sorted_t,
                                   short* __restrict__ gout) {
    int pp = blockIdx.x;
    int t = (pp < 2048) ? sorted_t[pp] : (pp - 2048);
    const s16x8* src = (const s16x8*)(h2bf + (size_t)t * HDIM);
    s16x8* dst = (s16x8*)(gout + (size_t)pp * HDIM);
    dst[threadIdx.x] = src[threadIdx.x];
}

// ---------------- final combine -> f32 out ----------------
__global__ void final_kernel(const float* __restrict__ resid, const float* __restrict__ md,
                             const int* __restrict__ slotpos, const float* __restrict__ topw,
                             float* __restrict__ out) {
    int t = blockIdx.x;
    int p0 = slotpos[t * 2 + 0], p1 = slotpos[t * 2 + 1];
    float w0 = topw[t * 2 + 0] * 2.5f, w1 = topw[t * 2 + 1] * 2.5f;
    const float* mds = md + (size_t)(2048 + t) * HDIM;
    for (int c = threadIdx.x; c < HDIM; c += blockDim.x) {
        float v = resid[(size_t)t * HDIM + c] + mds[c]
                + w0 * md[(size_t)p0 * HDIM + c] + w1 * md[(size_t)p1 * HDIM + c];
        out[(size_t)t * HDIM + c] = v;
    }
}

// ---------------- launcher ----------------
extern "C" void kernel_launch(void* const* d_in, const int* in_sizes, int n_in,
                              void* d_out, int out_size, void* d_ws, size_t ws_size,
                              hipStream_t stream) {
    (void)in_sizes; (void)n_in; (void)out_size; (void)ws_size;
    const int*   input_ids = (const int*)d_in[0];
    const int*   positions = (const int*)d_in[1];
    const float* prev      = (const float*)d_in[2];
    const float* embed     = (const float*)d_in[3];
    const float* enorm_w   = (const float*)d_in[4];
    const float* hnorm_w   = (const float*)d_in[5];
    const float* eh_proj_w = (const float*)d_in[6];
    const float* in_ln_w   = (const float*)d_in[7];
    const float* post_ln_w = (const float*)d_in[8];
    const float* q_a_w     = (const float*)d_in[9];
    const float* q_a_ln_w  = (const float*)d_in[10];
    const float* q_b_w     = (const float*)d_in[11];
    const float* kv_a_w    = (const float*)d_in[12];
    const float* kv_a_ln_w = (const float*)d_in[13];
    const float* kv_b_w    = (const float*)d_in[14];
    const float* o_w       = (const float*)d_in[15];
    const float* gate_w    = (const float*)d_in[16];
    const float* gate_bias = (const float*)d_in[17];
    const float* exp_g     = (const float*)d_in[18];
    const float* exp_u     = (const float*)d_in[19];
    const float* exp_d     = (const float*)d_in[20];
    const float* sh_g      = (const float*)d_in[21];
    const float* sh_u      = (const float*)d_in[22];
    const float* sh_d      = (const float*)d_in[23];
    float* out = (float*)d_out;

    float* ws = (float*)d_ws;
    short* catH  = (short*)(ws + OF_CATH);
    short* catL  = (short*)(ws + OF_CATL);
    short* gact  = (short*)(ws + OF_GACT);
    float* x0    = ws + OF_X0;
    short* mact  = (short*)(ws + OF_MACT);
    short* hH    = (short*)(ws + OF_HH);
    short* hL    = (short*)(ws + OF_HL);
    float* qraw  = ws + OF_QRAW;
    float* qbuf  = ws + OF_QBUF;
    float* kva   = ws + OF_KVA;
    float* kvbuf = ws + OF_KVBUF;
    short* qaH   = (short*)(ws + OF_QAH);
    short* qaL   = (short*)(ws + OF_QAL);
    short* kvcnH = (short*)(ws + OF_KVCNH);
    short* kvcnL = (short*)(ws + OF_KVCNL);
    short* qfH   = (short*)(ws + OF_QFH);
    short* qfL   = (short*)(ws + OF_QFL);
    short* kfH   = (short*)(ws + OF_KFH);
    short* kfL   = (short*)(ws + OF_KFL);
    short* vbH   = (short*)(ws + OF_VBH);
    short* vbL   = (short*)(ws + OF_VBL);
    short* obH   = (short*)(ws + OF_OBH);
    short* obL   = (short*)(ws + OF_OBL);
    float* att   = ws + OF_ATT;
    short* h2bf  = (short*)(ws + OF_H2BF);
    float* md    = ws + OF_MD;
    int*   ri       = (int*)(ws + OF_ROUT);
    int*   topidx   = ri;
    int*   sorted_t = ri + 2048;
    int*   slotpos  = ri + 4096;
    int4*  tilemap  = (int4*)(ri + 6144);
    float* topw     = (float*)(ri + 6144 + 4 * MAXTILES);
    short* ehTH  = (short*)(ws + OF_EHTH);
    short* ehTL  = (short*)(ws + OF_EHTL);
    short* qaTH  = (short*)(ws + OF_QATH);
    short* qaTL  = (short*)(ws + OF_QATL);
    short* qbTH  = (short*)(ws + OF_QBTH);
    short* qbTL  = (short*)(ws + OF_QBTL);
    short* kvaTH = (short*)(ws + OF_KVATH);
    short* kvaTL = (short*)(ws + OF_KVATL);
    short* kvbTH = (short*)(ws + OF_KVBTH);
    short* kvbTL = (short*)(ws + OF_KVBTL);
    short* owTH  = (short*)(ws + OF_OWTH);
    short* owTL  = (short*)(ws + OF_OWTL);

    dim3 blk(256);

    // 0. weight transpose+split (dense chain only; MoE weights stay f32)
    transpose_split_kernel<<<dim3(64, 32), blk, 0, stream>>>(eh_proj_w, ehTH, ehTL, 4096, 2048, 1);
    transpose_split_kernel<<<dim3(32, 8), blk, 0, stream>>>(q_a_w, qaTH, qaTL, 2048, 512, 1);
    transpose_split_kernel<<<dim3(8, 24), blk, 0, stream>>>(q_b_w, qbTH, qbTL, 512, 1536, 1);
    transpose_split_kernel<<<dim3(32, 5), blk, 0, stream>>>(kv_a_w, kvaTH, kvaTL, 2048, 288, 1);
    transpose_split_kernel<<<dim3(4, 32), blk, 0, stream>>>(kv_b_w, kvbTH, kvbTL, 256, 2048, 1);
    transpose_split_kernel<<<dim3(16, 32), blk, 0, stream>>>(o_w, owTH, owTL, 1024, 2048, 1);

    // 1. embed + rmsnorm + concat
    embed_cat_kernel<<<T_, blk, 0, stream>>>(input_ids, embed, enorm_w, prev, hnorm_w, catH, catL);
    // 2. x0 = cat @ eh_proj
    gemm_planes<true><<<dim3(32, 8), blk, 0, stream>>>(catH, catL, ehTH, ehTL, x0, T_, 2048, 4096);
    // 3. h = rmsnorm(x0)
    rmsnorm_kernel<<<T_, blk, 0, stream>>>(x0, 2048, 2048, in_ln_w, nullptr, hH, hL, 2048);
    // 4. q_a
    gemm_planes<true><<<dim3(8, 8), blk, 0, stream>>>(hH, hL, qaTH, qaTL, qraw, T_, 512, 2048);
    rmsnorm_kernel<<<T_, blk, 0, stream>>>(qraw, 512, 512, q_a_ln_w, nullptr, qaH, qaL, 512);
    // 5. q = qa @ q_b
    gemm_planes<true><<<dim3(24, 8), blk, 0, stream>>>(qaH, qaL, qbTH, qbTL, qbuf, T_, 1536, 512);
    // 6. kva = h @ kv_a
    gemm_planes<true><<<dim3(5, 8), blk, 0, stream>>>(hH, hL, kvaTH, kvaTL, kva, T_, 288, 2048);
    // 7. kvcn
    rmsnorm_kernel<<<T_, blk, 0, stream>>>(kva, 288, 256, kv_a_ln_w, nullptr, kvcnH, kvcnL, 256);
    // 8. kv = kvcn @ kv_b
    gemm_planes<true><<<dim3(32, 8), blk, 0, stream>>>(kvcnH, kvcnL, kvbTH, kvbTL, kvbuf, T_, 2048, 256);
    // 9. rope + planes
    prep_qkv_kernel<<<T_, blk, 0, stream>>>(qbuf, kva, kvbuf, positions, qfH, qfL, kfH, kfL, vbH, vbL);
    // 10. flash attention
    attn_mfma_kernel<<<dim3(T_ / 64, NH), blk, 0, stream>>>(qfH, qfL, kfH, kfL, vbH, vbL, obH, obL);
    // 11. attn_out = ob @ o_w
    gemm_planes<true><<<dim3(32, 8), blk, 0, stream>>>(obH, obL, owTH, owTL, att, T_, 2048, 1024);
    // 12-14. fused resid + rmsnorm + routing
    fused_post_attn<<<T_, blk, 0, stream>>>(x0, att, post_ln_w, gate_w, gate_bias, h2bf, topidx, topw);
    // 15. sort (+shared tiles)
    sort_kernel<<<1, 512, 0, stream>>>(topidx, sorted_t, slotpos, tilemap);
    // 16. gather (bf16; slots 2048+ identity)
    gather_bf16_kernel<<<3 * T_, blk, 0, stream>>>(h2bf, sorted_t, gact);
    // 17+18. MoE gate+up fused with silu -> mact (experts + shared)
    moe_gateup<<<dim3(16, MAXTILES), blk, 0, stream>>>(gact, exp_g, exp_u, sh_g, sh_u, mact, tilemap, 2048, 1024);
    // 19. MoE down (experts + shared)
    moe_down<<<dim3(32, MAXTILES), blk, 0, stream>>>(mact, exp_d, sh_d, md, tilemap, 1024, 2048);
    // 20. final combine (shared = md slot 2048+t)
    final_kernel<<<T_, blk, 0, stream>>>(x0, md, slotpos, topw, out);
}

// Round 14
// 538.725 us; speedup vs baseline: 1.3894x; 1.1299x over previous
//
#include <hip/hip_runtime.h>
#include <hip/hip_bf16.h>
#include <math.h>

constexpr int T_ = 1024;
constexpr int HDIM = 2048;
constexpr int NH = 16;
constexpr int QKD = 96;
constexpr int VD = 64;
constexpr int MAXTILES = 32;   // <=24 expert tiles + 8 shared tiles
constexpr float EPSF = 1e-6f;

using f32x4 = __attribute__((ext_vector_type(4))) float;
using s16x8 = __attribute__((ext_vector_type(8))) short;
using s16x4 = __attribute__((ext_vector_type(4))) short;

// ---------------- workspace layout (float offsets; ws is ~1 GB) ----------------
constexpr size_t OF_CATH  = 0;                 // bf16 T*4096
constexpr size_t OF_CATL  = 2097152;
constexpr size_t OF_X0    = 4194304;           // f32 T*2048
constexpr size_t OF_MACT  = 6291456;           // bf16 3072*1024
constexpr size_t OF_HH    = 8388608;           // bf16 T*2048
constexpr size_t OF_HL    = 9437184;
constexpr size_t OF_QBUF  = 11010048;          // f32 T*1536
constexpr size_t OF_KVBUF = 12877824;          // f32 T*2048
constexpr size_t OF_QAH   = 14974976;          // bf16 T*512
constexpr size_t OF_QAL   = 15237120;
constexpr size_t OF_KVCNH = 15499264;          // bf16 T*256
constexpr size_t OF_KVCNL = 15630336;
constexpr size_t OF_QFH   = 15761408;          // bf16 T*1536
constexpr size_t OF_QFL   = 16547840;
constexpr size_t OF_KFH   = 17334272;
constexpr size_t OF_KFL   = 18120704;
constexpr size_t OF_VBH   = 18907136;          // bf16 T*1024
constexpr size_t OF_VBL   = 19431424;
constexpr size_t OF_OBH   = 19955712;          // bf16 T*1024
constexpr size_t OF_OBL   = 20480000;
constexpr size_t OF_ATT   = 21004288;          // f32 T*2048
constexpr size_t OF_H2BF  = 23101440;          // bf16 T*2048
constexpr size_t OF_ROUT  = 24674304;          // ints
// weight planes (bf16)
constexpr size_t OF_EHTH  = 24682752;          // [2048][4096]
constexpr size_t OF_EHTL  = 28877056;
constexpr size_t OF_QBTH  = 34119936;          // [1536][512]
constexpr size_t OF_QBTL  = 34513152;
constexpr size_t OF_KVBTH = 35561728;          // [2048][256]
constexpr size_t OF_KVBTL = 35823872;
constexpr size_t OF_OWTH  = 36086016;          // [2048][1024]
constexpr size_t OF_OWTL  = 37134592;
constexpr size_t OF_MD    = 38183168;          // f32 3072*2048  (ends 44474624)
constexpr size_t OF_QKRAW = 44474624;          // f32 [1024][800] (ends 45293824)
constexpr size_t OF_BATH  = 45293824;          // bf16 [832][2048] = 851968 floats (ends 46145792)
constexpr size_t OF_BATL  = 46145792;          // bf16 [832][2048] (ends 46997760; FIXED round-13 overlap)

// ---------------- helpers ----------------
__device__ __forceinline__ short f2bf(float f) {
    union { float f; unsigned u; } x; x.f = f;
    unsigned r = x.u + 0x7fffu + ((x.u >> 16) & 1u);
    return (short)(r >> 16);
}
__device__ __forceinline__ float bf2f(short h) {
    union { unsigned u; float f; } x; x.u = ((unsigned)(unsigned short)h) << 16; return x.f;
}
// LDS swizzle (plane GEMM): row stride 64 shorts; chunk ^= row&7
__device__ __forceinline__ int swz(int r, int k) {
    return (r << 6) + ((((k >> 3) ^ (r & 7)) << 3) | (k & 7));
}
// async global->LDS, 16 B per lane; LDS dest = wave-uniform base + lane*16
__device__ __forceinline__ void gload16(const void* g, void* l) {
    __builtin_amdgcn_global_load_lds((__attribute__((address_space(1))) void*)g,
                                     (__attribute__((address_space(3))) void*)l, 16, 0, 0);
}

__device__ __forceinline__ float block_sum(float v) {
    __shared__ float sbuf[9];
    int lane = threadIdx.x & 63;
    int wid  = threadIdx.x >> 6;
#pragma unroll
    for (int off = 32; off > 0; off >>= 1) v += __shfl_down(v, off);
    __syncthreads();
    if (lane == 0) sbuf[wid] = v;
    __syncthreads();
    if (threadIdx.x == 0) {
        float s = 0.f;
        int nw = blockDim.x >> 6;
        for (int i = 0; i < nw; i++) s += sbuf[i];
        sbuf[8] = s;
    }
    __syncthreads();
    return sbuf[8];
}

// ---------------- multi-job weight transpose + split ----------------
struct TJobs {
    const float* W[6];
    short* Whi[6];
    short* Wlo[6];
    int K[6];
    int N[6];
    int nbx[6];
    int base[7];
};

__global__ void transpose_multi_kernel(TJobs J) {
    int bid = blockIdx.x;
    int j = 0;
#pragma unroll
    for (int i = 1; i < 6; i++) if (bid >= J.base[i]) j = i;
    int local = bid - J.base[j];
    int K = J.K[j], N = J.N[j];
    int bx = local % J.nbx[j], by = local / J.nbx[j];
    const float* W = J.W[j];
    short* Whi = J.Whi[j];
    short* Wlo = J.Wlo[j];

    __shared__ float tile[64][65];
    int k0 = bx * 64, n0 = by * 64;
    int tn = threadIdx.x & 63;
    int tk4 = threadIdx.x >> 6;
#pragma unroll 4
    for (int i = 0; i < 16; i++) {
        int kk = tk4 * 16 + i;
        int gn = n0 + tn;
        tile[kk][tn] = (gn < N) ? W[(size_t)(k0 + kk) * N + gn] : 0.f;
    }
    __syncthreads();
    int on = threadIdx.x >> 2;
    int oc = threadIdx.x & 3;
#pragma unroll 4
    for (int i = 0; i < 16; i++) {
        int kk = oc * 16 + i;
        float v = tile[kk][on];
        short hh = f2bf(v);
        size_t o = (size_t)(n0 + on) * K + k0 + kk;
        Whi[o] = hh;
        Wlo[o] = f2bf(v - bf2f(hh));
    }
}

// ---------------- embedding + rmsnorm + concat -> split planes ----------------
__global__ void embed_cat_kernel(const int* __restrict__ ids, const float* __restrict__ embed,
                                 const float* __restrict__ enorm, const float* __restrict__ prev,
                                 const float* __restrict__ hnorm, short* __restrict__ ch,
                                 short* __restrict__ cl) {
    int t = blockIdx.x;
    const float* e = embed + (size_t)ids[t] * HDIM;
    float ss = 0.f;
    for (int i = threadIdx.x; i < HDIM; i += blockDim.x) { float v = e[i]; ss += v * v; }
    float r = rsqrtf(block_sum(ss) / HDIM + EPSF);
    for (int i = threadIdx.x; i < HDIM; i += blockDim.x) {
        float v = e[i] * r * enorm[i];
        short hh = f2bf(v);
        ch[(size_t)t * 4096 + i] = hh;
        cl[(size_t)t * 4096 + i] = f2bf(v - bf2f(hh));
    }
    const float* p = prev + (size_t)t * HDIM;
    ss = 0.f;
    for (int i = threadIdx.x; i < HDIM; i += blockDim.x) { float v = p[i]; ss += v * v; }
    r = rsqrtf(block_sum(ss) / HDIM + EPSF);
    for (int i = threadIdx.x; i < HDIM; i += blockDim.x) {
        float v = p[i] * r * hnorm[i];
        short hh = f2bf(v);
        ch[(size_t)t * 4096 + 2048 + i] = hh;
        cl[(size_t)t * 4096 + 2048 + i] = f2bf(v - bf2f(hh));
    }
}

// ---------------- rmsnorm (f32 / hi / lo outputs) ----------------
__global__ void rmsnorm_kernel(const float* __restrict__ in, int in_stride, int width,
                               const float* __restrict__ w, float* __restrict__ outf,
                               short* __restrict__ outh, short* __restrict__ outl, int out_stride) {
    int t = blockIdx.x;
    const float* x = in + (size_t)t * in_stride;
    float ss = 0.f;
    for (int i = threadIdx.x; i < width; i += blockDim.x) { float v = x[i]; ss += v * v; }
    float r = rsqrtf(block_sum(ss) / width + EPSF);
    size_t ob = (size_t)t * out_stride;
    for (int i = threadIdx.x; i < width; i += blockDim.x) {
        float v = x[i] * r * w[i];
        if (outf) outf[ob + i] = v;
        if (outh) {
            short hh = f2bf(v);
            outh[ob + i] = hh;
            if (outl) outl[ob + i] = f2bf(v - bf2f(hh));
        }
    }
}

// ---------------- fused rmsnorm for qkraw: q_a (cols 0-511) + kv_c (cols 512-767) ----------------
__global__ void rmsnorm_qkv_kernel(const float* __restrict__ qkraw, const float* __restrict__ wq,
                                   const float* __restrict__ wkv, short* __restrict__ qaH,
                                   short* __restrict__ qaL, short* __restrict__ kvcnH,
                                   short* __restrict__ kvcnL) {
    int t = blockIdx.x;
    const float* row = qkraw + (size_t)t * 800;
    float ss = 0.f;
    for (int i = threadIdx.x; i < 512; i += blockDim.x) { float v = row[i]; ss += v * v; }
    float r = rsqrtf(block_sum(ss) / 512.f + EPSF);
    for (int i = threadIdx.x; i < 512; i += blockDim.x) {
        float v = row[i] * r * wq[i];
        short hh = f2bf(v);
        qaH[(size_t)t * 512 + i] = hh;
        qaL[(size_t)t * 512 + i] = f2bf(v - bf2f(hh));
    }
    ss = 0.f;
    for (int i = threadIdx.x; i < 256; i += blockDim.x) { float v = row[512 + i]; ss += v * v; }
    r = rsqrtf(block_sum(ss) / 256.f + EPSF);
    for (int i = threadIdx.x; i < 256; i += blockDim.x) {
        float v = row[512 + i] * r * wkv[i];
        short hh = f2bf(v);
        kvcnH[(size_t)t * 256 + i] = hh;
        kvcnL[(size_t)t * 256 + i] = f2bf(v - bf2f(hh));
    }
}

// =====================================================================
// Plane GEMM (round-10 verified): BM=128 BN=64 BK=64, gload16 staging
// with inverse-swizzled global source, swizzled LDS reads.
// =====================================================================
template<bool SPLIT>
__global__ __launch_bounds__(256) void gemm_planes(const short* __restrict__ Ahi, const short* __restrict__ Alo,
                                                   const short* __restrict__ Bhi, const short* __restrict__ Blo,
                                                   float* __restrict__ C, int M, int N, int K) {
    __shared__ short As[SPLIT ? 2 : 1][128 * 64];
    __shared__ short Bs[SPLIT ? 2 : 1][64 * 64];
    const int tid = threadIdx.x;
    const int lane = tid & 63, wid = tid >> 6;
    const int g = lane >> 4, li = lane & 15;
    const int wm = wid >> 1, wn = wid & 1;
    const int row0 = blockIdx.y * 128, col0 = blockIdx.x * 64;

    f32x4 acc[4][2];
#pragma unroll
    for (int mi = 0; mi < 4; mi++)
#pragma unroll
        for (int ni = 0; ni < 2; ni++)
#pragma unroll
            for (int r = 0; r < 4; r++) acc[mi][ni][r] = 0.f;

    for (int k0 = 0; k0 < K; k0 += 64) {
#pragma unroll
        for (int j = 0; j < 4; j++) {
            int blkI = wid * 4 + j;
            int cid = blkI * 64 + lane;
            int r = cid >> 3, c = (cid & 7) ^ (r & 7);
            gload16(&Ahi[(size_t)(row0 + r) * K + k0 + c * 8], &As[0][blkI * 512]);
            if constexpr (SPLIT)
                gload16(&Alo[(size_t)(row0 + r) * K + k0 + c * 8], &As[1][blkI * 512]);
        }
#pragma unroll
        for (int j = 0; j < 2; j++) {
            int blkI = wid * 2 + j;
            int cid = blkI * 64 + lane;
            int r = cid >> 3, c = (cid & 7) ^ (r & 7);
            gload16(&Bhi[(size_t)(col0 + r) * K + k0 + c * 8], &Bs[0][blkI * 512]);
            if constexpr (SPLIT)
                gload16(&Blo[(size_t)(col0 + r) * K + k0 + c * 8], &Bs[1][blkI * 512]);
        }
        __syncthreads();
#pragma unroll
        for (int kk = 0; kk < 64; kk += 32) {
            s16x8 ah[4], bh[2];
#pragma unroll
            for (int mi = 0; mi < 4; mi++) ah[mi] = *(const s16x8*)&As[0][swz(wm * 64 + mi * 16 + li, kk + g * 8)];
#pragma unroll
            for (int ni = 0; ni < 2; ni++) bh[ni] = *(const s16x8*)&Bs[0][swz(wn * 32 + ni * 16 + li, kk + g * 8)];
            if constexpr (SPLIT) {
                s16x8 al[4], bl[2];
#pragma unroll
                for (int mi = 0; mi < 4; mi++) al[mi] = *(const s16x8*)&As[1][swz(wm * 64 + mi * 16 + li, kk + g * 8)];
#pragma unroll
                for (int ni = 0; ni < 2; ni++) bl[ni] = *(const s16x8*)&Bs[1][swz(wn * 32 + ni * 16 + li, kk + g * 8)];
#pragma unroll
                for (int mi = 0; mi < 4; mi++)
#pragma unroll
                    for (int ni = 0; ni < 2; ni++) {
                        acc[mi][ni] = __builtin_amdgcn_mfma_f32_16x16x32_bf16(ah[mi], bh[ni], acc[mi][ni], 0, 0, 0);
                        acc[mi][ni] = __builtin_amdgcn_mfma_f32_16x16x32_bf16(al[mi], bh[ni], acc[mi][ni], 0, 0, 0);
                        acc[mi][ni] = __builtin_amdgcn_mfma_f32_16x16x32_bf16(ah[mi], bl[ni], acc[mi][ni], 0, 0, 0);
                    }
            } else {
#pragma unroll
                for (int mi = 0; mi < 4; mi++)
#pragma unroll
                    for (int ni = 0; ni < 2; ni++)
                        acc[mi][ni] = __builtin_amdgcn_mfma_f32_16x16x32_bf16(ah[mi], bh[ni], acc[mi][ni], 0, 0, 0);
            }
        }
        __syncthreads();
    }
#pragma unroll
    for (int mi = 0; mi < 4; mi++)
#pragma unroll
        for (int ni = 0; ni < 2; ni++) {
            int gc = col0 + wn * 32 + ni * 16 + li;
            if (gc < N) {
#pragma unroll
                for (int r = 0; r < 4; r++) {
                    int gr = row0 + wm * 64 + mi * 16 + g * 4 + r;
                    C[(size_t)gr * N + gc] = acc[mi][ni][r];
                }
            }
        }
}

// =====================================================================
// MoE gate+up GEMM + silu epilogue; A rows gathered inline from h2bf via
// sorted_t (gload16 global source is per-lane); B f32->bf16 staged.
// =====================================================================
__global__ __launch_bounds__(256) void moe_gateup(const short* __restrict__ h2bf, const int* __restrict__ sorted_t,
                                                  const float* __restrict__ Wg, const float* __restrict__ Wu,
                                                  const float* __restrict__ Sg, const float* __restrict__ Su,
                                                  short* __restrict__ Cact, const int4* __restrict__ tilemap,
                                                  int K, int N) {
    int4 tm = tilemap[blockIdx.y];
    int nrows = tm.z;
    if (nrows == 0) return;
    const float* Bg = (tm.x < 8) ? Wg + (size_t)tm.x * K * N : Sg;
    const float* Bu = (tm.x < 8) ? Wu + (size_t)tm.x * K * N : Su;

    __shared__ short As[128 * 64];
    alignas(16) __shared__ short Bgs[64][72];
    alignas(16) __shared__ short Bus[64][72];
    const int tid = threadIdx.x;
    const int lane = tid & 63, wid = tid >> 6;
    const int g = lane >> 4, li = lane & 15;
    const int wm = wid >> 1, wn = wid & 1;
    const int col0 = blockIdx.x * 64;

    // per-lane A row token (fixed across K loop)
    int tokens[4];
#pragma unroll
    for (int j = 0; j < 4; j++) {
        int blkI = wid * 4 + j;
        int cid = blkI * 64 + lane;
        int r = cid >> 3;
        int slot = tm.y + r;
        tokens[j] = (slot < 2048) ? sorted_t[slot] : (slot - 2048);
    }

    f32x4 accg[4][2], accu[4][2];
#pragma unroll
    for (int mi = 0; mi < 4; mi++)
#pragma unroll
        for (int ni = 0; ni < 2; ni++)
#pragma unroll
            for (int r = 0; r < 4; r++) { accg[mi][ni][r] = 0.f; accu[mi][ni][r] = 0.f; }

    const int skb = (tid >> 4) << 2, snb = (tid & 15) << 2;

    for (int k0 = 0; k0 < K; k0 += 64) {
#pragma unroll
        for (int j = 0; j < 4; j++) {
            int blkI = wid * 4 + j;
            int cid = blkI * 64 + lane;
            int r = cid >> 3, c = (cid & 7) ^ (r & 7);
            gload16(&h2bf[(size_t)tokens[j] * K + k0 + c * 8], &As[blkI * 512]);
        }
        {
            float4 rg[4], ru[4];
#pragma unroll
            for (int kk = 0; kk < 4; kk++) {
                rg[kk] = *(const float4*)(Bg + (size_t)(k0 + skb + kk) * N + col0 + snb);
                ru[kk] = *(const float4*)(Bu + (size_t)(k0 + skb + kk) * N + col0 + snb);
            }
#pragma unroll
            for (int n = 0; n < 4; n++) {
                s16x4 wg4, wu4;
                wg4[0] = f2bf((&rg[0].x)[n]); wg4[1] = f2bf((&rg[1].x)[n]);
                wg4[2] = f2bf((&rg[2].x)[n]); wg4[3] = f2bf((&rg[3].x)[n]);
                wu4[0] = f2bf((&ru[0].x)[n]); wu4[1] = f2bf((&ru[1].x)[n]);
                wu4[2] = f2bf((&ru[2].x)[n]); wu4[3] = f2bf((&ru[3].x)[n]);
                *(s16x4*)&Bgs[snb + n][skb] = wg4;
                *(s16x4*)&Bus[snb + n][skb] = wu4;
            }
        }
        __syncthreads();
#pragma unroll
        for (int kk = 0; kk < 64; kk += 32) {
            s16x8 a[4], bg2[2], bu2[2];
#pragma unroll
            for (int mi = 0; mi < 4; mi++) a[mi] = *(const s16x8*)&As[swz(wm * 64 + mi * 16 + li, kk + g * 8)];
#pragma unroll
            for (int ni = 0; ni < 2; ni++) {
                bg2[ni] = *(const s16x8*)&Bgs[wn * 32 + ni * 16 + li][kk + g * 8];
                bu2[ni] = *(const s16x8*)&Bus[wn * 32 + ni * 16 + li][kk + g * 8];
            }
#pragma unroll
            for (int mi = 0; mi < 4; mi++)
#pragma unroll
                for (int ni = 0; ni < 2; ni++) {
                    accg[mi][ni] = __builtin_amdgcn_mfma_f32_16x16x32_bf16(a[mi], bg2[ni], accg[mi][ni], 0, 0, 0);
                    accu[mi][ni] = __builtin_amdgcn_mfma_f32_16x16x32_bf16(a[mi], bu2[ni], accu[mi][ni], 0, 0, 0);
                }
        }
        __syncthreads();
    }
#pragma unroll
    for (int mi = 0; mi < 4; mi++)
#pragma unroll
        for (int ni = 0; ni < 2; ni++) {
            int gc = col0 + wn * 32 + ni * 16 + li;
#pragma unroll
            for (int r = 0; r < 4; r++) {
                int gr = wm * 64 + mi * 16 + g * 4 + r;
                if (gr < nrows) {
                    float x = accg[mi][ni][r], u = accu[mi][ni][r];
                    Cact[(size_t)(tm.y + gr) * N + gc] = f2bf((x / (1.f + expf(-x))) * u);
                }
            }
        }
}

// =====================================================================
// MoE down GEMM; A bf16 (mact) via gload16; B f32->bf16 staged; out md f32.
// =====================================================================
__global__ __launch_bounds__(256) void moe_down(const short* __restrict__ Abase, const float* __restrict__ Wall,
                                                const float* __restrict__ Sd, float* __restrict__ Cbase,
                                                const int4* __restrict__ tilemap, int K, int N) {
    int4 tm = tilemap[blockIdx.y];
    int nrows = tm.z;
    if (nrows == 0) return;
    const short* A = Abase + (size_t)tm.y * K;
    float* C = Cbase + (size_t)tm.y * N;
    const float* B = (tm.x < 8) ? Wall + (size_t)tm.x * K * N : Sd;

    __shared__ short As[128 * 64];
    alignas(16) __shared__ short Bs[64][72];
    const int tid = threadIdx.x;
    const int lane = tid & 63, wid = tid >> 6;
    const int g = lane >> 4, li = lane & 15;
    const int wm = wid >> 1, wn = wid & 1;
    const int col0 = blockIdx.x * 64;

    f32x4 acc[4][2];
#pragma unroll
    for (int mi = 0; mi < 4; mi++)
#pragma unroll
        for (int ni = 0; ni < 2; ni++)
#pragma unroll
            for (int r = 0; r < 4; r++) acc[mi][ni][r] = 0.f;

    const int skb = (tid >> 4) << 2, snb = (tid & 15) << 2;

    for (int k0 = 0; k0 < K; k0 += 64) {
#pragma unroll
        for (int j = 0; j < 4; j++) {
            int blkI = wid * 4 + j;
            int cid = blkI * 64 + lane;
            int r = cid >> 3, c = (cid & 7) ^ (r & 7);
            gload16(&A[(size_t)r * K + k0 + c * 8], &As[blkI * 512]);
        }
        {
            float4 r4[4];
#pragma unroll
            for (int kk = 0; kk < 4; kk++)
                r4[kk] = *(const float4*)(B + (size_t)(k0 + skb + kk) * N + col0 + snb);
#pragma unroll
            for (int n = 0; n < 4; n++) {
                s16x4 w;
                w[0] = f2bf((&r4[0].x)[n]); w[1] = f2bf((&r4[1].x)[n]);
                w[2] = f2bf((&r4[2].x)[n]); w[3] = f2bf((&r4[3].x)[n]);
                *(s16x4*)&Bs[snb + n][skb] = w;
            }
        }
        __syncthreads();
#pragma unroll
        for (int kk = 0; kk < 64; kk += 32) {
            s16x8 a[4], b[2];
#pragma unroll
            for (int mi = 0; mi < 4; mi++) a[mi] = *(const s16x8*)&As[swz(wm * 64 + mi * 16 + li, kk + g * 8)];
#pragma unroll
            for (int ni = 0; ni < 2; ni++) b[ni] = *(const s16x8*)&Bs[wn * 32 + ni * 16 + li][kk + g * 8];
#pragma unroll
            for (int mi = 0; mi < 4; mi++)
#pragma unroll
                for (int ni = 0; ni < 2; ni++)
                    acc[mi][ni] = __builtin_amdgcn_mfma_f32_16x16x32_bf16(a[mi], b[ni], acc[mi][ni], 0, 0, 0);
        }
        __syncthreads();
    }
#pragma unroll
    for (int mi = 0; mi < 4; mi++)
#pragma unroll
        for (int ni = 0; ni < 2; ni++) {
            int gc = col0 + wn * 32 + ni * 16 + li;
#pragma unroll
            for (int r = 0; r < 4; r++) {
                int gr = wm * 64 + mi * 16 + g * 4 + r;
                if (gr < nrows) C[(size_t)gr * N + gc] = acc[mi][ni][r];
            }
        }
}

// ---------------- RoPE + build qf/kf/v as split planes ----------------
__global__ void prep_qkv_kernel(const float* __restrict__ q, const float* __restrict__ qkraw,
                                const float* __restrict__ kv, const int* __restrict__ positions,
                                short* __restrict__ qfh, short* __restrict__ qfl,
                                short* __restrict__ kfh, short* __restrict__ kfl,
                                short* __restrict__ vbh, short* __restrict__ vbl) {
    int t = blockIdx.x;
    __shared__ float cs[16], sn[16];
    if (threadIdx.x < 16) {
        float invf = powf(10000.f, -(float)(2 * threadIdx.x) / 32.f);
        float fr = (float)positions[t] * invf;
        cs[threadIdx.x] = cosf(fr);
        sn[threadIdx.x] = sinf(fr);
    }
    __syncthreads();
    for (int i = threadIdx.x; i < NH * QKD; i += blockDim.x) {
        int h = i / QKD, d = i % QKD;
        float val;
        if (d < 64) val = q[(size_t)t * 1536 + h * QKD + d];
        else {
            int r = d - 64, pr = r >> 1;
            float x1 = q[(size_t)t * 1536 + h * QKD + 64 + 2 * pr];
            float x2 = q[(size_t)t * 1536 + h * QKD + 64 + 2 * pr + 1];
            val = (r & 1) ? (x1 * sn[pr] + x2 * cs[pr]) : (x1 * cs[pr] - x2 * sn[pr]);
        }
        short hh = f2bf(val);
        qfh[(size_t)t * 1536 + i] = hh;
        qfl[(size_t)t * 1536 + i] = f2bf(val - bf2f(hh));
    }
    for (int i = threadIdx.x; i < NH * QKD; i += blockDim.x) {
        int h = i / QKD, d = i % QKD;
        float val;
        if (d < 64) val = kv[(size_t)t * 2048 + h * 128 + d];
        else {
            int r = d - 64, pr = r >> 1;
            float x1 = qkraw[(size_t)t * 800 + 768 + 2 * pr];
            float x2 = qkraw[(size_t)t * 800 + 768 + 2 * pr + 1];
            val = (r & 1) ? (x1 * sn[pr] + x2 * cs[pr]) : (x1 * cs[pr] - x2 * sn[pr]);
        }
        short hh = f2bf(val);
        kfh[(size_t)t * 1536 + i] = hh;
        kfl[(size_t)t * 1536 + i] = f2bf(val - bf2f(hh));
    }
    for (int i = threadIdx.x; i < NH * VD; i += blockDim.x) {
        int h = i / VD, d = i % VD;
        float val = kv[(size_t)t * 2048 + h * 128 + 64 + d];
        short hh = f2bf(val);
        vbh[(size_t)t * 1024 + i] = hh;
        vbl[(size_t)t * 1024 + i] = f2bf(val - bf2f(hh));
    }
}

// =====================================================================
// MFMA flash attention (verified; reads/writes bf16 planes)
// =====================================================================
__global__ __launch_bounds__(256) void attn_mfma_kernel(const short* __restrict__ qfh, const short* __restrict__ qfl,
                                                        const short* __restrict__ kfh, const short* __restrict__ kfl,
                                                        const short* __restrict__ vbh, const short* __restrict__ vbl,
                                                        short* __restrict__ obh, short* __restrict__ obl) {
    __shared__ short K_hi[64][104], K_lo[64][104];
    __shared__ short Vt_hi[64][72], Vt_lo[64][72];
    __shared__ short P_hi[4][16][72], P_lo[4][16][72];
    const int qt = blockIdx.x, h = blockIdx.y;
    const int tid = threadIdx.x, lane = tid & 63, w = tid >> 6;
    const int g = lane >> 4, li = lane & 15;

    s16x8 q_hi[3], q_lo[3];
    {
        const short* qb_h = qfh + (size_t)(qt * 64 + w * 16 + li) * 1536 + h * QKD;
        const short* qb_l = qfl + (size_t)(qt * 64 + w * 16 + li) * 1536 + h * QKD;
#pragma unroll
        for (int ks = 0; ks < 3; ks++) {
            q_hi[ks] = *(const s16x8*)(qb_h + ks * 32 + g * 8);
            q_lo[ks] = *(const s16x8*)(qb_l + ks * 32 + g * 8);
        }
    }

    f32x4 acc_o[4];
#pragma unroll
    for (int nc = 0; nc < 4; nc++)
#pragma unroll
        for (int r = 0; r < 4; r++) acc_o[nc][r] = 0.f;
    float m4[4] = {-1e30f, -1e30f, -1e30f, -1e30f};
    float l4[4] = {0.f, 0.f, 0.f, 0.f};
    const float scale = 0.102062072616f;

    for (int kt = 0; kt <= qt; kt++) {
#pragma unroll
        for (int it = 0; it < 3; it++) {
            int cid = it * 256 + tid;
            int key = cid / 12, c = cid % 12;
            *(s16x8*)&K_hi[key][c * 8] = *(const s16x8*)&kfh[(size_t)(kt * 64 + key) * 1536 + h * QKD + c * 8];
            *(s16x8*)&K_lo[key][c * 8] = *(const s16x8*)&kfl[(size_t)(kt * 64 + key) * 1536 + h * QKD + c * 8];
        }
#pragma unroll
        for (int it = 0; it < 2; it++) {
            int cid = it * 256 + tid;
            int key = cid >> 3, vc = cid & 7;
            s16x8 vh = *(const s16x8*)&vbh[(size_t)(kt * 64 + key) * 1024 + h * VD + vc * 8];
            s16x8 vl = *(const s16x8*)&vbl[(size_t)(kt * 64 + key) * 1024 + h * VD + vc * 8];
#pragma unroll
            for (int j = 0; j < 8; j++) {
                Vt_hi[vc * 8 + j][key] = vh[j];
                Vt_lo[vc * 8 + j][key] = vl[j];
            }
        }
        __syncthreads();

        f32x4 acc_s[4];
#pragma unroll
        for (int kc = 0; kc < 4; kc++)
#pragma unroll
            for (int r = 0; r < 4; r++) acc_s[kc][r] = 0.f;
#pragma unroll
        for (int ks = 0; ks < 3; ks++) {
#pragma unroll
            for (int kc = 0; kc < 4; kc++) {
                s16x8 kh = *(const s16x8*)&K_hi[kc * 16 + li][ks * 32 + g * 8];
                s16x8 kl = *(const s16x8*)&K_lo[kc * 16 + li][ks * 32 + g * 8];
                acc_s[kc] = __builtin_amdgcn_mfma_f32_16x16x32_bf16(q_hi[ks], kh, acc_s[kc], 0, 0, 0);
                acc_s[kc] = __builtin_amdgcn_mfma_f32_16x16x32_bf16(q_lo[ks], kh, acc_s[kc], 0, 0, 0);
                acc_s[kc] = __builtin_amdgcn_mfma_f32_16x16x32_bf16(q_hi[ks], kl, acc_s[kc], 0, 0, 0);
            }
        }
#pragma unroll
        for (int kc = 0; kc < 4; kc++)
#pragma unroll
            for (int r = 0; r < 4; r++) acc_s[kc][r] *= scale;
        if (kt == qt) {
#pragma unroll
            for (int kc = 0; kc < 4; kc++) {
                int key = kt * 64 + kc * 16 + li;
#pragma unroll
                for (int r = 0; r < 4; r++) {
                    int qr = qt * 64 + w * 16 + g * 4 + r;
                    if (key > qr) acc_s[kc][r] = -1e30f;
                }
            }
        }
        float tm4[4];
#pragma unroll
        for (int r = 0; r < 4; r++)
            tm4[r] = fmaxf(fmaxf(acc_s[0][r], acc_s[1][r]), fmaxf(acc_s[2][r], acc_s[3][r]));
#pragma unroll
        for (int off = 1; off < 16; off <<= 1)
#pragma unroll
            for (int r = 0; r < 4; r++) tm4[r] = fmaxf(tm4[r], __shfl_xor(tm4[r], off));
        float alpha[4];
#pragma unroll
        for (int r = 0; r < 4; r++) {
            float mn = fmaxf(m4[r], tm4[r]);
            alpha[r] = __expf(m4[r] - mn);
            m4[r] = mn;
        }
        float rs[4] = {0.f, 0.f, 0.f, 0.f};
#pragma unroll
        for (int kc = 0; kc < 4; kc++)
#pragma unroll
            for (int r = 0; r < 4; r++) {
                float p = __expf(acc_s[kc][r] - m4[r]);
                rs[r] += p;
                short hh = f2bf(p);
                P_hi[w][g * 4 + r][kc * 16 + li] = hh;
                P_lo[w][g * 4 + r][kc * 16 + li] = f2bf(p - bf2f(hh));
            }
#pragma unroll
        for (int off = 1; off < 16; off <<= 1)
#pragma unroll
            for (int r = 0; r < 4; r++) rs[r] += __shfl_xor(rs[r], off);
#pragma unroll
        for (int r = 0; r < 4; r++) l4[r] = l4[r] * alpha[r] + rs[r];
#pragma unroll
        for (int nc = 0; nc < 4; nc++)
#pragma unroll
            for (int r = 0; r < 4; r++) acc_o[nc][r] *= alpha[r];
#pragma unroll
        for (int ks = 0; ks < 2; ks++) {
            s16x8 ph = *(const s16x8*)&P_hi[w][li][ks * 32 + g * 8];
            s16x8 pl = *(const s16x8*)&P_lo[w][li][ks * 32 + g * 8];
#pragma unroll
            for (int nc = 0; nc < 4; nc++) {
                s16x8 vh = *(const s16x8*)&Vt_hi[nc * 16 + li][ks * 32 + g * 8];
                s16x8 vl = *(const s16x8*)&Vt_lo[nc * 16 + li][ks * 32 + g * 8];
                acc_o[nc] = __builtin_amdgcn_mfma_f32_16x16x32_bf16(ph, vh, acc_o[nc], 0, 0, 0);
                acc_o[nc] = __builtin_amdgcn_mfma_f32_16x16x32_bf16(pl, vh, acc_o[nc], 0, 0, 0);
                acc_o[nc] = __builtin_amdgcn_mfma_f32_16x16x32_bf16(ph, vl, acc_o[nc], 0, 0, 0);
            }
        }
        __syncthreads();
    }
    float inv[4];
#pragma unroll
    for (int r = 0; r < 4; r++) inv[r] = 1.f / l4[r];
#pragma unroll
    for (int nc = 0; nc < 4; nc++)
#pragma unroll
        for (int r = 0; r < 4; r++) {
            float o = acc_o[nc][r] * inv[r];
            size_t idx = (size_t)(qt * 64 + w * 16 + g * 4 + r) * 1024 + h * VD + nc * 16 + li;
            short hh = f2bf(o);
            obh[idx] = hh;
            obl[idx] = f2bf(o - bf2f(hh));
        }
}

// ---------------- fused resid-add + post-rmsnorm + routing ----------------
__global__ __launch_bounds__(256) void fused_post_attn(float* __restrict__ x0, const float* __restrict__ att,
                                                       const float* __restrict__ w, const float* __restrict__ gate_w,
                                                       const float* __restrict__ gate_bias,
                                                       short* __restrict__ h2bf, int* __restrict__ topidx,
                                                       float* __restrict__ topw) {
    int t = blockIdx.x;
    float resid[8];
    float ss = 0.f;
#pragma unroll
    for (int j = 0; j < 8; j++) {
        int i = threadIdx.x + j * 256;
        float v = x0[(size_t)t * HDIM + i] + att[(size_t)t * HDIM + i];
        resid[j] = v;
        x0[(size_t)t * HDIM + i] = v;
        ss += v * v;
    }
    float r = rsqrtf(block_sum(ss) / HDIM + EPSF);
    float acc[8] = {0.f, 0.f, 0.f, 0.f, 0.f, 0.f, 0.f, 0.f};
#pragma unroll
    for (int j = 0; j < 8; j++) {
        int i = threadIdx.x + j * 256;
        float v = resid[j] * r * w[i];
        h2bf[(size_t)t * HDIM + i] = f2bf(v);
        const float* gw = gate_w + (size_t)i * 8;
        float4 g0 = *(const float4*)gw;
        float4 g1 = *(const float4*)(gw + 4);
        acc[0] = fmaf(v, g0.x, acc[0]); acc[1] = fmaf(v, g0.y, acc[1]);
        acc[2] = fmaf(v, g0.z, acc[2]); acc[3] = fmaf(v, g0.w, acc[3]);
        acc[4] = fmaf(v, g1.x, acc[4]); acc[5] = fmaf(v, g1.y, acc[5]);
        acc[6] = fmaf(v, g1.z, acc[6]); acc[7] = fmaf(v, g1.w, acc[7]);
    }
    __shared__ float logits[8];
    for (int e = 0; e < 8; e++) {
        float s = block_sum(acc[e]);
        if (threadIdx.x == 0) logits[e] = s;
    }
    __syncthreads();
    if (threadIdx.x == 0) {
        float sig[8], sc[8];
        for (int e = 0; e < 8; e++) {
            sig[e] = 1.f / (1.f + expf(-logits[e]));
            sc[e] = sig[e] + gate_bias[e];
        }
        int i0 = 0;
        for (int e = 1; e < 8; e++) if (sc[e] > sc[i0]) i0 = e;
        int i1 = -1;
        for (int e = 0; e < 8; e++) if (e != i0 && (i1 < 0 || sc[e] > sc[i1])) i1 = e;
        float w0 = sig[i0], w1 = sig[i1], s = w0 + w1 + 1e-20f;
        topidx[t * 2 + 0] = i0; topidx[t * 2 + 1] = i1;
        topw[t * 2 + 0] = w0 / s; topw[t * 2 + 1] = w1 / s;
    }
}

// ---------------- counting sort + tile map (+8 shared tiles) ----------------
__global__ void sort_kernel(const int* __restrict__ topidx, int* __restrict__ sorted_t,
                            int* __restrict__ slotpos, int4* __restrict__ tilemap) {
    __shared__ int counts[8], offs[9];
    int wid = threadIdx.x >> 6, lane = threadIdx.x & 63;
    int cnt = 0;
    for (int base = 0; base < 2 * T_; base += 64) {
        int e = topidx[base + lane];
        unsigned long long m = __ballot(e == wid);
        cnt += __popcll(m);
    }
    if (lane == 0) counts[wid] = cnt;
    __syncthreads();
    if (threadIdx.x == 0) {
        offs[0] = 0;
        for (int e = 0; e < 8; e++) offs[e + 1] = offs[e] + counts[e];
    }
    __syncthreads();
    int pos = offs[wid];
    for (int base = 0; base < 2 * T_; base += 64) {
        int sl = base + lane;
        int e = topidx[sl];
        bool match = (e == wid);
        unsigned long long m = __ballot(match);
        if (match) {
            int before = __popcll(m & ((1ull << lane) - 1ull));
            int pp = pos + before;
            sorted_t[pp] = sl >> 1;
            slotpos[sl] = pp;
        }
        pos += __popcll(m);
    }
    __syncthreads();
    if (threadIdx.x == 0) {
        int nt = 0;
        for (int e = 0; e < 8; e++) {
            int c = counts[e], o = offs[e];
            for (int r = 0; r < c; r += 128) {
                tilemap[nt] = make_int4(e, o + r, min(128, c - r), 0);
                nt++;
            }
        }
        for (int r = 0; r < 8; r++) {
            tilemap[nt] = make_int4(8, 2048 + r * 128, 128, 0);
            nt++;
        }
        for (int i = nt; i < MAXTILES; i++) tilemap[i] = make_int4(0, 0, 0, 0);
    }
}

// ---------------- final combine -> f32 out ----------------
__global__ void final_kernel(const float* __restrict__ resid, const float* __restrict__ md,
                             const int* __restrict__ slotpos, const float* __restrict__ topw,
                             float* __restrict__ out) {
    int t = blockIdx.x;
    int p0 = slotpos[t * 2 + 0], p1 = slotpos[t * 2 + 1];
    float w0 = topw[t * 2 + 0] * 2.5f, w1 = topw[t * 2 + 1] * 2.5f;
    const float* mds = md + (size_t)(2048 + t) * HDIM;
    for (int c = threadIdx.x; c < HDIM; c += blockDim.x) {
        float v = resid[(size_t)t * HDIM + c] + mds[c]
                + w0 * md[(size_t)p0 * HDIM + c] + w1 * md[(size_t)p1 * HDIM + c];
        out[(size_t)t * HDIM + c] = v;
    }
}

// ---------------- launcher ----------------
extern "C" void kernel_launch(void* const* d_in, const int* in_sizes, int n_in,
                              void* d_out, int out_size, void* d_ws, size_t ws_size,
                              hipStream_t stream) {
    (void)in_sizes; (void)n_in; (void)out_size; (void)ws_size;
    const int*   input_ids = (const int*)d_in[0];
    const int*   positions = (const int*)d_in[1];
    const float* prev      = (const float*)d_in[2];
    const float* embed     = (const float*)d_in[3];
    const float* enorm_w   = (const float*)d_in[4];
    const float* hnorm_w   = (const float*)d_in[5];
    const float* eh_proj_w = (const float*)d_in[6];
    const float* in_ln_w   = (const float*)d_in[7];
    const float* post_ln_w = (const float*)d_in[8];
    const float* q_a_w     = (const float*)d_in[9];
    const float* q_a_ln_w  = (const float*)d_in[10];
    const float* q_b_w     = (const float*)d_in[11];
    const float* kv_a_w    = (const float*)d_in[12];
    const float* kv_a_ln_w = (const float*)d_in[13];
    const float* kv_b_w    = (const float*)d_in[14];
    const float* o_w       = (const float*)d_in[15];
    const float* gate_w    = (const float*)d_in[16];
    const float* gate_bias = (const float*)d_in[17];
    const float* exp_g     = (const float*)d_in[18];
    const float* exp_u     = (const float*)d_in[19];
    const float* exp_d     = (const float*)d_in[20];
    const float* sh_g      = (const float*)d_in[21];
    const float* sh_u      = (const float*)d_in[22];
    const float* sh_d      = (const float*)d_in[23];
    float* out = (float*)d_out;

    float* ws = (float*)d_ws;
    short* catH  = (short*)(ws + OF_CATH);
    short* catL  = (short*)(ws + OF_CATL);
    float* x0    = ws + OF_X0;
    short* mact  = (short*)(ws + OF_MACT);
    short* hH    = (short*)(ws + OF_HH);
    short* hL    = (short*)(ws + OF_HL);
    float* qbuf  = ws + OF_QBUF;
    float* kvbuf = ws + OF_KVBUF;
    short* qaH   = (short*)(ws + OF_QAH);
    short* qaL   = (short*)(ws + OF_QAL);
    short* kvcnH = (short*)(ws + OF_KVCNH);
    short* kvcnL = (short*)(ws + OF_KVCNL);
    short* qfH   = (short*)(ws + OF_QFH);
    short* qfL   = (short*)(ws + OF_QFL);
    short* kfH   = (short*)(ws + OF_KFH);
    short* kfL   = (short*)(ws + OF_KFL);
    short* vbH   = (short*)(ws + OF_VBH);
    short* vbL   = (short*)(ws + OF_VBL);
    short* obH   = (short*)(ws + OF_OBH);
    short* obL   = (short*)(ws + OF_OBL);
    float* att   = ws + OF_ATT;
    short* h2bf  = (short*)(ws + OF_H2BF);
    float* md    = ws + OF_MD;
    float* qkraw = ws + OF_QKRAW;
    short* batH  = (short*)(ws + OF_BATH);
    short* batL  = (short*)(ws + OF_BATL);
    int*   ri       = (int*)(ws + OF_ROUT);
    int*   topidx   = ri;
    int*   sorted_t = ri + 2048;
    int*   slotpos  = ri + 4096;
    int4*  tilemap  = (int4*)(ri + 6144);
    float* topw     = (float*)(ri + 6144 + 4 * MAXTILES);
    short* ehTH  = (short*)(ws + OF_EHTH);
    short* ehTL  = (short*)(ws + OF_EHTL);
    short* qbTH  = (short*)(ws + OF_QBTH);
    short* qbTL  = (short*)(ws + OF_QBTL);
    short* kvbTH = (short*)(ws + OF_KVBTH);
    short* kvbTL = (short*)(ws + OF_KVBTL);
    short* owTH  = (short*)(ws + OF_OWTH);
    short* owTL  = (short*)(ws + OF_OWTL);

    dim3 blk(256);

    // 0. one-launch weight transpose+split (6 jobs)
    TJobs J;
    J.W[0] = eh_proj_w; J.Whi[0] = ehTH; J.Wlo[0] = ehTL; J.K[0] = 4096; J.N[0] = 2048; J.nbx[0] = 64;
    J.W[1] = q_a_w; J.Whi[1] = batH; J.Wlo[1] = batL; J.K[1] = 2048; J.N[1] = 512; J.nbx[1] = 32;
    J.W[2] = kv_a_w; J.Whi[2] = batH + (size_t)512 * 2048; J.Wlo[2] = batL + (size_t)512 * 2048;
    J.K[2] = 2048; J.N[2] = 288; J.nbx[2] = 32;
    J.W[3] = q_b_w; J.Whi[3] = qbTH; J.Wlo[3] = qbTL; J.K[3] = 512; J.N[3] = 1536; J.nbx[3] = 8;
    J.W[4] = kv_b_w; J.Whi[4] = kvbTH; J.Wlo[4] = kvbTL; J.K[4] = 256; J.N[4] = 2048; J.nbx[4] = 4;
    J.W[5] = o_w; J.Whi[5] = owTH; J.Wlo[5] = owTL; J.K[5] = 1024; J.N[5] = 2048; J.nbx[5] = 16;
    int nby[6] = {32, 8, 5, 24, 32, 32};
    J.base[0] = 0;
    for (int i = 0; i < 6; i++) J.base[i + 1] = J.base[i] + J.nbx[i] * nby[i];
    transpose_multi_kernel<<<J.base[6], blk, 0, stream>>>(J);

    // 1. embed + rmsnorm + concat
    embed_cat_kernel<<<T_, blk, 0, stream>>>(input_ids, embed, enorm_w, prev, hnorm_w, catH, catL);
    // 2. x0 = cat @ eh_proj
    gemm_planes<true><<<dim3(32, 8), blk, 0, stream>>>(catH, catL, ehTH, ehTL, x0, T_, 2048, 4096);
    // 3. h = rmsnorm(x0)
    rmsnorm_kernel<<<T_, blk, 0, stream>>>(x0, 2048, 2048, in_ln_w, nullptr, hH, hL, 2048);
    // 4. qkraw = h @ [q_a | kv_a]  (N=800)
    gemm_planes<true><<<dim3(13, 8), blk, 0, stream>>>(hH, hL, batH, batL, qkraw, T_, 800, 2048);
    // 5. fused rmsnorms (q_a_ln + kv_a_ln)
    rmsnorm_qkv_kernel<<<T_, blk, 0, stream>>>(qkraw, q_a_ln_w, kv_a_ln_w, qaH, qaL, kvcnH, kvcnL);
    // 6. q = qa @ q_b
    gemm_planes<true><<<dim3(24, 8), blk, 0, stream>>>(qaH, qaL, qbTH, qbTL, qbuf, T_, 1536, 512);
    // 7. kv = kvcn @ kv_b
    gemm_planes<true><<<dim3(32, 8), blk, 0, stream>>>(kvcnH, kvcnL, kvbTH, kvbTL, kvbuf, T_, 2048, 256);
    // 8. rope + planes (k_pe from qkraw cols 768-799)
    prep_qkv_kernel<<<T_, blk, 0, stream>>>(qbuf, qkraw, kvbuf, positions, qfH, qfL, kfH, kfL, vbH, vbL);
    // 9. flash attention
    attn_mfma_kernel<<<dim3(T_ / 64, NH), blk, 0, stream>>>(qfH, qfL, kfH, kfL, vbH, vbL, obH, obL);
    // 10. attn_out = ob @ o_w
    gemm_planes<true><<<dim3(32, 8), blk, 0, stream>>>(obH, obL, owTH, owTL, att, T_, 2048, 1024);
    // 11. fused resid + rmsnorm + routing
    fused_post_attn<<<T_, blk, 0, stream>>>(x0, att, post_ln_w, gate_w, gate_bias, h2bf, topidx, topw);
    // 12. sort (+shared tiles)
    sort_kernel<<<1, 512, 0, stream>>>(topidx, sorted_t, slotpos, tilemap);
    // 13. MoE gate+up fused with silu -> mact (inline gather via sorted_t)
    moe_gateup<<<dim3(16, MAXTILES), blk, 0, stream>>>(h2bf, sorted_t, exp_g, exp_u, sh_g, sh_u, mact, tilemap, 2048, 1024);
    // 14. MoE down (experts + shared)
    moe_down<<<dim3(32, MAXTILES), blk, 0, stream>>>(mact, exp_d, sh_d, md, tilemap, 1024, 2048);
    // 15. final combine
    final_kernel<<<T_, blk, 0, stream>>>(x0, md, slotpos, topw, out);
}

// Round 15
// 516.803 us; speedup vs baseline: 1.4483x; 1.0424x over previous
//
#include <hip/hip_runtime.h>
#include <hip/hip_bf16.h>
#include <math.h>

constexpr int T_ = 1024;
constexpr int HDIM = 2048;
constexpr int NH = 16;
constexpr int QKD = 96;
constexpr int VD = 64;
constexpr int MAXTILES = 32;   // <=~15 expert 256-tiles + 4 shared tiles
constexpr float EPSF = 1e-6f;

using f32x4 = __attribute__((ext_vector_type(4))) float;
using s16x8 = __attribute__((ext_vector_type(8))) short;
using s16x4 = __attribute__((ext_vector_type(4))) short;

// ---------------- workspace layout (float offsets; ws is ~1 GB) ----------------
constexpr size_t OF_CATH  = 0;                 // bf16 T*4096
constexpr size_t OF_CATL  = 2097152;
constexpr size_t OF_X0    = 4194304;           // f32 T*2048
constexpr size_t OF_MACT  = 6291456;           // bf16 3072*1024
constexpr size_t OF_HH    = 8388608;           // bf16 T*2048
constexpr size_t OF_HL    = 9437184;
constexpr size_t OF_QBUF  = 11010048;          // f32 T*1536
constexpr size_t OF_KVBUF = 12877824;          // f32 T*2048
constexpr size_t OF_QAH   = 14974976;          // bf16 T*512
constexpr size_t OF_QAL   = 15237120;
constexpr size_t OF_KVCNH = 15499264;          // bf16 T*256
constexpr size_t OF_KVCNL = 15630336;
constexpr size_t OF_QFH   = 15761408;          // bf16 T*1536
constexpr size_t OF_QFL   = 16547840;
constexpr size_t OF_KFH   = 17334272;
constexpr size_t OF_KFL   = 18120704;
constexpr size_t OF_VBH   = 18907136;          // bf16 T*1024
constexpr size_t OF_VBL   = 19431424;
constexpr size_t OF_OBH   = 19955712;          // bf16 T*1024
constexpr size_t OF_OBL   = 20480000;
constexpr size_t OF_ATT   = 21004288;          // f32 T*2048
constexpr size_t OF_H2BF  = 23101440;          // bf16 T*2048
constexpr size_t OF_ROUT  = 24674304;          // ints
// weight planes (bf16)
constexpr size_t OF_EHTH  = 24682752;          // [2048][4096]
constexpr size_t OF_EHTL  = 28877056;
constexpr size_t OF_QBTH  = 34119936;          // [1536][512]
constexpr size_t OF_QBTL  = 34513152;
constexpr size_t OF_KVBTH = 35561728;          // [2048][256]
constexpr size_t OF_KVBTL = 35823872;
constexpr size_t OF_OWTH  = 36086016;          // [2048][1024]
constexpr size_t OF_OWTL  = 37134592;
constexpr size_t OF_MD    = 38183168;          // f32 3072*2048  (ends 44474624)
constexpr size_t OF_QKRAW = 44474624;          // f32 [1024][800] (ends 45293824)
constexpr size_t OF_BATH  = 45293824;          // bf16 [832][2048] = 851968 floats (ends 46145792)
constexpr size_t OF_BATL  = 46145792;          // bf16 [832][2048] (ends 46997760)

// ---------------- helpers ----------------
__device__ __forceinline__ short f2bf(float f) {
    union { float f; unsigned u; } x; x.f = f;
    unsigned r = x.u + 0x7fffu + ((x.u >> 16) & 1u);
    return (short)(r >> 16);
}
__device__ __forceinline__ float bf2f(short h) {
    union { unsigned u; float f; } x; x.u = ((unsigned)(unsigned short)h) << 16; return x.f;
}
// LDS swizzle (plane GEMM): row stride 64 shorts; chunk ^= row&7
__device__ __forceinline__ int swz(int r, int k) {
    return (r << 6) + ((((k >> 3) ^ (r & 7)) << 3) | (k & 7));
}
// async global->LDS, 16 B per lane; LDS dest = wave-uniform base + lane*16
__device__ __forceinline__ void gload16(const void* g, void* l) {
    __builtin_amdgcn_global_load_lds((__attribute__((address_space(1))) void*)g,
                                     (__attribute__((address_space(3))) void*)l, 16, 0, 0);
}

__device__ __forceinline__ float block_sum(float v) {
    __shared__ float sbuf[9];
    int lane = threadIdx.x & 63;
    int wid  = threadIdx.x >> 6;
#pragma unroll
    for (int off = 32; off > 0; off >>= 1) v += __shfl_down(v, off);
    __syncthreads();
    if (lane == 0) sbuf[wid] = v;
    __syncthreads();
    if (threadIdx.x == 0) {
        float s = 0.f;
        int nw = blockDim.x >> 6;
        for (int i = 0; i < nw; i++) s += sbuf[i];
        sbuf[8] = s;
    }
    __syncthreads();
    return sbuf[8];
}

// ---------------- multi-job weight transpose + split ----------------
struct TJobs {
    const float* W[6];
    short* Whi[6];
    short* Wlo[6];
    int K[6];
    int N[6];
    int nbx[6];
    int base[7];
};

__global__ void transpose_multi_kernel(TJobs J) {
    int bid = blockIdx.x;
    int j = 0;
#pragma unroll
    for (int i = 1; i < 6; i++) if (bid >= J.base[i]) j = i;
    int local = bid - J.base[j];
    int K = J.K[j], N = J.N[j];
    int bx = local % J.nbx[j], by = local / J.nbx[j];
    const float* W = J.W[j];
    short* Whi = J.Whi[j];
    short* Wlo = J.Wlo[j];

    __shared__ float tile[64][65];
    int k0 = bx * 64, n0 = by * 64;
    int tn = threadIdx.x & 63;
    int tk4 = threadIdx.x >> 6;
#pragma unroll 4
    for (int i = 0; i < 16; i++) {
        int kk = tk4 * 16 + i;
        int gn = n0 + tn;
        tile[kk][tn] = (gn < N) ? W[(size_t)(k0 + kk) * N + gn] : 0.f;
    }
    __syncthreads();
    int on = threadIdx.x >> 2;
    int oc = threadIdx.x & 3;
#pragma unroll 4
    for (int i = 0; i < 16; i++) {
        int kk = oc * 16 + i;
        float v = tile[kk][on];
        short hh = f2bf(v);
        size_t o = (size_t)(n0 + on) * K + k0 + kk;
        Whi[o] = hh;
        Wlo[o] = f2bf(v - bf2f(hh));
    }
}

// ---------------- embedding + rmsnorm + concat -> split planes ----------------
__global__ void embed_cat_kernel(const int* __restrict__ ids, const float* __restrict__ embed,
                                 const float* __restrict__ enorm, const float* __restrict__ prev,
                                 const float* __restrict__ hnorm, short* __restrict__ ch,
                                 short* __restrict__ cl) {
    int t = blockIdx.x;
    const float* e = embed + (size_t)ids[t] * HDIM;
    float ss = 0.f;
    for (int i = threadIdx.x; i < HDIM; i += blockDim.x) { float v = e[i]; ss += v * v; }
    float r = rsqrtf(block_sum(ss) / HDIM + EPSF);
    for (int i = threadIdx.x; i < HDIM; i += blockDim.x) {
        float v = e[i] * r * enorm[i];
        short hh = f2bf(v);
        ch[(size_t)t * 4096 + i] = hh;
        cl[(size_t)t * 4096 + i] = f2bf(v - bf2f(hh));
    }
    const float* p = prev + (size_t)t * HDIM;
    ss = 0.f;
    for (int i = threadIdx.x; i < HDIM; i += blockDim.x) { float v = p[i]; ss += v * v; }
    r = rsqrtf(block_sum(ss) / HDIM + EPSF);
    for (int i = threadIdx.x; i < HDIM; i += blockDim.x) {
        float v = p[i] * r * hnorm[i];
        short hh = f2bf(v);
        ch[(size_t)t * 4096 + 2048 + i] = hh;
        cl[(size_t)t * 4096 + 2048 + i] = f2bf(v - bf2f(hh));
    }
}

// ---------------- rmsnorm (f32 / hi / lo outputs) ----------------
__global__ void rmsnorm_kernel(const float* __restrict__ in, int in_stride, int width,
                               const float* __restrict__ w, float* __restrict__ outf,
                               short* __restrict__ outh, short* __restrict__ outl, int out_stride) {
    int t = blockIdx.x;
    const float* x = in + (size_t)t * in_stride;
    float ss = 0.f;
    for (int i = threadIdx.x; i < width; i += blockDim.x) { float v = x[i]; ss += v * v; }
    float r = rsqrtf(block_sum(ss) / width + EPSF);
    size_t ob = (size_t)t * out_stride;
    for (int i = threadIdx.x; i < width; i += blockDim.x) {
        float v = x[i] * r * w[i];
        if (outf) outf[ob + i] = v;
        if (outh) {
            short hh = f2bf(v);
            outh[ob + i] = hh;
            if (outl) outl[ob + i] = f2bf(v - bf2f(hh));
        }
    }
}

// ---------------- fused rmsnorm for qkraw: q_a (cols 0-511) + kv_c (cols 512-767) ----------------
__global__ void rmsnorm_qkv_kernel(const float* __restrict__ qkraw, const float* __restrict__ wq,
                                   const float* __restrict__ wkv, short* __restrict__ qaH,
                                   short* __restrict__ qaL, short* __restrict__ kvcnH,
                                   short* __restrict__ kvcnL) {
    int t = blockIdx.x;
    const float* row = qkraw + (size_t)t * 800;
    float ss = 0.f;
    for (int i = threadIdx.x; i < 512; i += blockDim.x) { float v = row[i]; ss += v * v; }
    float r = rsqrtf(block_sum(ss) / 512.f + EPSF);
    for (int i = threadIdx.x; i < 512; i += blockDim.x) {
        float v = row[i] * r * wq[i];
        short hh = f2bf(v);
        qaH[(size_t)t * 512 + i] = hh;
        qaL[(size_t)t * 512 + i] = f2bf(v - bf2f(hh));
    }
    ss = 0.f;
    for (int i = threadIdx.x; i < 256; i += blockDim.x) { float v = row[512 + i]; ss += v * v; }
    r = rsqrtf(block_sum(ss) / 256.f + EPSF);
    for (int i = threadIdx.x; i < 256; i += blockDim.x) {
        float v = row[512 + i] * r * wkv[i];
        short hh = f2bf(v);
        kvcnH[(size_t)t * 256 + i] = hh;
        kvcnL[(size_t)t * 256 + i] = f2bf(v - bf2f(hh));
    }
}

// =====================================================================
// Plane GEMM (verified): BM=128 BN=64 BK=64, gload16 staging
// with inverse-swizzled global source, swizzled LDS reads.
// =====================================================================
template<bool SPLIT>
__global__ __launch_bounds__(256) void gemm_planes(const short* __restrict__ Ahi, const short* __restrict__ Alo,
                                                   const short* __restrict__ Bhi, const short* __restrict__ Blo,
                                                   float* __restrict__ C, int M, int N, int K) {
    __shared__ short As[SPLIT ? 2 : 1][128 * 64];
    __shared__ short Bs[SPLIT ? 2 : 1][64 * 64];
    const int tid = threadIdx.x;
    const int lane = tid & 63, wid = tid >> 6;
    const int g = lane >> 4, li = lane & 15;
    const int wm = wid >> 1, wn = wid & 1;
    const int row0 = blockIdx.y * 128, col0 = blockIdx.x * 64;

    f32x4 acc[4][2];
#pragma unroll
    for (int mi = 0; mi < 4; mi++)
#pragma unroll
        for (int ni = 0; ni < 2; ni++)
#pragma unroll
            for (int r = 0; r < 4; r++) acc[mi][ni][r] = 0.f;

    for (int k0 = 0; k0 < K; k0 += 64) {
#pragma unroll
        for (int j = 0; j < 4; j++) {
            int blkI = wid * 4 + j;
            int cid = blkI * 64 + lane;
            int r = cid >> 3, c = (cid & 7) ^ (r & 7);
            gload16(&Ahi[(size_t)(row0 + r) * K + k0 + c * 8], &As[0][blkI * 512]);
            if constexpr (SPLIT)
                gload16(&Alo[(size_t)(row0 + r) * K + k0 + c * 8], &As[1][blkI * 512]);
        }
#pragma unroll
        for (int j = 0; j < 2; j++) {
            int blkI = wid * 2 + j;
            int cid = blkI * 64 + lane;
            int r = cid >> 3, c = (cid & 7) ^ (r & 7);
            gload16(&Bhi[(size_t)(col0 + r) * K + k0 + c * 8], &Bs[0][blkI * 512]);
            if constexpr (SPLIT)
                gload16(&Blo[(size_t)(col0 + r) * K + k0 + c * 8], &Bs[1][blkI * 512]);
        }
        __syncthreads();
#pragma unroll
        for (int kk = 0; kk < 64; kk += 32) {
            s16x8 ah[4], bh[2];
#pragma unroll
            for (int mi = 0; mi < 4; mi++) ah[mi] = *(const s16x8*)&As[0][swz(wm * 64 + mi * 16 + li, kk + g * 8)];
#pragma unroll
            for (int ni = 0; ni < 2; ni++) bh[ni] = *(const s16x8*)&Bs[0][swz(wn * 32 + ni * 16 + li, kk + g * 8)];
            if constexpr (SPLIT) {
                s16x8 al[4], bl[2];
#pragma unroll
                for (int mi = 0; mi < 4; mi++) al[mi] = *(const s16x8*)&As[1][swz(wm * 64 + mi * 16 + li, kk + g * 8)];
#pragma unroll
                for (int ni = 0; ni < 2; ni++) bl[ni] = *(const s16x8*)&Bs[1][swz(wn * 32 + ni * 16 + li, kk + g * 8)];
#pragma unroll
                for (int mi = 0; mi < 4; mi++)
#pragma unroll
                    for (int ni = 0; ni < 2; ni++) {
                        acc[mi][ni] = __builtin_amdgcn_mfma_f32_16x16x32_bf16(ah[mi], bh[ni], acc[mi][ni], 0, 0, 0);
                        acc[mi][ni] = __builtin_amdgcn_mfma_f32_16x16x32_bf16(al[mi], bh[ni], acc[mi][ni], 0, 0, 0);
                        acc[mi][ni] = __builtin_amdgcn_mfma_f32_16x16x32_bf16(ah[mi], bl[ni], acc[mi][ni], 0, 0, 0);
                    }
            } else {
#pragma unroll
                for (int mi = 0; mi < 4; mi++)
#pragma unroll
                    for (int ni = 0; ni < 2; ni++)
                        acc[mi][ni] = __builtin_amdgcn_mfma_f32_16x16x32_bf16(ah[mi], bh[ni], acc[mi][ni], 0, 0, 0);
            }
        }
        __syncthreads();
    }
#pragma unroll
    for (int mi = 0; mi < 4; mi++)
#pragma unroll
        for (int ni = 0; ni < 2; ni++) {
            int gc = col0 + wn * 32 + ni * 16 + li;
            if (gc < N) {
#pragma unroll
                for (int r = 0; r < 4; r++) {
                    int gr = row0 + wm * 64 + mi * 16 + g * 4 + r;
                    C[(size_t)gr * N + gc] = acc[mi][ni][r];
                }
            }
        }
}

// =====================================================================
// MoE gate+up GEMM + silu epilogue; BM=256, 512 threads (8 waves 4m x 2n).
// A rows gathered inline from h2bf via sorted_t; B f32->bf16 staged
// (threads <256 stage Wg, threads >=256 stage Wu with identical map).
// =====================================================================
__global__ __launch_bounds__(512) void moe_gateup(const short* __restrict__ h2bf, const int* __restrict__ sorted_t,
                                                  const float* __restrict__ Wg, const float* __restrict__ Wu,
                                                  const float* __restrict__ Sg, const float* __restrict__ Su,
                                                  short* __restrict__ Cact, const int4* __restrict__ tilemap,
                                                  int K, int N) {
    int4 tm = tilemap[blockIdx.y];
    int nrows = tm.z;
    if (nrows == 0) return;
    const float* Bg = (tm.x < 8) ? Wg + (size_t)tm.x * K * N : Sg;
    const float* Bu = (tm.x < 8) ? Wu + (size_t)tm.x * K * N : Su;

    __shared__ short As[256 * 64];
    alignas(16) __shared__ short Bgs[64][72];
    alignas(16) __shared__ short Bus[64][72];
    const int tid = threadIdx.x;
    const int lane = tid & 63, wid = tid >> 6;   // wid 0..7
    const int g = lane >> 4, li = lane & 15;
    const int wm = wid >> 1, wn = wid & 1;       // 4m x 2n wave grid
    const int col0 = blockIdx.x * 64;

    // per-lane A row token (fixed across K loop)
    int tokens[4];
#pragma unroll
    for (int j = 0; j < 4; j++) {
        int blkI = wid * 4 + j;                  // 0..31
        int cid = blkI * 64 + lane;              // 0..2047
        int r = cid >> 3;                        // 0..255
        int slot = tm.y + r;
        tokens[j] = (slot < 2048) ? sorted_t[slot] : (slot - 2048);
    }

    f32x4 accg[4][2], accu[4][2];
#pragma unroll
    for (int mi = 0; mi < 4; mi++)
#pragma unroll
        for (int ni = 0; ni < 2; ni++)
#pragma unroll
            for (int r = 0; r < 4; r++) { accg[mi][ni][r] = 0.f; accu[mi][ni][r] = 0.f; }

    const int t2 = tid & 255;
    const int skb = (t2 >> 4) << 2, snb = (t2 & 15) << 2;

    for (int k0 = 0; k0 < K; k0 += 64) {
        // stage A (256 rows): 2048 chunks, 4/thread
#pragma unroll
        for (int j = 0; j < 4; j++) {
            int blkI = wid * 4 + j;
            int cid = blkI * 64 + lane;
            int r = cid >> 3, c = (cid & 7) ^ (r & 7);
            gload16(&h2bf[(size_t)tokens[j] * K + k0 + c * 8], &As[blkI * 512]);
        }
        // stage B: first half-block -> Wg, second half-block -> Wu
        {
            const float* B = (tid < 256) ? Bg : Bu;
            short (*Bst)[72] = (tid < 256) ? Bgs : Bus;
            float4 r4[4];
#pragma unroll
            for (int kk = 0; kk < 4; kk++)
                r4[kk] = *(const float4*)(B + (size_t)(k0 + skb + kk) * N + col0 + snb);
#pragma unroll
            for (int n = 0; n < 4; n++) {
                s16x4 w4;
                w4[0] = f2bf((&r4[0].x)[n]); w4[1] = f2bf((&r4[1].x)[n]);
                w4[2] = f2bf((&r4[2].x)[n]); w4[3] = f2bf((&r4[3].x)[n]);
                *(s16x4*)&Bst[snb + n][skb] = w4;
            }
        }
        __syncthreads();
#pragma unroll
        for (int kk = 0; kk < 64; kk += 32) {
            s16x8 a[4], bg2[2], bu2[2];
#pragma unroll
            for (int mi = 0; mi < 4; mi++) a[mi] = *(const s16x8*)&As[swz(wm * 64 + mi * 16 + li, kk + g * 8)];
#pragma unroll
            for (int ni = 0; ni < 2; ni++) {
                bg2[ni] = *(const s16x8*)&Bgs[wn * 32 + ni * 16 + li][kk + g * 8];
                bu2[ni] = *(const s16x8*)&Bus[wn * 32 + ni * 16 + li][kk + g * 8];
            }
#pragma unroll
            for (int mi = 0; mi < 4; mi++)
#pragma unroll
                for (int ni = 0; ni < 2; ni++) {
                    accg[mi][ni] = __builtin_amdgcn_mfma_f32_16x16x32_bf16(a[mi], bg2[ni], accg[mi][ni], 0, 0, 0);
                    accu[mi][ni] = __builtin_amdgcn_mfma_f32_16x16x32_bf16(a[mi], bu2[ni], accu[mi][ni], 0, 0, 0);
                }
        }
        __syncthreads();
    }
#pragma unroll
    for (int mi = 0; mi < 4; mi++)
#pragma unroll
        for (int ni = 0; ni < 2; ni++) {
            int gc = col0 + wn * 32 + ni * 16 + li;
#pragma unroll
            for (int r = 0; r < 4; r++) {
                int gr = wm * 64 + mi * 16 + g * 4 + r;
                if (gr < nrows) {
                    float x = accg[mi][ni][r], u = accu[mi][ni][r];
                    Cact[(size_t)(tm.y + gr) * N + gc] = f2bf((x / (1.f + expf(-x))) * u);
                }
            }
        }
}

// =====================================================================
// MoE down GEMM; BM=256, 512 threads; A bf16 (mact) via gload16;
// B f32->bf16 staged by threads <256; out md f32.
// =====================================================================
__global__ __launch_bounds__(512) void moe_down(const short* __restrict__ Abase, const float* __restrict__ Wall,
                                                const float* __restrict__ Sd, float* __restrict__ Cbase,
                                                const int4* __restrict__ tilemap, int K, int N) {
    int4 tm = tilemap[blockIdx.y];
    int nrows = tm.z;
    if (nrows == 0) return;
    const short* A = Abase + (size_t)tm.y * K;
    float* C = Cbase + (size_t)tm.y * N;
    const float* B = (tm.x < 8) ? Wall + (size_t)tm.x * K * N : Sd;

    __shared__ short As[256 * 64];
    alignas(16) __shared__ short Bs[64][72];
    const int tid = threadIdx.x;
    const int lane = tid & 63, wid = tid >> 6;
    const int g = lane >> 4, li = lane & 15;
    const int wm = wid >> 1, wn = wid & 1;
    const int col0 = blockIdx.x * 64;

    f32x4 acc[4][2];
#pragma unroll
    for (int mi = 0; mi < 4; mi++)
#pragma unroll
        for (int ni = 0; ni < 2; ni++)
#pragma unroll
            for (int r = 0; r < 4; r++) acc[mi][ni][r] = 0.f;

    const int skb = (tid >> 4) << 2, snb = (tid & 15) << 2;

    for (int k0 = 0; k0 < K; k0 += 64) {
#pragma unroll
        for (int j = 0; j < 4; j++) {
            int blkI = wid * 4 + j;
            int cid = blkI * 64 + lane;
            int r = cid >> 3, c = (cid & 7) ^ (r & 7);
            gload16(&A[(size_t)r * K + k0 + c * 8], &As[blkI * 512]);
        }
        if (tid < 256) {
            float4 r4[4];
#pragma unroll
            for (int kk = 0; kk < 4; kk++)
                r4[kk] = *(const float4*)(B + (size_t)(k0 + skb + kk) * N + col0 + snb);
#pragma unroll
            for (int n = 0; n < 4; n++) {
                s16x4 w4;
                w4[0] = f2bf((&r4[0].x)[n]); w4[1] = f2bf((&r4[1].x)[n]);
                w4[2] = f2bf((&r4[2].x)[n]); w4[3] = f2bf((&r4[3].x)[n]);
                *(s16x4*)&Bs[snb + n][skb] = w4;
            }
        }
        __syncthreads();
#pragma unroll
        for (int kk = 0; kk < 64; kk += 32) {
            s16x8 a[4], b[2];
#pragma unroll
            for (int mi = 0; mi < 4; mi++) a[mi] = *(const s16x8*)&As[swz(wm * 64 + mi * 16 + li, kk + g * 8)];
#pragma unroll
            for (int ni = 0; ni < 2; ni++) b[ni] = *(const s16x8*)&Bs[wn * 32 + ni * 16 + li][kk + g * 8];
#pragma unroll
            for (int mi = 0; mi < 4; mi++)
#pragma unroll
                for (int ni = 0; ni < 2; ni++)
                    acc[mi][ni] = __builtin_amdgcn_mfma_f32_16x16x32_bf16(a[mi], b[ni], acc[mi][ni], 0, 0, 0);
        }
        __syncthreads();
    }
#pragma unroll
    for (int mi = 0; mi < 4; mi++)
#pragma unroll
        for (int ni = 0; ni < 2; ni++) {
            int gc = col0 + wn * 32 + ni * 16 + li;
#pragma unroll
            for (int r = 0; r < 4; r++) {
                int gr = wm * 64 + mi * 16 + g * 4 + r;
                if (gr < nrows) C[(size_t)gr * N + gc] = acc[mi][ni][r];
            }
        }
}

// ---------------- RoPE + build qf/kf/v as split planes ----------------
__global__ void prep_qkv_kernel(const float* __restrict__ q, const float* __restrict__ qkraw,
                                const float* __restrict__ kv, const int* __restrict__ positions,
                                short* __restrict__ qfh, short* __restrict__ qfl,
                                short* __restrict__ kfh, short* __restrict__ kfl,
                                short* __restrict__ vbh, short* __restrict__ vbl) {
    int t = blockIdx.x;
    __shared__ float cs[16], sn[16];
    if (threadIdx.x < 16) {
        float invf = powf(10000.f, -(float)(2 * threadIdx.x) / 32.f);
        float fr = (float)positions[t] * invf;
        cs[threadIdx.x] = cosf(fr);
        sn[threadIdx.x] = sinf(fr);
    }
    __syncthreads();
    for (int i = threadIdx.x; i < NH * QKD; i += blockDim.x) {
        int h = i / QKD, d = i % QKD;
        float val;
        if (d < 64) val = q[(size_t)t * 1536 + h * QKD + d];
        else {
            int r = d - 64, pr = r >> 1;
            float x1 = q[(size_t)t * 1536 + h * QKD + 64 + 2 * pr];
            float x2 = q[(size_t)t * 1536 + h * QKD + 64 + 2 * pr + 1];
            val = (r & 1) ? (x1 * sn[pr] + x2 * cs[pr]) : (x1 * cs[pr] - x2 * sn[pr]);
        }
        short hh = f2bf(val);
        qfh[(size_t)t * 1536 + i] = hh;
        qfl[(size_t)t * 1536 + i] = f2bf(val - bf2f(hh));
    }
    for (int i = threadIdx.x; i < NH * QKD; i += blockDim.x) {
        int h = i / QKD, d = i % QKD;
        float val;
        if (d < 64) val = kv[(size_t)t * 2048 + h * 128 + d];
        else {
            int r = d - 64, pr = r >> 1;
            float x1 = qkraw[(size_t)t * 800 + 768 + 2 * pr];
            float x2 = qkraw[(size_t)t * 800 + 768 + 2 * pr + 1];
            val = (r & 1) ? (x1 * sn[pr] + x2 * cs[pr]) : (x1 * cs[pr] - x2 * sn[pr]);
        }
        short hh = f2bf(val);
        kfh[(size_t)t * 1536 + i] = hh;
        kfl[(size_t)t * 1536 + i] = f2bf(val - bf2f(hh));
    }
    for (int i = threadIdx.x; i < NH * VD; i += blockDim.x) {
        int h = i / VD, d = i % VD;
        float val = kv[(size_t)t * 2048 + h * 128 + 64 + d];
        short hh = f2bf(val);
        vbh[(size_t)t * 1024 + i] = hh;
        vbl[(size_t)t * 1024 + i] = f2bf(val - bf2f(hh));
    }
}

// =====================================================================
// MFMA flash attention (verified; reads/writes bf16 planes)
// =====================================================================
__global__ __launch_bounds__(256) void attn_mfma_kernel(const short* __restrict__ qfh, const short* __restrict__ qfl,
                                                        const short* __restrict__ kfh, const short* __restrict__ kfl,
                                                        const short* __restrict__ vbh, const short* __restrict__ vbl,
                                                        short* __restrict__ obh, short* __restrict__ obl) {
    __shared__ short K_hi[64][104], K_lo[64][104];
    __shared__ short Vt_hi[64][72], Vt_lo[64][72];
    __shared__ short P_hi[4][16][72], P_lo[4][16][72];
    const int qt = blockIdx.x, h = blockIdx.y;
    const int tid = threadIdx.x, lane = tid & 63, w = tid >> 6;
    const int g = lane >> 4, li = lane & 15;

    s16x8 q_hi[3], q_lo[3];
    {
        const short* qb_h = qfh + (size_t)(qt * 64 + w * 16 + li) * 1536 + h * QKD;
        const short* qb_l = qfl + (size_t)(qt * 64 + w * 16 + li) * 1536 + h * QKD;
#pragma unroll
        for (int ks = 0; ks < 3; ks++) {
            q_hi[ks] = *(const s16x8*)(qb_h + ks * 32 + g * 8);
            q_lo[ks] = *(const s16x8*)(qb_l + ks * 32 + g * 8);
        }
    }

    f32x4 acc_o[4];
#pragma unroll
    for (int nc = 0; nc < 4; nc++)
#pragma unroll
        for (int r = 0; r < 4; r++) acc_o[nc][r] = 0.f;
    float m4[4] = {-1e30f, -1e30f, -1e30f, -1e30f};
    float l4[4] = {0.f, 0.f, 0.f, 0.f};
    const float scale = 0.102062072616f;

    for (int kt = 0; kt <= qt; kt++) {
#pragma unroll
        for (int it = 0; it < 3; it++) {
            int cid = it * 256 + tid;
            int key = cid / 12, c = cid % 12;
            *(s16x8*)&K_hi[key][c * 8] = *(const s16x8*)&kfh[(size_t)(kt * 64 + key) * 1536 + h * QKD + c * 8];
            *(s16x8*)&K_lo[key][c * 8] = *(const s16x8*)&kfl[(size_t)(kt * 64 + key) * 1536 + h * QKD + c * 8];
        }
#pragma unroll
        for (int it = 0; it < 2; it++) {
            int cid = it * 256 + tid;
            int key = cid >> 3, vc = cid & 7;
            s16x8 vh = *(const s16x8*)&vbh[(size_t)(kt * 64 + key) * 1024 + h * VD + vc * 8];
            s16x8 vl = *(const s16x8*)&vbl[(size_t)(kt * 64 + key) * 1024 + h * VD + vc * 8];
#pragma unroll
            for (int j = 0; j < 8; j++) {
                Vt_hi[vc * 8 + j][key] = vh[j];
                Vt_lo[vc * 8 + j][key] = vl[j];
            }
        }
        __syncthreads();

        f32x4 acc_s[4];
#pragma unroll
        for (int kc = 0; kc < 4; kc++)
#pragma unroll
            for (int r = 0; r < 4; r++) acc_s[kc][r] = 0.f;
#pragma unroll
        for (int ks = 0; ks < 3; ks++) {
#pragma unroll
            for (int kc = 0; kc < 4; kc++) {
                s16x8 kh = *(const s16x8*)&K_hi[kc * 16 + li][ks * 32 + g * 8];
                s16x8 kl = *(const s16x8*)&K_lo[kc * 16 + li][ks * 32 + g * 8];
                acc_s[kc] = __builtin_amdgcn_mfma_f32_16x16x32_bf16(q_hi[ks], kh, acc_s[kc], 0, 0, 0);
                acc_s[kc] = __builtin_amdgcn_mfma_f32_16x16x32_bf16(q_lo[ks], kh, acc_s[kc], 0, 0, 0);
                acc_s[kc] = __builtin_amdgcn_mfma_f32_16x16x32_bf16(q_hi[ks], kl, acc_s[kc], 0, 0, 0);
            }
        }
#pragma unroll
        for (int kc = 0; kc < 4; kc++)
#pragma unroll
            for (int r = 0; r < 4; r++) acc_s[kc][r] *= scale;
        if (kt == qt) {
#pragma unroll
            for (int kc = 0; kc < 4; kc++) {
                int key = kt * 64 + kc * 16 + li;
#pragma unroll
                for (int r = 0; r < 4; r++) {
                    int qr = qt * 64 + w * 16 + g * 4 + r;
                    if (key > qr) acc_s[kc][r] = -1e30f;
                }
            }
        }
        float tm4[4];
#pragma unroll
        for (int r = 0; r < 4; r++)
            tm4[r] = fmaxf(fmaxf(acc_s[0][r], acc_s[1][r]), fmaxf(acc_s[2][r], acc_s[3][r]));
#pragma unroll
        for (int off = 1; off < 16; off <<= 1)
#pragma unroll
            for (int r = 0; r < 4; r++) tm4[r] = fmaxf(tm4[r], __shfl_xor(tm4[r], off));
        float alpha[4];
#pragma unroll
        for (int r = 0; r < 4; r++) {
            float mn = fmaxf(m4[r], tm4[r]);
            alpha[r] = __expf(m4[r] - mn);
            m4[r] = mn;
        }
        float rs[4] = {0.f, 0.f, 0.f, 0.f};
#pragma unroll
        for (int kc = 0; kc < 4; kc++)
#pragma unroll
            for (int r = 0; r < 4; r++) {
                float p = __expf(acc_s[kc][r] - m4[r]);
                rs[r] += p;
                short hh = f2bf(p);
                P_hi[w][g * 4 + r][kc * 16 + li] = hh;
                P_lo[w][g * 4 + r][kc * 16 + li] = f2bf(p - bf2f(hh));
            }
#pragma unroll
        for (int off = 1; off < 16; off <<= 1)
#pragma unroll
            for (int r = 0; r < 4; r++) rs[r] += __shfl_xor(rs[r], off);
#pragma unroll
        for (int r = 0; r < 4; r++) l4[r] = l4[r] * alpha[r] + rs[r];
#pragma unroll
        for (int nc = 0; nc < 4; nc++)
#pragma unroll
            for (int r = 0; r < 4; r++) acc_o[nc][r] *= alpha[r];
#pragma unroll
        for (int ks = 0; ks < 2; ks++) {
            s16x8 ph = *(const s16x8*)&P_hi[w][li][ks * 32 + g * 8];
            s16x8 pl = *(const s16x8*)&P_lo[w][li][ks * 32 + g * 8];
#pragma unroll
            for (int nc = 0; nc < 4; nc++) {
                s16x8 vh = *(const s16x8*)&Vt_hi[nc * 16 + li][ks * 32 + g * 8];
                s16x8 vl = *(const s16x8*)&Vt_lo[nc * 16 + li][ks * 32 + g * 8];
                acc_o[nc] = __builtin_amdgcn_mfma_f32_16x16x32_bf16(ph, vh, acc_o[nc], 0, 0, 0);
                acc_o[nc] = __builtin_amdgcn_mfma_f32_16x16x32_bf16(pl, vh, acc_o[nc], 0, 0, 0);
                acc_o[nc] = __builtin_amdgcn_mfma_f32_16x16x32_bf16(ph, vl, acc_o[nc], 0, 0, 0);
            }
        }
        __syncthreads();
    }
    float inv[4];
#pragma unroll
    for (int r = 0; r < 4; r++) inv[r] = 1.f / l4[r];
#pragma unroll
    for (int nc = 0; nc < 4; nc++)
#pragma unroll
        for (int r = 0; r < 4; r++) {
            float o = acc_o[nc][r] * inv[r];
            size_t idx = (size_t)(qt * 64 + w * 16 + g * 4 + r) * 1024 + h * VD + nc * 16 + li;
            short hh = f2bf(o);
            obh[idx] = hh;
            obl[idx] = f2bf(o - bf2f(hh));
        }
}

// ---------------- fused resid-add + post-rmsnorm + routing ----------------
__global__ __launch_bounds__(256) void fused_post_attn(float* __restrict__ x0, const float* __restrict__ att,
                                                       const float* __restrict__ w, const float* __restrict__ gate_w,
                                                       const float* __restrict__ gate_bias,
                                                       short* __restrict__ h2bf, int* __restrict__ topidx,
                                                       float* __restrict__ topw) {
    int t = blockIdx.x;
    float resid[8];
    float ss = 0.f;
#pragma unroll
    for (int j = 0; j < 8; j++) {
        int i = threadIdx.x + j * 256;
        float v = x0[(size_t)t * HDIM + i] + att[(size_t)t * HDIM + i];
        resid[j] = v;
        x0[(size_t)t * HDIM + i] = v;
        ss += v * v;
    }
    float r = rsqrtf(block_sum(ss) / HDIM + EPSF);
    float acc[8] = {0.f, 0.f, 0.f, 0.f, 0.f, 0.f, 0.f, 0.f};
#pragma unroll
    for (int j = 0; j < 8; j++) {
        int i = threadIdx.x + j * 256;
        float v = resid[j] * r * w[i];
        h2bf[(size_t)t * HDIM + i] = f2bf(v);
        const float* gw = gate_w + (size_t)i * 8;
        float4 g0 = *(const float4*)gw;
        float4 g1 = *(const float4*)(gw + 4);
        acc[0] = fmaf(v, g0.x, acc[0]); acc[1] = fmaf(v, g0.y, acc[1]);
        acc[2] = fmaf(v, g0.z, acc[2]); acc[3] = fmaf(v, g0.w, acc[3]);
        acc[4] = fmaf(v, g1.x, acc[4]); acc[5] = fmaf(v, g1.y, acc[5]);
        acc[6] = fmaf(v, g1.z, acc[6]); acc[7] = fmaf(v, g1.w, acc[7]);
    }
    __shared__ float logits[8];
    for (int e = 0; e < 8; e++) {
        float s = block_sum(acc[e]);
        if (threadIdx.x == 0) logits[e] = s;
    }
    __syncthreads();
    if (threadIdx.x == 0) {
        float sig[8], sc[8];
        for (int e = 0; e < 8; e++) {
            sig[e] = 1.f / (1.f + expf(-logits[e]));
            sc[e] = sig[e] + gate_bias[e];
        }
        int i0 = 0;
        for (int e = 1; e < 8; e++) if (sc[e] > sc[i0]) i0 = e;
        int i1 = -1;
        for (int e = 0; e < 8; e++) if (e != i0 && (i1 < 0 || sc[e] > sc[i1])) i1 = e;
        float w0 = sig[i0], w1 = sig[i1], s = w0 + w1 + 1e-20f;
        topidx[t * 2 + 0] = i0; topidx[t * 2 + 1] = i1;
        topw[t * 2 + 0] = w0 / s; topw[t * 2 + 1] = w1 / s;
    }
}

// ---------------- counting sort + 256-row tile map (+4 shared tiles) ----------------
__global__ void sort_kernel(const int* __restrict__ topidx, int* __restrict__ sorted_t,
                            int* __restrict__ slotpos, int4* __restrict__ tilemap) {
    __shared__ int counts[8], offs[9];
    int wid = threadIdx.x >> 6, lane = threadIdx.x & 63;
    int cnt = 0;
    for (int base = 0; base < 2 * T_; base += 64) {
        int e = topidx[base + lane];
        unsigned long long m = __ballot(e == wid);
        cnt += __popcll(m);
    }
    if (lane == 0) counts[wid] = cnt;
    __syncthreads();
    if (threadIdx.x == 0) {
        offs[0] = 0;
        for (int e = 0; e < 8; e++) offs[e + 1] = offs[e] + counts[e];
    }
    __syncthreads();
    int pos = offs[wid];
    for (int base = 0; base < 2 * T_; base += 64) {
        int sl = base + lane;
        int e = topidx[sl];
        bool match = (e == wid);
        unsigned long long m = __ballot(match);
        if (match) {
            int before = __popcll(m & ((1ull << lane) - 1ull));
            int pp = pos + before;
            sorted_t[pp] = sl >> 1;
            slotpos[sl] = pp;
        }
        pos += __popcll(m);
    }
    __syncthreads();
    if (threadIdx.x == 0) {
        int nt = 0;
        for (int e = 0; e < 8; e++) {
            int c = counts[e], o = offs[e];
            for (int r = 0; r < c; r += 256) {
                tilemap[nt] = make_int4(e, o + r, min(256, c - r), 0);
                nt++;
            }
        }
        for (int r = 0; r < 4; r++) {             // shared MLP as expert 8, 256-row tiles
            tilemap[nt] = make_int4(8, 2048 + r * 256, 256, 0);
            nt++;
        }
        for (int i = nt; i < MAXTILES; i++) tilemap[i] = make_int4(0, 0, 0, 0);
    }
}

// ---------------- final combine -> f32 out ----------------
__global__ void final_kernel(const float* __restrict__ resid, const float* __restrict__ md,
                             const int* __restrict__ slotpos, const float* __restrict__ topw,
                             float* __restrict__ out) {
    int t = blockIdx.x;
    int p0 = slotpos[t * 2 + 0], p1 = slotpos[t * 2 + 1];
    float w0 = topw[t * 2 + 0] * 2.5f, w1 = topw[t * 2 + 1] * 2.5f;
    const float* mds = md + (size_t)(2048 + t) * HDIM;
    for (int c = threadIdx.x; c < HDIM; c += blockDim.x) {
        float v = resid[(size_t)t * HDIM + c] + mds[c]
                + w0 * md[(size_t)p0 * HDIM + c] + w1 * md[(size_t)p1 * HDIM + c];
        out[(size_t)t * HDIM + c] = v;
    }
}

// ---------------- launcher ----------------
extern "C" void kernel_launch(void* const* d_in, const int* in_sizes, int n_in,
                              void* d_out, int out_size, void* d_ws, size_t ws_size,
                              hipStream_t stream) {
    (void)in_sizes; (void)n_in; (void)out_size; (void)ws_size;
    const int*   input_ids = (const int*)d_in[0];
    const int*   positions = (const int*)d_in[1];
    const float* prev      = (const float*)d_in[2];
    const float* embed     = (const float*)d_in[3];
    const float* enorm_w   = (const float*)d_in[4];
    const float* hnorm_w   = (const float*)d_in[5];
    const float* eh_proj_w = (const float*)d_in[6];
    const float* in_ln_w   = (const float*)d_in[7];
    const float* post_ln_w = (const float*)d_in[8];
    const float* q_a_w     = (const float*)d_in[9];
    const float* q_a_ln_w  = (const float*)d_in[10];
    const float* q_b_w     = (const float*)d_in[11];
    const float* kv_a_w    = (const float*)d_in[12];
    const float* kv_a_ln_w = (const float*)d_in[13];
    const float* kv_b_w    = (const float*)d_in[14];
    const float* o_w       = (const float*)d_in[15];
    const float* gate_w    = (const float*)d_in[16];
    const float* gate_bias = (const float*)d_in[17];
    const float* exp_g     = (const float*)d_in[18];
    const float* exp_u     = (const float*)d_in[19];
    const float* exp_d     = (const float*)d_in[20];
    const float* sh_g      = (const float*)d_in[21];
    const float* sh_u      = (const float*)d_in[22];
    const float* sh_d      = (const float*)d_in[23];
    float* out = (float*)d_out;

    float* ws = (float*)d_ws;
    short* catH  = (short*)(ws + OF_CATH);
    short* catL  = (short*)(ws + OF_CATL);
    float* x0    = ws + OF_X0;
    short* mact  = (short*)(ws + OF_MACT);
    short* hH    = (short*)(ws + OF_HH);
    short* hL    = (short*)(ws + OF_HL);
    float* qbuf  = ws + OF_QBUF;
    float* kvbuf = ws + OF_KVBUF;
    short* qaH   = (short*)(ws + OF_QAH);
    short* qaL   = (short*)(ws + OF_QAL);
    short* kvcnH = (short*)(ws + OF_KVCNH);
    short* kvcnL = (short*)(ws + OF_KVCNL);
    short* qfH   = (short*)(ws + OF_QFH);
    short* qfL   = (short*)(ws + OF_QFL);
    short* kfH   = (short*)(ws + OF_KFH);
    short* kfL   = (short*)(ws + OF_KFL);
    short* vbH   = (short*)(ws + OF_VBH);
    short* vbL   = (short*)(ws + OF_VBL);
    short* obH   = (short*)(ws + OF_OBH);
    short* obL   = (short*)(ws + OF_OBL);
    float* att   = ws + OF_ATT;
    short* h2bf  = (short*)(ws + OF_H2BF);
    float* md    = ws + OF_MD;
    float* qkraw = ws + OF_QKRAW;
    short* batH  = (short*)(ws + OF_BATH);
    short* batL  = (short*)(ws + OF_BATL);
    int*   ri       = (int*)(ws + OF_ROUT);
    int*   topidx   = ri;
    int*   sorted_t = ri + 2048;
    int*   slotpos  = ri + 4096;
    int4*  tilemap  = (int4*)(ri + 6144);
    float* topw     = (float*)(ri + 6144 + 4 * MAXTILES);
    short* ehTH  = (short*)(ws + OF_EHTH);
    short* ehTL  = (short*)(ws + OF_EHTL);
    short* qbTH  = (short*)(ws + OF_QBTH);
    short* qbTL  = (short*)(ws + OF_QBTL);
    short* kvbTH = (short*)(ws + OF_KVBTH);
    short* kvbTL = (short*)(ws + OF_KVBTL);
    short* owTH  = (short*)(ws + OF_OWTH);
    short* owTL  = (short*)(ws + OF_OWTL);

    dim3 blk(256);

    // 0. one-launch weight transpose+split (6 jobs)
    TJobs J;
    J.W[0] = eh_proj_w; J.Whi[0] = ehTH; J.Wlo[0] = ehTL; J.K[0] = 4096; J.N[0] = 2048; J.nbx[0] = 64;
    J.W[1] = q_a_w; J.Whi[1] = batH; J.Wlo[1] = batL; J.K[1] = 2048; J.N[1] = 512; J.nbx[1] = 32;
    J.W[2] = kv_a_w; J.Whi[2] = batH + (size_t)512 * 2048; J.Wlo[2] = batL + (size_t)512 * 2048;
    J.K[2] = 2048; J.N[2] = 288; J.nbx[2] = 32;
    J.W[3] = q_b_w; J.Whi[3] = qbTH; J.Wlo[3] = qbTL; J.K[3] = 512; J.N[3] = 1536; J.nbx[3] = 8;
    J.W[4] = kv_b_w; J.Whi[4] = kvbTH; J.Wlo[4] = kvbTL; J.K[4] = 256; J.N[4] = 2048; J.nbx[4] = 4;
    J.W[5] = o_w; J.Whi[5] = owTH; J.Wlo[5] = owTL; J.K[5] = 1024; J.N[5] = 2048; J.nbx[5] = 16;
    int nby[6] = {32, 8, 5, 24, 32, 32};
    J.base[0] = 0;
    for (int i = 0; i < 6; i++) J.base[i + 1] = J.base[i] + J.nbx[i] * nby[i];
    transpose_multi_kernel<<<J.base[6], blk, 0, stream>>>(J);

    // 1. embed + rmsnorm + concat
    embed_cat_kernel<<<T_, blk, 0, stream>>>(input_ids, embed, enorm_w, prev, hnorm_w, catH, catL);
    // 2. x0 = cat @ eh_proj
    gemm_planes<true><<<dim3(32, 8), blk, 0, stream>>>(catH, catL, ehTH, ehTL, x0, T_, 2048, 4096);
    // 3. h = rmsnorm(x0)
    rmsnorm_kernel<<<T_, blk, 0, stream>>>(x0, 2048, 2048, in_ln_w, nullptr, hH, hL, 2048);
    // 4. qkraw = h @ [q_a | kv_a]  (N=800)
    gemm_planes<true><<<dim3(13, 8), blk, 0, stream>>>(hH, hL, batH, batL, qkraw, T_, 800, 2048);
    // 5. fused rmsnorms (q_a_ln + kv_a_ln)
    rmsnorm_qkv_kernel<<<T_, blk, 0, stream>>>(qkraw, q_a_ln_w, kv_a_ln_w, qaH, qaL, kvcnH, kvcnL);
    // 6. q = qa @ q_b
    gemm_planes<true><<<dim3(24, 8), blk, 0, stream>>>(qaH, qaL, qbTH, qbTL, qbuf, T_, 1536, 512);
    // 7. kv = kvcn @ kv_b
    gemm_planes<true><<<dim3(32, 8), blk, 0, stream>>>(kvcnH, kvcnL, kvbTH, kvbTL, kvbuf, T_, 2048, 256);
    // 8. rope + planes (k_pe from qkraw cols 768-799)
    prep_qkv_kernel<<<T_, blk, 0, stream>>>(qbuf, qkraw, kvbuf, positions, qfH, qfL, kfH, kfL, vbH, vbL);
    // 9. flash attention
    attn_mfma_kernel<<<dim3(T_ / 64, NH), blk, 0, stream>>>(qfH, qfL, kfH, kfL, vbH, vbL, obH, obL);
    // 10. attn_out = ob @ o_w
    gemm_planes<true><<<dim3(32, 8), blk, 0, stream>>>(obH, obL, owTH, owTL, att, T_, 2048, 1024);
    // 11. fused resid + rmsnorm + routing
    fused_post_attn<<<T_, blk, 0, stream>>>(x0, att, post_ln_w, gate_w, gate_bias, h2bf, topidx, topw);
    // 12. sort (256-row tiles + 4 shared tiles)
    sort_kernel<<<1, 512, 0, stream>>>(topidx, sorted_t, slotpos, tilemap);
    // 13. MoE gate+up fused with silu -> mact (BM=256, inline gather)
    moe_gateup<<<dim3(16, MAXTILES), dim3(512), 0, stream>>>(h2bf, sorted_t, exp_g, exp_u, sh_g, sh_u, mact, tilemap, 2048, 1024);
    // 14. MoE down (BM=256)
    moe_down<<<dim3(32, MAXTILES), dim3(512), 0, stream>>>(mact, exp_d, sh_d, md, tilemap, 1024, 2048);
    // 15. final combine
    final_kernel<<<T_, blk, 0, stream>>>(x0, md, slotpos, topw, out);
}

// Round 16
// 508.692 us; speedup vs baseline: 1.4714x; 1.0159x over previous
//
#include <hip/hip_runtime.h>
#include <hip/hip_bf16.h>
#include <math.h>

constexpr int T_ = 1024;
constexpr int HDIM = 2048;
constexpr int NH = 16;
constexpr int QKD = 96;
constexpr int VD = 64;
constexpr int MAXTILES = 32;
constexpr int NITEMS = 24;     // 8 full q-tiles + 8 split q-tiles x 2 partials
constexpr float EPSF = 1e-6f;

using f32x4 = __attribute__((ext_vector_type(4))) float;
using s16x8 = __attribute__((ext_vector_type(8))) short;
using s16x4 = __attribute__((ext_vector_type(4))) short;

// ---------------- workspace layout (float offsets; ws is ~1 GB) ----------------
constexpr size_t OF_CATH  = 0;                 // bf16 T*4096
constexpr size_t OF_CATL  = 2097152;
constexpr size_t OF_X0    = 4194304;           // f32 T*2048
constexpr size_t OF_MACT  = 6291456;           // bf16 3072*1024
constexpr size_t OF_HH    = 8388608;           // bf16 T*2048
constexpr size_t OF_HL    = 9437184;
constexpr size_t OF_QBUF  = 11010048;          // f32 T*1536
constexpr size_t OF_KVBUF = 12877824;          // f32 T*2048
constexpr size_t OF_QAH   = 14974976;          // bf16 T*512
constexpr size_t OF_QAL   = 15237120;
constexpr size_t OF_KVCNH = 15499264;          // bf16 T*256
constexpr size_t OF_KVCNL = 15630336;
constexpr size_t OF_QFH   = 15761408;          // bf16 T*1536
constexpr size_t OF_QFL   = 16547840;
constexpr size_t OF_KFH   = 17334272;
constexpr size_t OF_KFL   = 18120704;
constexpr size_t OF_VBH   = 18907136;          // bf16 T*1024
constexpr size_t OF_VBL   = 19431424;
constexpr size_t OF_OBH   = 19955712;          // bf16 T*1024
constexpr size_t OF_OBL   = 20480000;
constexpr size_t OF_ATT   = 21004288;          // f32 T*2048
constexpr size_t OF_H2BF  = 23101440;          // bf16 T*2048
constexpr size_t OF_ROUT  = 24674304;          // ints
// weight planes (bf16)
constexpr size_t OF_EHTH  = 24682752;          // [2048][4096]
constexpr size_t OF_EHTL  = 28877056;
constexpr size_t OF_QBTH  = 34119936;          // [1536][512]
constexpr size_t OF_QBTL  = 34513152;
constexpr size_t OF_KVBTH = 35561728;          // [2048][256]
constexpr size_t OF_KVBTL = 35823872;
constexpr size_t OF_OWTH  = 36086016;          // [2048][1024]
constexpr size_t OF_OWTL  = 37134592;
constexpr size_t OF_MD    = 38183168;          // f32 3072*2048  (ends 44474624)
constexpr size_t OF_QKRAW = 44474624;          // f32 [1024][800] (ends 45293824)
constexpr size_t OF_BATH  = 45293824;          // bf16 [832][2048] (ends 46145792)
constexpr size_t OF_BATL  = 46145792;          // bf16 [832][2048] (ends 46997760)
constexpr size_t OF_OPART = 46997760;          // f32 [2][1024][16][64] (ends 49094912)
constexpr size_t OF_MLPART= 49094912;          // f32 [2][1024][16][2]  (ends 49160448)

// ---------------- helpers ----------------
__device__ __forceinline__ short f2bf(float f) {
    union { float f; unsigned u; } x; x.f = f;
    unsigned r = x.u + 0x7fffu + ((x.u >> 16) & 1u);
    return (short)(r >> 16);
}
__device__ __forceinline__ float bf2f(short h) {
    union { unsigned u; float f; } x; x.u = ((unsigned)(unsigned short)h) << 16; return x.f;
}
// LDS swizzle (plane GEMM): row stride 64 shorts; chunk ^= row&7
__device__ __forceinline__ int swz(int r, int k) {
    return (r << 6) + ((((k >> 3) ^ (r & 7)) << 3) | (k & 7));
}
// async global->LDS, 16 B per lane; LDS dest = wave-uniform base + lane*16
__device__ __forceinline__ void gload16(const void* g, void* l) {
    __builtin_amdgcn_global_load_lds((__attribute__((address_space(1))) void*)g,
                                     (__attribute__((address_space(3))) void*)l, 16, 0, 0);
}

__device__ __forceinline__ float block_sum(float v) {
    __shared__ float sbuf[9];
    int lane = threadIdx.x & 63;
    int wid  = threadIdx.x >> 6;
#pragma unroll
    for (int off = 32; off > 0; off >>= 1) v += __shfl_down(v, off);
    __syncthreads();
    if (lane == 0) sbuf[wid] = v;
    __syncthreads();
    if (threadIdx.x == 0) {
        float s = 0.f;
        int nw = blockDim.x >> 6;
        for (int i = 0; i < nw; i++) s += sbuf[i];
        sbuf[8] = s;
    }
    __syncthreads();
    return sbuf[8];
}

// ---------------- multi-job weight transpose + split ----------------
struct TJobs {
    const float* W[6];
    short* Whi[6];
    short* Wlo[6];
    int K[6];
    int N[6];
    int nbx[6];
    int base[7];
};

__global__ void transpose_multi_kernel(TJobs J) {
    int bid = blockIdx.x;
    int j = 0;
#pragma unroll
    for (int i = 1; i < 6; i++) if (bid >= J.base[i]) j = i;
    int local = bid - J.base[j];
    int K = J.K[j], N = J.N[j];
    int bx = local % J.nbx[j], by = local / J.nbx[j];
    const float* W = J.W[j];
    short* Whi = J.Whi[j];
    short* Wlo = J.Wlo[j];

    __shared__ float tile[64][65];
    int k0 = bx * 64, n0 = by * 64;
    int tn = threadIdx.x & 63;
    int tk4 = threadIdx.x >> 6;
#pragma unroll 4
    for (int i = 0; i < 16; i++) {
        int kk = tk4 * 16 + i;
        int gn = n0 + tn;
        tile[kk][tn] = (gn < N) ? W[(size_t)(k0 + kk) * N + gn] : 0.f;
    }
    __syncthreads();
    int on = threadIdx.x >> 2;
    int oc = threadIdx.x & 3;
#pragma unroll 4
    for (int i = 0; i < 16; i++) {
        int kk = oc * 16 + i;
        float v = tile[kk][on];
        short hh = f2bf(v);
        size_t o = (size_t)(n0 + on) * K + k0 + kk;
        Whi[o] = hh;
        Wlo[o] = f2bf(v - bf2f(hh));
    }
}

// ---------------- embedding + rmsnorm + concat -> split planes ----------------
__global__ void embed_cat_kernel(const int* __restrict__ ids, const float* __restrict__ embed,
                                 const float* __restrict__ enorm, const float* __restrict__ prev,
                                 const float* __restrict__ hnorm, short* __restrict__ ch,
                                 short* __restrict__ cl) {
    int t = blockIdx.x;
    const float* e = embed + (size_t)ids[t] * HDIM;
    float ss = 0.f;
    for (int i = threadIdx.x; i < HDIM; i += blockDim.x) { float v = e[i]; ss += v * v; }
    float r = rsqrtf(block_sum(ss) / HDIM + EPSF);
    for (int i = threadIdx.x; i < HDIM; i += blockDim.x) {
        float v = e[i] * r * enorm[i];
        short hh = f2bf(v);
        ch[(size_t)t * 4096 + i] = hh;
        cl[(size_t)t * 4096 + i] = f2bf(v - bf2f(hh));
    }
    const float* p = prev + (size_t)t * HDIM;
    ss = 0.f;
    for (int i = threadIdx.x; i < HDIM; i += blockDim.x) { float v = p[i]; ss += v * v; }
    r = rsqrtf(block_sum(ss) / HDIM + EPSF);
    for (int i = threadIdx.x; i < HDIM; i += blockDim.x) {
        float v = p[i] * r * hnorm[i];
        short hh = f2bf(v);
        ch[(size_t)t * 4096 + 2048 + i] = hh;
        cl[(size_t)t * 4096 + 2048 + i] = f2bf(v - bf2f(hh));
    }
}

// ---------------- rmsnorm (f32 / hi / lo outputs) ----------------
__global__ void rmsnorm_kernel(const float* __restrict__ in, int in_stride, int width,
                               const float* __restrict__ w, float* __restrict__ outf,
                               short* __restrict__ outh, short* __restrict__ outl, int out_stride) {
    int t = blockIdx.x;
    const float* x = in + (size_t)t * in_stride;
    float ss = 0.f;
    for (int i = threadIdx.x; i < width; i += blockDim.x) { float v = x[i]; ss += v * v; }
    float r = rsqrtf(block_sum(ss) / width + EPSF);
    size_t ob = (size_t)t * out_stride;
    for (int i = threadIdx.x; i < width; i += blockDim.x) {
        float v = x[i] * r * w[i];
        if (outf) outf[ob + i] = v;
        if (outh) {
            short hh = f2bf(v);
            outh[ob + i] = hh;
            if (outl) outl[ob + i] = f2bf(v - bf2f(hh));
        }
    }
}

// ---------------- fused rmsnorm for qkraw: q_a (cols 0-511) + kv_c (cols 512-767) ----------------
__global__ void rmsnorm_qkv_kernel(const float* __restrict__ qkraw, const float* __restrict__ wq,
                                   const float* __restrict__ wkv, short* __restrict__ qaH,
                                   short* __restrict__ qaL, short* __restrict__ kvcnH,
                                   short* __restrict__ kvcnL) {
    int t = blockIdx.x;
    const float* row = qkraw + (size_t)t * 800;
    float ss = 0.f;
    for (int i = threadIdx.x; i < 512; i += blockDim.x) { float v = row[i]; ss += v * v; }
    float r = rsqrtf(block_sum(ss) / 512.f + EPSF);
    for (int i = threadIdx.x; i < 512; i += blockDim.x) {
        float v = row[i] * r * wq[i];
        short hh = f2bf(v);
        qaH[(size_t)t * 512 + i] = hh;
        qaL[(size_t)t * 512 + i] = f2bf(v - bf2f(hh));
    }
    ss = 0.f;
    for (int i = threadIdx.x; i < 256; i += blockDim.x) { float v = row[512 + i]; ss += v * v; }
    r = rsqrtf(block_sum(ss) / 256.f + EPSF);
    for (int i = threadIdx.x; i < 256; i += blockDim.x) {
        float v = row[512 + i] * r * wkv[i];
        short hh = f2bf(v);
        kvcnH[(size_t)t * 256 + i] = hh;
        kvcnL[(size_t)t * 256 + i] = f2bf(v - bf2f(hh));
    }
}

// =====================================================================
// Plane GEMM (verified): BM=128 BN=64 BK=64, gload16 staging
// with inverse-swizzled global source, swizzled LDS reads.
// =====================================================================
template<bool SPLIT>
__global__ __launch_bounds__(256) void gemm_planes(const short* __restrict__ Ahi, const short* __restrict__ Alo,
                                                   const short* __restrict__ Bhi, const short* __restrict__ Blo,
                                                   float* __restrict__ C, int M, int N, int K) {
    __shared__ short As[SPLIT ? 2 : 1][128 * 64];
    __shared__ short Bs[SPLIT ? 2 : 1][64 * 64];
    const int tid = threadIdx.x;
    const int lane = tid & 63, wid = tid >> 6;
    const int g = lane >> 4, li = lane & 15;
    const int wm = wid >> 1, wn = wid & 1;
    const int row0 = blockIdx.y * 128, col0 = blockIdx.x * 64;

    f32x4 acc[4][2];
#pragma unroll
    for (int mi = 0; mi < 4; mi++)
#pragma unroll
        for (int ni = 0; ni < 2; ni++)
#pragma unroll
            for (int r = 0; r < 4; r++) acc[mi][ni][r] = 0.f;

    for (int k0 = 0; k0 < K; k0 += 64) {
#pragma unroll
        for (int j = 0; j < 4; j++) {
            int blkI = wid * 4 + j;
            int cid = blkI * 64 + lane;
            int r = cid >> 3, c = (cid & 7) ^ (r & 7);
            gload16(&Ahi[(size_t)(row0 + r) * K + k0 + c * 8], &As[0][blkI * 512]);
            if constexpr (SPLIT)
                gload16(&Alo[(size_t)(row0 + r) * K + k0 + c * 8], &As[1][blkI * 512]);
        }
#pragma unroll
        for (int j = 0; j < 2; j++) {
            int blkI = wid * 2 + j;
            int cid = blkI * 64 + lane;
            int r = cid >> 3, c = (cid & 7) ^ (r & 7);
            gload16(&Bhi[(size_t)(col0 + r) * K + k0 + c * 8], &Bs[0][blkI * 512]);
            if constexpr (SPLIT)
                gload16(&Blo[(size_t)(col0 + r) * K + k0 + c * 8], &Bs[1][blkI * 512]);
        }
        __syncthreads();
#pragma unroll
        for (int kk = 0; kk < 64; kk += 32) {
            s16x8 ah[4], bh[2];
#pragma unroll
            for (int mi = 0; mi < 4; mi++) ah[mi] = *(const s16x8*)&As[0][swz(wm * 64 + mi * 16 + li, kk + g * 8)];
#pragma unroll
            for (int ni = 0; ni < 2; ni++) bh[ni] = *(const s16x8*)&Bs[0][swz(wn * 32 + ni * 16 + li, kk + g * 8)];
            if constexpr (SPLIT) {
                s16x8 al[4], bl[2];
#pragma unroll
                for (int mi = 0; mi < 4; mi++) al[mi] = *(const s16x8*)&As[1][swz(wm * 64 + mi * 16 + li, kk + g * 8)];
#pragma unroll
                for (int ni = 0; ni < 2; ni++) bl[ni] = *(const s16x8*)&Bs[1][swz(wn * 32 + ni * 16 + li, kk + g * 8)];
#pragma unroll
                for (int mi = 0; mi < 4; mi++)
#pragma unroll
                    for (int ni = 0; ni < 2; ni++) {
                        acc[mi][ni] = __builtin_amdgcn_mfma_f32_16x16x32_bf16(ah[mi], bh[ni], acc[mi][ni], 0, 0, 0);
                        acc[mi][ni] = __builtin_amdgcn_mfma_f32_16x16x32_bf16(al[mi], bh[ni], acc[mi][ni], 0, 0, 0);
                        acc[mi][ni] = __builtin_amdgcn_mfma_f32_16x16x32_bf16(ah[mi], bl[ni], acc[mi][ni], 0, 0, 0);
                    }
            } else {
#pragma unroll
                for (int mi = 0; mi < 4; mi++)
#pragma unroll
                    for (int ni = 0; ni < 2; ni++)
                        acc[mi][ni] = __builtin_amdgcn_mfma_f32_16x16x32_bf16(ah[mi], bh[ni], acc[mi][ni], 0, 0, 0);
            }
        }
        __syncthreads();
    }
#pragma unroll
    for (int mi = 0; mi < 4; mi++)
#pragma unroll
        for (int ni = 0; ni < 2; ni++) {
            int gc = col0 + wn * 32 + ni * 16 + li;
            if (gc < N) {
#pragma unroll
                for (int r = 0; r < 4; r++) {
                    int gr = row0 + wm * 64 + mi * 16 + g * 4 + r;
                    C[(size_t)gr * N + gc] = acc[mi][ni][r];
                }
            }
        }
}

// =====================================================================
// MoE gate+up GEMM + silu epilogue; BM=256, 512 threads (8 waves 4m x 2n).
// =====================================================================
__global__ __launch_bounds__(512) void moe_gateup(const short* __restrict__ h2bf, const int* __restrict__ sorted_t,
                                                  const float* __restrict__ Wg, const float* __restrict__ Wu,
                                                  const float* __restrict__ Sg, const float* __restrict__ Su,
                                                  short* __restrict__ Cact, const int4* __restrict__ tilemap,
                                                  int K, int N) {
    int4 tm = tilemap[blockIdx.y];
    int nrows = tm.z;
    if (nrows == 0) return;
    const float* Bg = (tm.x < 8) ? Wg + (size_t)tm.x * K * N : Sg;
    const float* Bu = (tm.x < 8) ? Wu + (size_t)tm.x * K * N : Su;

    __shared__ short As[256 * 64];
    alignas(16) __shared__ short Bgs[64][72];
    alignas(16) __shared__ short Bus[64][72];
    const int tid = threadIdx.x;
    const int lane = tid & 63, wid = tid >> 6;
    const int g = lane >> 4, li = lane & 15;
    const int wm = wid >> 1, wn = wid & 1;
    const int col0 = blockIdx.x * 64;

    int tokens[4];
#pragma unroll
    for (int j = 0; j < 4; j++) {
        int blkI = wid * 4 + j;
        int cid = blkI * 64 + lane;
        int r = cid >> 3;
        int slot = tm.y + r;
        tokens[j] = (slot < 2048) ? sorted_t[slot] : (slot - 2048);
    }

    f32x4 accg[4][2], accu[4][2];
#pragma unroll
    for (int mi = 0; mi < 4; mi++)
#pragma unroll
        for (int ni = 0; ni < 2; ni++)
#pragma unroll
            for (int r = 0; r < 4; r++) { accg[mi][ni][r] = 0.f; accu[mi][ni][r] = 0.f; }

    const int t2 = tid & 255;
    const int skb = (t2 >> 4) << 2, snb = (t2 & 15) << 2;

    for (int k0 = 0; k0 < K; k0 += 64) {
#pragma unroll
        for (int j = 0; j < 4; j++) {
            int blkI = wid * 4 + j;
            int cid = blkI * 64 + lane;
            int r = cid >> 3, c = (cid & 7) ^ (r & 7);
            gload16(&h2bf[(size_t)tokens[j] * K + k0 + c * 8], &As[blkI * 512]);
        }
        {
            const float* B = (tid < 256) ? Bg : Bu;
            short (*Bst)[72] = (tid < 256) ? Bgs : Bus;
            float4 r4[4];
#pragma unroll
            for (int kk = 0; kk < 4; kk++)
                r4[kk] = *(const float4*)(B + (size_t)(k0 + skb + kk) * N + col0 + snb);
#pragma unroll
            for (int n = 0; n < 4; n++) {
                s16x4 w4;
                w4[0] = f2bf((&r4[0].x)[n]); w4[1] = f2bf((&r4[1].x)[n]);
                w4[2] = f2bf((&r4[2].x)[n]); w4[3] = f2bf((&r4[3].x)[n]);
                *(s16x4*)&Bst[snb + n][skb] = w4;
            }
        }
        __syncthreads();
#pragma unroll
        for (int kk = 0; kk < 64; kk += 32) {
            s16x8 a[4], bg2[2], bu2[2];
#pragma unroll
            for (int mi = 0; mi < 4; mi++) a[mi] = *(const s16x8*)&As[swz(wm * 64 + mi * 16 + li, kk + g * 8)];
#pragma unroll
            for (int ni = 0; ni < 2; ni++) {
                bg2[ni] = *(const s16x8*)&Bgs[wn * 32 + ni * 16 + li][kk + g * 8];
                bu2[ni] = *(const s16x8*)&Bus[wn * 32 + ni * 16 + li][kk + g * 8];
            }
#pragma unroll
            for (int mi = 0; mi < 4; mi++)
#pragma unroll
                for (int ni = 0; ni < 2; ni++) {
                    accg[mi][ni] = __builtin_amdgcn_mfma_f32_16x16x32_bf16(a[mi], bg2[ni], accg[mi][ni], 0, 0, 0);
                    accu[mi][ni] = __builtin_amdgcn_mfma_f32_16x16x32_bf16(a[mi], bu2[ni], accu[mi][ni], 0, 0, 0);
                }
        }
        __syncthreads();
    }
#pragma unroll
    for (int mi = 0; mi < 4; mi++)
#pragma unroll
        for (int ni = 0; ni < 2; ni++) {
            int gc = col0 + wn * 32 + ni * 16 + li;
#pragma unroll
            for (int r = 0; r < 4; r++) {
                int gr = wm * 64 + mi * 16 + g * 4 + r;
                if (gr < nrows) {
                    float x = accg[mi][ni][r], u = accu[mi][ni][r];
                    Cact[(size_t)(tm.y + gr) * N + gc] = f2bf((x / (1.f + expf(-x))) * u);
                }
            }
        }
}

// =====================================================================
// MoE down GEMM; BM=256, 512 threads.
// =====================================================================
__global__ __launch_bounds__(512) void moe_down(const short* __restrict__ Abase, const float* __restrict__ Wall,
                                                const float* __restrict__ Sd, float* __restrict__ Cbase,
                                                const int4* __restrict__ tilemap, int K, int N) {
    int4 tm = tilemap[blockIdx.y];
    int nrows = tm.z;
    if (nrows == 0) return;
    const short* A = Abase + (size_t)tm.y * K;
    float* C = Cbase + (size_t)tm.y * N;
    const float* B = (tm.x < 8) ? Wall + (size_t)tm.x * K * N : Sd;

    __shared__ short As[256 * 64];
    alignas(16) __shared__ short Bs[64][72];
    const int tid = threadIdx.x;
    const int lane = tid & 63, wid = tid >> 6;
    const int g = lane >> 4, li = lane & 15;
    const int wm = wid >> 1, wn = wid & 1;
    const int col0 = blockIdx.x * 64;

    f32x4 acc[4][2];
#pragma unroll
    for (int mi = 0; mi < 4; mi++)
#pragma unroll
        for (int ni = 0; ni < 2; ni++)
#pragma unroll
            for (int r = 0; r < 4; r++) acc[mi][ni][r] = 0.f;

    const int skb = (tid >> 4) << 2, snb = (tid & 15) << 2;

    for (int k0 = 0; k0 < K; k0 += 64) {
#pragma unroll
        for (int j = 0; j < 4; j++) {
            int blkI = wid * 4 + j;
            int cid = blkI * 64 + lane;
            int r = cid >> 3, c = (cid & 7) ^ (r & 7);
            gload16(&A[(size_t)r * K + k0 + c * 8], &As[blkI * 512]);
        }
        if (tid < 256) {
            float4 r4[4];
#pragma unroll
            for (int kk = 0; kk < 4; kk++)
                r4[kk] = *(const float4*)(B + (size_t)(k0 + skb + kk) * N + col0 + snb);
#pragma unroll
            for (int n = 0; n < 4; n++) {
                s16x4 w4;
                w4[0] = f2bf((&r4[0].x)[n]); w4[1] = f2bf((&r4[1].x)[n]);
                w4[2] = f2bf((&r4[2].x)[n]); w4[3] = f2bf((&r4[3].x)[n]);
                *(s16x4*)&Bs[snb + n][skb] = w4;
            }
        }
        __syncthreads();
#pragma unroll
        for (int kk = 0; kk < 64; kk += 32) {
            s16x8 a[4], b[2];
#pragma unroll
            for (int mi = 0; mi < 4; mi++) a[mi] = *(const s16x8*)&As[swz(wm * 64 + mi * 16 + li, kk + g * 8)];
#pragma unroll
            for (int ni = 0; ni < 2; ni++) b[ni] = *(const s16x8*)&Bs[wn * 32 + ni * 16 + li][kk + g * 8];
#pragma unroll
            for (int mi = 0; mi < 4; mi++)
#pragma unroll
                for (int ni = 0; ni < 2; ni++)
                    acc[mi][ni] = __builtin_amdgcn_mfma_f32_16x16x32_bf16(a[mi], b[ni], acc[mi][ni], 0, 0, 0);
        }
        __syncthreads();
    }
#pragma unroll
    for (int mi = 0; mi < 4; mi++)
#pragma unroll
        for (int ni = 0; ni < 2; ni++) {
            int gc = col0 + wn * 32 + ni * 16 + li;
#pragma unroll
            for (int r = 0; r < 4; r++) {
                int gr = wm * 64 + mi * 16 + g * 4 + r;
                if (gr < nrows) C[(size_t)gr * N + gc] = acc[mi][ni][r];
            }
        }
}

// ---------------- RoPE + build qf/kf/v as split planes ----------------
__global__ void prep_qkv_kernel(const float* __restrict__ q, const float* __restrict__ qkraw,
                                const float* __restrict__ kv, const int* __restrict__ positions,
                                short* __restrict__ qfh, short* __restrict__ qfl,
                                short* __restrict__ kfh, short* __restrict__ kfl,
                                short* __restrict__ vbh, short* __restrict__ vbl) {
    int t = blockIdx.x;
    __shared__ float cs[16], sn[16];
    if (threadIdx.x < 16) {
        float invf = powf(10000.f, -(float)(2 * threadIdx.x) / 32.f);
        float fr = (float)positions[t] * invf;
        cs[threadIdx.x] = cosf(fr);
        sn[threadIdx.x] = sinf(fr);
    }
    __syncthreads();
    for (int i = threadIdx.x; i < NH * QKD; i += blockDim.x) {
        int h = i / QKD, d = i % QKD;
        float val;
        if (d < 64) val = q[(size_t)t * 1536 + h * QKD + d];
        else {
            int r = d - 64, pr = r >> 1;
            float x1 = q[(size_t)t * 1536 + h * QKD + 64 + 2 * pr];
            float x2 = q[(size_t)t * 1536 + h * QKD + 64 + 2 * pr + 1];
            val = (r & 1) ? (x1 * sn[pr] + x2 * cs[pr]) : (x1 * cs[pr] - x2 * sn[pr]);
        }
        short hh = f2bf(val);
        qfh[(size_t)t * 1536 + i] = hh;
        qfl[(size_t)t * 1536 + i] = f2bf(val - bf2f(hh));
    }
    for (int i = threadIdx.x; i < NH * QKD; i += blockDim.x) {
        int h = i / QKD, d = i % QKD;
        float val;
        if (d < 64) val = kv[(size_t)t * 2048 + h * 128 + d];
        else {
            int r = d - 64, pr = r >> 1;
            float x1 = qkraw[(size_t)t * 800 + 768 + 2 * pr];
            float x2 = qkraw[(size_t)t * 800 + 768 + 2 * pr + 1];
            val = (r & 1) ? (x1 * sn[pr] + x2 * cs[pr]) : (x1 * cs[pr] - x2 * sn[pr]);
        }
        short hh = f2bf(val);
        kfh[(size_t)t * 1536 + i] = hh;
        kfl[(size_t)t * 1536 + i] = f2bf(val - bf2f(hh));
    }
    for (int i = threadIdx.x; i < NH * VD; i += blockDim.x) {
        int h = i / VD, d = i % VD;
        float val = kv[(size_t)t * 2048 + h * 128 + 64 + d];
        short hh = f2bf(val);
        vbh[(size_t)t * 1024 + i] = hh;
        vbl[(size_t)t * 1024 + i] = f2bf(val - bf2f(hh));
    }
}

// =====================================================================
// MFMA flash attention; blockIdx.x = work item (full q-tile, or one of
// two kt-range partials for qt>=8 — flash-decoding balance). Partials
// write unnormalized O + (m,l); attn_combine merges exactly in f32.
// =====================================================================
__global__ __launch_bounds__(256) void attn_mfma_kernel(const short* __restrict__ qfh, const short* __restrict__ qfl,
                                                        const short* __restrict__ kfh, const short* __restrict__ kfl,
                                                        const short* __restrict__ vbh, const short* __restrict__ vbl,
                                                        short* __restrict__ obh, short* __restrict__ obl,
                                                        float* __restrict__ o_part, float* __restrict__ ml_part) {
    __shared__ short K_hi[64][104], K_lo[64][104];
    __shared__ short Vt_hi[64][72], Vt_lo[64][72];
    __shared__ short P_hi[4][16][72], P_lo[4][16][72];
    const int item = blockIdx.x, h = blockIdx.y;
    int qt, kt0, kt1, part;
    bool full;
    if (item < 8) { qt = item; kt0 = 0; kt1 = qt + 1; full = true; part = 0; }
    else {
        int i = item - 8;
        qt = 8 + (i >> 1);
        part = i & 1;
        int mid = (qt + 1) >> 1;
        full = false;
        kt0 = part ? mid : 0;
        kt1 = part ? (qt + 1) : mid;
    }
    const int tid = threadIdx.x, lane = tid & 63, w = tid >> 6;
    const int g = lane >> 4, li = lane & 15;

    s16x8 q_hi[3], q_lo[3];
    {
        const short* qb_h = qfh + (size_t)(qt * 64 + w * 16 + li) * 1536 + h * QKD;
        const short* qb_l = qfl + (size_t)(qt * 64 + w * 16 + li) * 1536 + h * QKD;
#pragma unroll
        for (int ks = 0; ks < 3; ks++) {
            q_hi[ks] = *(const s16x8*)(qb_h + ks * 32 + g * 8);
            q_lo[ks] = *(const s16x8*)(qb_l + ks * 32 + g * 8);
        }
    }

    f32x4 acc_o[4];
#pragma unroll
    for (int nc = 0; nc < 4; nc++)
#pragma unroll
        for (int r = 0; r < 4; r++) acc_o[nc][r] = 0.f;
    float m4[4] = {-1e30f, -1e30f, -1e30f, -1e30f};
    float l4[4] = {0.f, 0.f, 0.f, 0.f};
    const float scale = 0.102062072616f;

    for (int kt = kt0; kt < kt1; kt++) {
#pragma unroll
        for (int it = 0; it < 3; it++) {
            int cid = it * 256 + tid;
            int key = cid / 12, c = cid % 12;
            *(s16x8*)&K_hi[key][c * 8] = *(const s16x8*)&kfh[(size_t)(kt * 64 + key) * 1536 + h * QKD + c * 8];
            *(s16x8*)&K_lo[key][c * 8] = *(const s16x8*)&kfl[(size_t)(kt * 64 + key) * 1536 + h * QKD + c * 8];
        }
#pragma unroll
        for (int it = 0; it < 2; it++) {
            int cid = it * 256 + tid;
            int key = cid >> 3, vc = cid & 7;
            s16x8 vh = *(const s16x8*)&vbh[(size_t)(kt * 64 + key) * 1024 + h * VD + vc * 8];
            s16x8 vl = *(const s16x8*)&vbl[(size_t)(kt * 64 + key) * 1024 + h * VD + vc * 8];
#pragma unroll
            for (int j = 0; j < 8; j++) {
                Vt_hi[vc * 8 + j][key] = vh[j];
                Vt_lo[vc * 8 + j][key] = vl[j];
            }
        }
        __syncthreads();

        f32x4 acc_s[4];
#pragma unroll
        for (int kc = 0; kc < 4; kc++)
#pragma unroll
            for (int r = 0; r < 4; r++) acc_s[kc][r] = 0.f;
#pragma unroll
        for (int ks = 0; ks < 3; ks++) {
#pragma unroll
            for (int kc = 0; kc < 4; kc++) {
                s16x8 kh = *(const s16x8*)&K_hi[kc * 16 + li][ks * 32 + g * 8];
                s16x8 kl = *(const s16x8*)&K_lo[kc * 16 + li][ks * 32 + g * 8];
                acc_s[kc] = __builtin_amdgcn_mfma_f32_16x16x32_bf16(q_hi[ks], kh, acc_s[kc], 0, 0, 0);
                acc_s[kc] = __builtin_amdgcn_mfma_f32_16x16x32_bf16(q_lo[ks], kh, acc_s[kc], 0, 0, 0);
                acc_s[kc] = __builtin_amdgcn_mfma_f32_16x16x32_bf16(q_hi[ks], kl, acc_s[kc], 0, 0, 0);
            }
        }
#pragma unroll
        for (int kc = 0; kc < 4; kc++)
#pragma unroll
            for (int r = 0; r < 4; r++) acc_s[kc][r] *= scale;
        if (kt == qt) {
#pragma unroll
            for (int kc = 0; kc < 4; kc++) {
                int key = kt * 64 + kc * 16 + li;
#pragma unroll
                for (int r = 0; r < 4; r++) {
                    int qr = qt * 64 + w * 16 + g * 4 + r;
                    if (key > qr) acc_s[kc][r] = -1e30f;
                }
            }
        }
        float tm4[4];
#pragma unroll
        for (int r = 0; r < 4; r++)
            tm4[r] = fmaxf(fmaxf(acc_s[0][r], acc_s[1][r]), fmaxf(acc_s[2][r], acc_s[3][r]));
#pragma unroll
        for (int off = 1; off < 16; off <<= 1)
#pragma unroll
            for (int r = 0; r < 4; r++) tm4[r] = fmaxf(tm4[r], __shfl_xor(tm4[r], off));
        float alpha[4];
#pragma unroll
        for (int r = 0; r < 4; r++) {
            float mn = fmaxf(m4[r], tm4[r]);
            alpha[r] = __expf(m4[r] - mn);
            m4[r] = mn;
        }
        float rs[4] = {0.f, 0.f, 0.f, 0.f};
#pragma unroll
        for (int kc = 0; kc < 4; kc++)
#pragma unroll
            for (int r = 0; r < 4; r++) {
                float p = __expf(acc_s[kc][r] - m4[r]);
                rs[r] += p;
                short hh = f2bf(p);
                P_hi[w][g * 4 + r][kc * 16 + li] = hh;
                P_lo[w][g * 4 + r][kc * 16 + li] = f2bf(p - bf2f(hh));
            }
#pragma unroll
        for (int off = 1; off < 16; off <<= 1)
#pragma unroll
            for (int r = 0; r < 4; r++) rs[r] += __shfl_xor(rs[r], off);
#pragma unroll
        for (int r = 0; r < 4; r++) l4[r] = l4[r] * alpha[r] + rs[r];
#pragma unroll
        for (int nc = 0; nc < 4; nc++)
#pragma unroll
            for (int r = 0; r < 4; r++) acc_o[nc][r] *= alpha[r];
#pragma unroll
        for (int ks = 0; ks < 2; ks++) {
            s16x8 ph = *(const s16x8*)&P_hi[w][li][ks * 32 + g * 8];
            s16x8 pl = *(const s16x8*)&P_lo[w][li][ks * 32 + g * 8];
#pragma unroll
            for (int nc = 0; nc < 4; nc++) {
                s16x8 vh = *(const s16x8*)&Vt_hi[nc * 16 + li][ks * 32 + g * 8];
                s16x8 vl = *(const s16x8*)&Vt_lo[nc * 16 + li][ks * 32 + g * 8];
                acc_o[nc] = __builtin_amdgcn_mfma_f32_16x16x32_bf16(ph, vh, acc_o[nc], 0, 0, 0);
                acc_o[nc] = __builtin_amdgcn_mfma_f32_16x16x32_bf16(pl, vh, acc_o[nc], 0, 0, 0);
                acc_o[nc] = __builtin_amdgcn_mfma_f32_16x16x32_bf16(ph, vl, acc_o[nc], 0, 0, 0);
            }
        }
        __syncthreads();
    }
    if (full) {
        float inv[4];
#pragma unroll
        for (int r = 0; r < 4; r++) inv[r] = 1.f / l4[r];
#pragma unroll
        for (int nc = 0; nc < 4; nc++)
#pragma unroll
            for (int r = 0; r < 4; r++) {
                float o = acc_o[nc][r] * inv[r];
                size_t idx = (size_t)(qt * 64 + w * 16 + g * 4 + r) * 1024 + h * VD + nc * 16 + li;
                short hh = f2bf(o);
                obh[idx] = hh;
                obl[idx] = f2bf(o - bf2f(hh));
            }
    } else {
        // unnormalized O + running (m, l) per row
#pragma unroll
        for (int nc = 0; nc < 4; nc++)
#pragma unroll
            for (int r = 0; r < 4; r++) {
                int t = qt * 64 + w * 16 + g * 4 + r;
                o_part[(((size_t)part * 1024 + t) * 16 + h) * 64 + nc * 16 + li] = acc_o[nc][r];
            }
        if (li == 0) {
#pragma unroll
            for (int r = 0; r < 4; r++) {
                int t = qt * 64 + w * 16 + g * 4 + r;
                size_t o = (((size_t)part * 1024 + t) * 16 + h) * 2;
                ml_part[o] = m4[r];
                ml_part[o + 1] = l4[r];
            }
        }
    }
}

// ---------------- merge two attention partials (rows 512..1023) ----------------
__global__ __launch_bounds__(256) void attn_combine_kernel(const float* __restrict__ o_part,
                                                           const float* __restrict__ ml_part,
                                                           short* __restrict__ obh, short* __restrict__ obl) {
    int t = 512 + blockIdx.x;
    int idx4 = threadIdx.x * 4;      // 0..1020 over h*64+vd
    int h = idx4 >> 6;
    int vd = idx4 & 63;
    size_t mb0 = (((size_t)0 * 1024 + t) * 16 + h) * 2;
    size_t mb1 = (((size_t)1 * 1024 + t) * 16 + h) * 2;
    float m0 = ml_part[mb0], l0 = ml_part[mb0 + 1];
    float m1 = ml_part[mb1], l1 = ml_part[mb1 + 1];
    float ms = fmaxf(m0, m1);
    float a0 = __expf(m0 - ms), a1 = __expf(m1 - ms);
    float inv = 1.f / (l0 * a0 + l1 * a1);
    size_t b0 = (((size_t)0 * 1024 + t) * 16 + h) * 64 + vd;
    size_t b1 = (((size_t)1 * 1024 + t) * 16 + h) * 64 + vd;
#pragma unroll
    for (int j = 0; j < 4; j++) {
        float o = (o_part[b0 + j] * a0 + o_part[b1 + j] * a1) * inv;
        size_t oi = (size_t)t * 1024 + h * VD + vd + j;
        short hh = f2bf(o);
        obh[oi] = hh;
        obl[oi] = f2bf(o - bf2f(hh));
    }
}

// ---------------- fused resid-add + post-rmsnorm + routing ----------------
__global__ __launch_bounds__(256) void fused_post_attn(float* __restrict__ x0, const float* __restrict__ att,
                                                       const float* __restrict__ w, const float* __restrict__ gate_w,
                                                       const float* __restrict__ gate_bias,
                                                       short* __restrict__ h2bf, int* __restrict__ topidx,
                                                       float* __restrict__ topw) {
    int t = blockIdx.x;
    float resid[8];
    float ss = 0.f;
#pragma unroll
    for (int j = 0; j < 8; j++) {
        int i = threadIdx.x + j * 256;
        float v = x0[(size_t)t * HDIM + i] + att[(size_t)t * HDIM + i];
        resid[j] = v;
        x0[(size_t)t * HDIM + i] = v;
        ss += v * v;
    }
    float r = rsqrtf(block_sum(ss) / HDIM + EPSF);
    float acc[8] = {0.f, 0.f, 0.f, 0.f, 0.f, 0.f, 0.f, 0.f};
#pragma unroll
    for (int j = 0; j < 8; j++) {
        int i = threadIdx.x + j * 256;
        float v = resid[j] * r * w[i];
        h2bf[(size_t)t * HDIM + i] = f2bf(v);
        const float* gw = gate_w + (size_t)i * 8;
        float4 g0 = *(const float4*)gw;
        float4 g1 = *(const float4*)(gw + 4);
        acc[0] = fmaf(v, g0.x, acc[0]); acc[1] = fmaf(v, g0.y, acc[1]);
        acc[2] = fmaf(v, g0.z, acc[2]); acc[3] = fmaf(v, g0.w, acc[3]);
        acc[4] = fmaf(v, g1.x, acc[4]); acc[5] = fmaf(v, g1.y, acc[5]);
        acc[6] = fmaf(v, g1.z, acc[6]); acc[7] = fmaf(v, g1.w, acc[7]);
    }
    __shared__ float logits[8];
    for (int e = 0; e < 8; e++) {
        float s = block_sum(acc[e]);
        if (threadIdx.x == 0) logits[e] = s;
    }
    __syncthreads();
    if (threadIdx.x == 0) {
        float sig[8], sc[8];
        for (int e = 0; e < 8; e++) {
            sig[e] = 1.f / (1.f + expf(-logits[e]));
            sc[e] = sig[e] + gate_bias[e];
        }
        int i0 = 0;
        for (int e = 1; e < 8; e++) if (sc[e] > sc[i0]) i0 = e;
        int i1 = -1;
        for (int e = 0; e < 8; e++) if (e != i0 && (i1 < 0 || sc[e] > sc[i1])) i1 = e;
        float w0 = sig[i0], w1 = sig[i1], s = w0 + w1 + 1e-20f;
        topidx[t * 2 + 0] = i0; topidx[t * 2 + 1] = i1;
        topw[t * 2 + 0] = w0 / s; topw[t * 2 + 1] = w1 / s;
    }
}

// ---------------- counting sort + 256-row tile map (+4 shared tiles) ----------------
__global__ void sort_kernel(const int* __restrict__ topidx, int* __restrict__ sorted_t,
                            int* __restrict__ slotpos, int4* __restrict__ tilemap) {
    __shared__ int counts[8], offs[9];
    int wid = threadIdx.x >> 6, lane = threadIdx.x & 63;
    int cnt = 0;
    for (int base = 0; base < 2 * T_; base += 64) {
        int e = topidx[base + lane];
        unsigned long long m = __ballot(e == wid);
        cnt += __popcll(m);
    }
    if (lane == 0) counts[wid] = cnt;
    __syncthreads();
    if (threadIdx.x == 0) {
        offs[0] = 0;
        for (int e = 0; e < 8; e++) offs[e + 1] = offs[e] + counts[e];
    }
    __syncthreads();
    int pos = offs[wid];
    for (int base = 0; base < 2 * T_; base += 64) {
        int sl = base + lane;
        int e = topidx[sl];
        bool match = (e == wid);
        unsigned long long m = __ballot(match);
        if (match) {
            int before = __popcll(m & ((1ull << lane) - 1ull));
            int pp = pos + before;
            sorted_t[pp] = sl >> 1;
            slotpos[sl] = pp;
        }
        pos += __popcll(m);
    }
    __syncthreads();
    if (threadIdx.x == 0) {
        int nt = 0;
        for (int e = 0; e < 8; e++) {
            int c = counts[e], o = offs[e];
            for (int r = 0; r < c; r += 256) {
                tilemap[nt] = make_int4(e, o + r, min(256, c - r), 0);
                nt++;
            }
        }
        for (int r = 0; r < 4; r++) {
            tilemap[nt] = make_int4(8, 2048 + r * 256, 256, 0);
            nt++;
        }
        for (int i = nt; i < MAXTILES; i++) tilemap[i] = make_int4(0, 0, 0, 0);
    }
}

// ---------------- final combine -> f32 out ----------------
__global__ void final_kernel(const float* __restrict__ resid, const float* __restrict__ md,
                             const int* __restrict__ slotpos, const float* __restrict__ topw,
                             float* __restrict__ out) {
    int t = blockIdx.x;
    int p0 = slotpos[t * 2 + 0], p1 = slotpos[t * 2 + 1];
    float w0 = topw[t * 2 + 0] * 2.5f, w1 = topw[t * 2 + 1] * 2.5f;
    const float* mds = md + (size_t)(2048 + t) * HDIM;
    for (int c = threadIdx.x; c < HDIM; c += blockDim.x) {
        float v = resid[(size_t)t * HDIM + c] + mds[c]
                + w0 * md[(size_t)p0 * HDIM + c] + w1 * md[(size_t)p1 * HDIM + c];
        out[(size_t)t * HDIM + c] = v;
    }
}

// ---------------- launcher ----------------
extern "C" void kernel_launch(void* const* d_in, const int* in_sizes, int n_in,
                              void* d_out, int out_size, void* d_ws, size_t ws_size,
                              hipStream_t stream) {
    (void)in_sizes; (void)n_in; (void)out_size; (void)ws_size;
    const int*   input_ids = (const int*)d_in[0];
    const int*   positions = (const int*)d_in[1];
    const float* prev      = (const float*)d_in[2];
    const float* embed     = (const float*)d_in[3];
    const float* enorm_w   = (const float*)d_in[4];
    const float* hnorm_w   = (const float*)d_in[5];
    const float* eh_proj_w = (const float*)d_in[6];
    const float* in_ln_w   = (const float*)d_in[7];
    const float* post_ln_w = (const float*)d_in[8];
    const float* q_a_w     = (const float*)d_in[9];
    const float* q_a_ln_w  = (const float*)d_in[10];
    const float* q_b_w     = (const float*)d_in[11];
    const float* kv_a_w    = (const float*)d_in[12];
    const float* kv_a_ln_w = (const float*)d_in[13];
    const float* kv_b_w    = (const float*)d_in[14];
    const float* o_w       = (const float*)d_in[15];
    const float* gate_w    = (const float*)d_in[16];
    const float* gate_bias = (const float*)d_in[17];
    const float* exp_g     = (const float*)d_in[18];
    const float* exp_u     = (const float*)d_in[19];
    const float* exp_d     = (const float*)d_in[20];
    const float* sh_g      = (const float*)d_in[21];
    const float* sh_u      = (const float*)d_in[22];
    const float* sh_d      = (const float*)d_in[23];
    float* out = (float*)d_out;

    float* ws = (float*)d_ws;
    short* catH  = (short*)(ws + OF_CATH);
    short* catL  = (short*)(ws + OF_CATL);
    float* x0    = ws + OF_X0;
    short* mact  = (short*)(ws + OF_MACT);
    short* hH    = (short*)(ws + OF_HH);
    short* hL    = (short*)(ws + OF_HL);
    float* qbuf  = ws + OF_QBUF;
    float* kvbuf = ws + OF_KVBUF;
    short* qaH   = (short*)(ws + OF_QAH);
    short* qaL   = (short*)(ws + OF_QAL);
    short* kvcnH = (short*)(ws + OF_KVCNH);
    short* kvcnL = (short*)(ws + OF_KVCNL);
    short* qfH   = (short*)(ws + OF_QFH);
    short* qfL   = (short*)(ws + OF_QFL);
    short* kfH   = (short*)(ws + OF_KFH);
    short* kfL   = (short*)(ws + OF_KFL);
    short* vbH   = (short*)(ws + OF_VBH);
    short* vbL   = (short*)(ws + OF_VBL);
    short* obH   = (short*)(ws + OF_OBH);
    short* obL   = (short*)(ws + OF_OBL);
    float* att   = ws + OF_ATT;
    short* h2bf  = (short*)(ws + OF_H2BF);
    float* md    = ws + OF_MD;
    float* qkraw = ws + OF_QKRAW;
    short* batH  = (short*)(ws + OF_BATH);
    short* batL  = (short*)(ws + OF_BATL);
    float* opart = ws + OF_OPART;
    float* mlpart= ws + OF_MLPART;
    int*   ri       = (int*)(ws + OF_ROUT);
    int*   topidx   = ri;
    int*   sorted_t = ri + 2048;
    int*   slotpos  = ri + 4096;
    int4*  tilemap  = (int4*)(ri + 6144);
    float* topw     = (float*)(ri + 6144 + 4 * MAXTILES);
    short* ehTH  = (short*)(ws + OF_EHTH);
    short* ehTL  = (short*)(ws + OF_EHTL);
    short* qbTH  = (short*)(ws + OF_QBTH);
    short* qbTL  = (short*)(ws + OF_QBTL);
    short* kvbTH = (short*)(ws + OF_KVBTH);
    short* kvbTL = (short*)(ws + OF_KVBTL);
    short* owTH  = (short*)(ws + OF_OWTH);
    short* owTL  = (short*)(ws + OF_OWTL);

    dim3 blk(256);

    // 0. one-launch weight transpose+split (6 jobs)
    TJobs J;
    J.W[0] = eh_proj_w; J.Whi[0] = ehTH; J.Wlo[0] = ehTL; J.K[0] = 4096; J.N[0] = 2048; J.nbx[0] = 64;
    J.W[1] = q_a_w; J.Whi[1] = batH; J.Wlo[1] = batL; J.K[1] = 2048; J.N[1] = 512; J.nbx[1] = 32;
    J.W[2] = kv_a_w; J.Whi[2] = batH + (size_t)512 * 2048; J.Wlo[2] = batL + (size_t)512 * 2048;
    J.K[2] = 2048; J.N[2] = 288; J.nbx[2] = 32;
    J.W[3] = q_b_w; J.Whi[3] = qbTH; J.Wlo[3] = qbTL; J.K[3] = 512; J.N[3] = 1536; J.nbx[3] = 8;
    J.W[4] = kv_b_w; J.Whi[4] = kvbTH; J.Wlo[4] = kvbTL; J.K[4] = 256; J.N[4] = 2048; J.nbx[4] = 4;
    J.W[5] = o_w; J.Whi[5] = owTH; J.Wlo[5] = owTL; J.K[5] = 1024; J.N[5] = 2048; J.nbx[5] = 16;
    int nby[6] = {32, 8, 5, 24, 32, 32};
    J.base[0] = 0;
    for (int i = 0; i < 6; i++) J.base[i + 1] = J.base[i] + J.nbx[i] * nby[i];
    transpose_multi_kernel<<<J.base[6], blk, 0, stream>>>(J);

    // 1. embed + rmsnorm + concat
    embed_cat_kernel<<<T_, blk, 0, stream>>>(input_ids, embed, enorm_w, prev, hnorm_w, catH, catL);
    // 2. x0 = cat @ eh_proj
    gemm_planes<true><<<dim3(32, 8), blk, 0, stream>>>(catH, catL, ehTH, ehTL, x0, T_, 2048, 4096);
    // 3. h = rmsnorm(x0)
    rmsnorm_kernel<<<T_, blk, 0, stream>>>(x0, 2048, 2048, in_ln_w, nullptr, hH, hL, 2048);
    // 4. qkraw = h @ [q_a | kv_a]  (N=800)
    gemm_planes<true><<<dim3(13, 8), blk, 0, stream>>>(hH, hL, batH, batL, qkraw, T_, 800, 2048);
    // 5. fused rmsnorms (q_a_ln + kv_a_ln)
    rmsnorm_qkv_kernel<<<T_, blk, 0, stream>>>(qkraw, q_a_ln_w, kv_a_ln_w, qaH, qaL, kvcnH, kvcnL);
    // 6. q = qa @ q_b
    gemm_planes<true><<<dim3(24, 8), blk, 0, stream>>>(qaH, qaL, qbTH, qbTL, qbuf, T_, 1536, 512);
    // 7. kv = kvcn @ kv_b
    gemm_planes<true><<<dim3(32, 8), blk, 0, stream>>>(kvcnH, kvcnL, kvbTH, kvbTL, kvbuf, T_, 2048, 256);
    // 8. rope + planes (k_pe from qkraw cols 768-799)
    prep_qkv_kernel<<<T_, blk, 0, stream>>>(qbuf, qkraw, kvbuf, positions, qfH, qfL, kfH, kfL, vbH, vbL);
    // 9. flash attention (balanced items: 8 full + 16 partials)
    attn_mfma_kernel<<<dim3(NITEMS, NH), blk, 0, stream>>>(qfH, qfL, kfH, kfL, vbH, vbL, obH, obL, opart, mlpart);
    // 9b. merge partials for rows 512..1023
    attn_combine_kernel<<<512, blk, 0, stream>>>(opart, mlpart, obH, obL);
    // 10. attn_out = ob @ o_w
    gemm_planes<true><<<dim3(32, 8), blk, 0, stream>>>(obH, obL, owTH, owTL, att, T_, 2048, 1024);
    // 11. fused resid + rmsnorm + routing
    fused_post_attn<<<T_, blk, 0, stream>>>(x0, att, post_ln_w, gate_w, gate_bias, h2bf, topidx, topw);
    // 12. sort (256-row tiles + 4 shared tiles)
    sort_kernel<<<1, 512, 0, stream>>>(topidx, sorted_t, slotpos, tilemap);
    // 13. MoE gate+up fused with silu -> mact (BM=256, inline gather)
    moe_gateup<<<dim3(16, MAXTILES), dim3(512), 0, stream>>>(h2bf, sorted_t, exp_g, exp_u, sh_g, sh_u, mact, tilemap, 2048, 1024);
    // 14. MoE down (BM=256)
    moe_down<<<dim3(32, MAXTILES), dim3(512), 0, stream>>>(mact, exp_d, sh_d, md, tilemap, 1024, 2048);
    // 15. final combine
    final_kernel<<<T_, blk, 0, stream>>>(x0, md, slotpos, topw, out);
}

// Round 17
// 502.098 us; speedup vs baseline: 1.4907x; 1.0131x over previous
//
#include <hip/hip_runtime.h>
#include <hip/hip_bf16.h>
#include <math.h>

constexpr int T_ = 1024;
constexpr int HDIM = 2048;
constexpr int NH = 16;
constexpr int QKD = 96;
constexpr int VD = 64;
constexpr int MAXTILES = 32;
constexpr int NITEMS = 24;     // 8 full q-tiles + 8 split q-tiles x 2 partials
constexpr float EPSF = 1e-6f;

using f32x4 = __attribute__((ext_vector_type(4))) float;
using s16x8 = __attribute__((ext_vector_type(8))) short;
using s16x4 = __attribute__((ext_vector_type(4))) short;

// ---------------- workspace layout (float offsets; ws is ~1 GB) ----------------
constexpr size_t OF_CATH  = 0;                 // bf16 T*4096
constexpr size_t OF_CATL  = 2097152;
constexpr size_t OF_X0    = 4194304;           // f32 T*2048
constexpr size_t OF_MACT  = 6291456;           // bf16 3072*1024
constexpr size_t OF_HH    = 8388608;           // bf16 T*2048
constexpr size_t OF_HL    = 9437184;
constexpr size_t OF_QBUF  = 11010048;          // f32 T*1536
constexpr size_t OF_KVBUF = 12877824;          // f32 T*2048
constexpr size_t OF_QAH   = 14974976;          // bf16 T*512
constexpr size_t OF_QAL   = 15237120;
constexpr size_t OF_KVCNH = 15499264;          // bf16 T*256
constexpr size_t OF_KVCNL = 15630336;
constexpr size_t OF_QFH   = 15761408;          // bf16 T*1536
constexpr size_t OF_QFL   = 16547840;
constexpr size_t OF_KFH   = 17334272;
constexpr size_t OF_KFL   = 18120704;
constexpr size_t OF_VBH   = 18907136;          // bf16 T*1024
constexpr size_t OF_VBL   = 19431424;
constexpr size_t OF_OBH   = 19955712;          // bf16 T*1024
constexpr size_t OF_OBL   = 20480000;
constexpr size_t OF_ATT   = 21004288;          // f32 T*2048
constexpr size_t OF_H2BF  = 23101440;          // bf16 T*2048
constexpr size_t OF_ROUT  = 24674304;          // ints
// weight planes (bf16)
constexpr size_t OF_EHTH  = 24682752;          // [2048][4096]
constexpr size_t OF_EHTL  = 28877056;
constexpr size_t OF_QBTH  = 34119936;          // [1536][512]
constexpr size_t OF_QBTL  = 34513152;
constexpr size_t OF_KVBTH = 35561728;          // [2048][256]
constexpr size_t OF_KVBTL = 35823872;
constexpr size_t OF_OWTH  = 36086016;          // [2048][1024]
constexpr size_t OF_OWTL  = 37134592;
constexpr size_t OF_MD    = 38183168;          // bf16 3072*2048 = 3145728 floats (ends 41328896)
constexpr size_t OF_QKRAW = 44474624;          // f32 [1024][800] (ends 45293824)
constexpr size_t OF_BATH  = 45293824;          // bf16 [832][2048] (ends 46145792)
constexpr size_t OF_BATL  = 46145792;          // bf16 [832][2048] (ends 46997760)
constexpr size_t OF_OPART = 46997760;          // f32 [2][1024][16][64] (ends 49094912)
constexpr size_t OF_MLPART= 49094912;          // f32 [2][1024][16][2]  (ends 49160448)

// ---------------- helpers ----------------
__device__ __forceinline__ short f2bf(float f) {
    union { float f; unsigned u; } x; x.f = f;
    unsigned r = x.u + 0x7fffu + ((x.u >> 16) & 1u);
    return (short)(r >> 16);
}
__device__ __forceinline__ float bf2f(short h) {
    union { unsigned u; float f; } x; x.u = ((unsigned)(unsigned short)h) << 16; return x.f;
}
// LDS swizzle (plane GEMM): row stride 64 shorts; chunk ^= row&7
__device__ __forceinline__ int swz(int r, int k) {
    return (r << 6) + ((((k >> 3) ^ (r & 7)) << 3) | (k & 7));
}
// async global->LDS, 16 B per lane; LDS dest = wave-uniform base + lane*16
__device__ __forceinline__ void gload16(const void* g, void* l) {
    __builtin_amdgcn_global_load_lds((__attribute__((address_space(1))) void*)g,
                                     (__attribute__((address_space(3))) void*)l, 16, 0, 0);
}

__device__ __forceinline__ float block_sum(float v) {
    __shared__ float sbuf[9];
    int lane = threadIdx.x & 63;
    int wid  = threadIdx.x >> 6;
#pragma unroll
    for (int off = 32; off > 0; off >>= 1) v += __shfl_down(v, off);
    __syncthreads();
    if (lane == 0) sbuf[wid] = v;
    __syncthreads();
    if (threadIdx.x == 0) {
        float s = 0.f;
        int nw = blockDim.x >> 6;
        for (int i = 0; i < nw; i++) s += sbuf[i];
        sbuf[8] = s;
    }
    __syncthreads();
    return sbuf[8];
}

// ---------------- multi-job weight transpose + split ----------------
struct TJobs {
    const float* W[6];
    short* Whi[6];
    short* Wlo[6];
    int K[6];
    int N[6];
    int nbx[6];
    int base[7];
};

__global__ void transpose_multi_kernel(TJobs J) {
    int bid = blockIdx.x;
    int j = 0;
#pragma unroll
    for (int i = 1; i < 6; i++) if (bid >= J.base[i]) j = i;
    int local = bid - J.base[j];
    int K = J.K[j], N = J.N[j];
    int bx = local % J.nbx[j], by = local / J.nbx[j];
    const float* W = J.W[j];
    short* Whi = J.Whi[j];
    short* Wlo = J.Wlo[j];

    __shared__ float tile[64][65];
    int k0 = bx * 64, n0 = by * 64;
    int tn = threadIdx.x & 63;
    int tk4 = threadIdx.x >> 6;
#pragma unroll 4
    for (int i = 0; i < 16; i++) {
        int kk = tk4 * 16 + i;
        int gn = n0 + tn;
        tile[kk][tn] = (gn < N) ? W[(size_t)(k0 + kk) * N + gn] : 0.f;
    }
    __syncthreads();
    int on = threadIdx.x >> 2;
    int oc = threadIdx.x & 3;
#pragma unroll 4
    for (int i = 0; i < 16; i++) {
        int kk = oc * 16 + i;
        float v = tile[kk][on];
        short hh = f2bf(v);
        size_t o = (size_t)(n0 + on) * K + k0 + kk;
        Whi[o] = hh;
        Wlo[o] = f2bf(v - bf2f(hh));
    }
}

// ---------------- embedding + rmsnorm + concat -> split planes ----------------
__global__ void embed_cat_kernel(const int* __restrict__ ids, const float* __restrict__ embed,
                                 const float* __restrict__ enorm, const float* __restrict__ prev,
                                 const float* __restrict__ hnorm, short* __restrict__ ch,
                                 short* __restrict__ cl) {
    int t = blockIdx.x;
    const float* e = embed + (size_t)ids[t] * HDIM;
    float ss = 0.f;
    for (int i = threadIdx.x; i < HDIM; i += blockDim.x) { float v = e[i]; ss += v * v; }
    float r = rsqrtf(block_sum(ss) / HDIM + EPSF);
    for (int i = threadIdx.x; i < HDIM; i += blockDim.x) {
        float v = e[i] * r * enorm[i];
        short hh = f2bf(v);
        ch[(size_t)t * 4096 + i] = hh;
        cl[(size_t)t * 4096 + i] = f2bf(v - bf2f(hh));
    }
    const float* p = prev + (size_t)t * HDIM;
    ss = 0.f;
    for (int i = threadIdx.x; i < HDIM; i += blockDim.x) { float v = p[i]; ss += v * v; }
    r = rsqrtf(block_sum(ss) / HDIM + EPSF);
    for (int i = threadIdx.x; i < HDIM; i += blockDim.x) {
        float v = p[i] * r * hnorm[i];
        short hh = f2bf(v);
        ch[(size_t)t * 4096 + 2048 + i] = hh;
        cl[(size_t)t * 4096 + 2048 + i] = f2bf(v - bf2f(hh));
    }
}

// ---------------- rmsnorm (f32 / hi / lo outputs) ----------------
__global__ void rmsnorm_kernel(const float* __restrict__ in, int in_stride, int width,
                               const float* __restrict__ w, float* __restrict__ outf,
                               short* __restrict__ outh, short* __restrict__ outl, int out_stride) {
    int t = blockIdx.x;
    const float* x = in + (size_t)t * in_stride;
    float ss = 0.f;
    for (int i = threadIdx.x; i < width; i += blockDim.x) { float v = x[i]; ss += v * v; }
    float r = rsqrtf(block_sum(ss) / width + EPSF);
    size_t ob = (size_t)t * out_stride;
    for (int i = threadIdx.x; i < width; i += blockDim.x) {
        float v = x[i] * r * w[i];
        if (outf) outf[ob + i] = v;
        if (outh) {
            short hh = f2bf(v);
            outh[ob + i] = hh;
            if (outl) outl[ob + i] = f2bf(v - bf2f(hh));
        }
    }
}

// ---------------- fused rmsnorm for qkraw: q_a (cols 0-511) + kv_c (cols 512-767) ----------------
__global__ void rmsnorm_qkv_kernel(const float* __restrict__ qkraw, const float* __restrict__ wq,
                                   const float* __restrict__ wkv, short* __restrict__ qaH,
                                   short* __restrict__ qaL, short* __restrict__ kvcnH,
                                   short* __restrict__ kvcnL) {
    int t = blockIdx.x;
    const float* row = qkraw + (size_t)t * 800;
    float ss = 0.f;
    for (int i = threadIdx.x; i < 512; i += blockDim.x) { float v = row[i]; ss += v * v; }
    float r = rsqrtf(block_sum(ss) / 512.f + EPSF);
    for (int i = threadIdx.x; i < 512; i += blockDim.x) {
        float v = row[i] * r * wq[i];
        short hh = f2bf(v);
        qaH[(size_t)t * 512 + i] = hh;
        qaL[(size_t)t * 512 + i] = f2bf(v - bf2f(hh));
    }
    ss = 0.f;
    for (int i = threadIdx.x; i < 256; i += blockDim.x) { float v = row[512 + i]; ss += v * v; }
    r = rsqrtf(block_sum(ss) / 256.f + EPSF);
    for (int i = threadIdx.x; i < 256; i += blockDim.x) {
        float v = row[512 + i] * r * wkv[i];
        short hh = f2bf(v);
        kvcnH[(size_t)t * 256 + i] = hh;
        kvcnL[(size_t)t * 256 + i] = f2bf(v - bf2f(hh));
    }
}

// =====================================================================
// Plane GEMM (verified): BM=128 BN=64 BK=64, gload16 staging
// with inverse-swizzled global source, swizzled LDS reads.
// The device body is shared; gemm_planes is the single-problem wrapper,
// gemm_planes_dual runs two independent problems selected by blockIdx.z.
// =====================================================================
template<bool SPLIT>
__device__ __forceinline__ void gemm_planes_body(const short* Ahi, const short* Alo,
                                                 const short* Bhi, const short* Blo,
                                                 float* C, int M, int N, int K,
                                                 int bx, int by) {
    __shared__ short As[SPLIT ? 2 : 1][128 * 64];
    __shared__ short Bs[SPLIT ? 2 : 1][64 * 64];
    const int tid = threadIdx.x;
    const int lane = tid & 63, wid = tid >> 6;
    const int g = lane >> 4, li = lane & 15;
    const int wm = wid >> 1, wn = wid & 1;
    const int row0 = by * 128, col0 = bx * 64;

    f32x4 acc[4][2];
#pragma unroll
    for (int mi = 0; mi < 4; mi++)
#pragma unroll
        for (int ni = 0; ni < 2; ni++)
#pragma unroll
            for (int r = 0; r < 4; r++) acc[mi][ni][r] = 0.f;

    for (int k0 = 0; k0 < K; k0 += 64) {
#pragma unroll
        for (int j = 0; j < 4; j++) {
            int blkI = wid * 4 + j;
            int cid = blkI * 64 + lane;
            int r = cid >> 3, c = (cid & 7) ^ (r & 7);
            gload16(&Ahi[(size_t)(row0 + r) * K + k0 + c * 8], &As[0][blkI * 512]);
            if constexpr (SPLIT)
                gload16(&Alo[(size_t)(row0 + r) * K + k0 + c * 8], &As[1][blkI * 512]);
        }
#pragma unroll
        for (int j = 0; j < 2; j++) {
            int blkI = wid * 2 + j;
            int cid = blkI * 64 + lane;
            int r = cid >> 3, c = (cid & 7) ^ (r & 7);
            gload16(&Bhi[(size_t)(col0 + r) * K + k0 + c * 8], &Bs[0][blkI * 512]);
            if constexpr (SPLIT)
                gload16(&Blo[(size_t)(col0 + r) * K + k0 + c * 8], &Bs[1][blkI * 512]);
        }
        __syncthreads();
#pragma unroll
        for (int kk = 0; kk < 64; kk += 32) {
            s16x8 ah[4], bh[2];
#pragma unroll
            for (int mi = 0; mi < 4; mi++) ah[mi] = *(const s16x8*)&As[0][swz(wm * 64 + mi * 16 + li, kk + g * 8)];
#pragma unroll
            for (int ni = 0; ni < 2; ni++) bh[ni] = *(const s16x8*)&Bs[0][swz(wn * 32 + ni * 16 + li, kk + g * 8)];
            if constexpr (SPLIT) {
                s16x8 al[4], bl[2];
#pragma unroll
                for (int mi = 0; mi < 4; mi++) al[mi] = *(const s16x8*)&As[1][swz(wm * 64 + mi * 16 + li, kk + g * 8)];
#pragma unroll
                for (int ni = 0; ni < 2; ni++) bl[ni] = *(const s16x8*)&Bs[1][swz(wn * 32 + ni * 16 + li, kk + g * 8)];
#pragma unroll
                for (int mi = 0; mi < 4; mi++)
#pragma unroll
                    for (int ni = 0; ni < 2; ni++) {
                        acc[mi][ni] = __builtin_amdgcn_mfma_f32_16x16x32_bf16(ah[mi], bh[ni], acc[mi][ni], 0, 0, 0);
                        acc[mi][ni] = __builtin_amdgcn_mfma_f32_16x16x32_bf16(al[mi], bh[ni], acc[mi][ni], 0, 0, 0);
                        acc[mi][ni] = __builtin_amdgcn_mfma_f32_16x16x32_bf16(ah[mi], bl[ni], acc[mi][ni], 0, 0, 0);
                    }
            } else {
#pragma unroll
                for (int mi = 0; mi < 4; mi++)
#pragma unroll
                    for (int ni = 0; ni < 2; ni++)
                        acc[mi][ni] = __builtin_amdgcn_mfma_f32_16x16x32_bf16(ah[mi], bh[ni], acc[mi][ni], 0, 0, 0);
            }
        }
        __syncthreads();
    }
#pragma unroll
    for (int mi = 0; mi < 4; mi++)
#pragma unroll
        for (int ni = 0; ni < 2; ni++) {
            int gc = col0 + wn * 32 + ni * 16 + li;
            if (gc < N) {
#pragma unroll
                for (int r = 0; r < 4; r++) {
                    int gr = row0 + wm * 64 + mi * 16 + g * 4 + r;
                    C[(size_t)gr * N + gc] = acc[mi][ni][r];
                }
            }
        }
}

template<bool SPLIT>
__global__ __launch_bounds__(256) void gemm_planes(const short* __restrict__ Ahi, const short* __restrict__ Alo,
                                                   const short* __restrict__ Bhi, const short* __restrict__ Blo,
                                                   float* __restrict__ C, int M, int N, int K) {
    gemm_planes_body<SPLIT>(Ahi, Alo, Bhi, Blo, C, M, N, K, blockIdx.x, blockIdx.y);
}

// two split-GEMM problems in one launch, selected by blockIdx.z
__global__ __launch_bounds__(256) void gemm_planes_dual(
        const short* __restrict__ A0h, const short* __restrict__ A0l,
        const short* __restrict__ B0h, const short* __restrict__ B0l,
        float* __restrict__ C0, int N0, int K0, int nx0,
        const short* __restrict__ A1h, const short* __restrict__ A1l,
        const short* __restrict__ B1h, const short* __restrict__ B1l,
        float* __restrict__ C1, int N1, int K1, int nx1) {
    if (blockIdx.z == 0) {
        if ((int)blockIdx.x >= nx0) return;
        gemm_planes_body<true>(A0h, A0l, B0h, B0l, C0, T_, N0, K0, blockIdx.x, blockIdx.y);
    } else {
        if ((int)blockIdx.x >= nx1) return;
        gemm_planes_body<true>(A1h, A1l, B1h, B1l, C1, T_, N1, K1, blockIdx.x, blockIdx.y);
    }
}

// =====================================================================
// MoE gate+up GEMM + silu epilogue; BM=256, 512 threads (8 waves 4m x 2n).
// =====================================================================
__global__ __launch_bounds__(512) void moe_gateup(const short* __restrict__ h2bf, const int* __restrict__ sorted_t,
                                                  const float* __restrict__ Wg, const float* __restrict__ Wu,
                                                  const float* __restrict__ Sg, const float* __restrict__ Su,
                                                  short* __restrict__ Cact, const int4* __restrict__ tilemap,
                                                  int K, int N) {
    int4 tm = tilemap[blockIdx.y];
    int nrows = tm.z;
    if (nrows == 0) return;
    const float* Bg = (tm.x < 8) ? Wg + (size_t)tm.x * K * N : Sg;
    const float* Bu = (tm.x < 8) ? Wu + (size_t)tm.x * K * N : Su;

    __shared__ short As[256 * 64];
    alignas(16) __shared__ short Bgs[64][72];
    alignas(16) __shared__ short Bus[64][72];
    const int tid = threadIdx.x;
    const int lane = tid & 63, wid = tid >> 6;
    const int g = lane >> 4, li = lane & 15;
    const int wm = wid >> 1, wn = wid & 1;
    const int col0 = blockIdx.x * 64;

    int tokens[4];
#pragma unroll
    for (int j = 0; j < 4; j++) {
        int blkI = wid * 4 + j;
        int cid = blkI * 64 + lane;
        int r = cid >> 3;
        int slot = tm.y + r;
        tokens[j] = (slot < 2048) ? sorted_t[slot] : (slot - 2048);
    }

    f32x4 accg[4][2], accu[4][2];
#pragma unroll
    for (int mi = 0; mi < 4; mi++)
#pragma unroll
        for (int ni = 0; ni < 2; ni++)
#pragma unroll
            for (int r = 0; r < 4; r++) { accg[mi][ni][r] = 0.f; accu[mi][ni][r] = 0.f; }

    const int t2 = tid & 255;
    const int skb = (t2 >> 4) << 2, snb = (t2 & 15) << 2;

    for (int k0 = 0; k0 < K; k0 += 64) {
#pragma unroll
        for (int j = 0; j < 4; j++) {
            int blkI = wid * 4 + j;
            int cid = blkI * 64 + lane;
            int r = cid >> 3, c = (cid & 7) ^ (r & 7);
            gload16(&h2bf[(size_t)tokens[j] * K + k0 + c * 8], &As[blkI * 512]);
        }
        {
            const float* B = (tid < 256) ? Bg : Bu;
            short (*Bst)[72] = (tid < 256) ? Bgs : Bus;
            float4 r4[4];
#pragma unroll
            for (int kk = 0; kk < 4; kk++)
                r4[kk] = *(const float4*)(B + (size_t)(k0 + skb + kk) * N + col0 + snb);
#pragma unroll
            for (int n = 0; n < 4; n++) {
                s16x4 w4;
                w4[0] = f2bf((&r4[0].x)[n]); w4[1] = f2bf((&r4[1].x)[n]);
                w4[2] = f2bf((&r4[2].x)[n]); w4[3] = f2bf((&r4[3].x)[n]);
                *(s16x4*)&Bst[snb + n][skb] = w4;
            }
        }
        __syncthreads();
#pragma unroll
        for (int kk = 0; kk < 64; kk += 32) {
            s16x8 a[4], bg2[2], bu2[2];
#pragma unroll
            for (int mi = 0; mi < 4; mi++) a[mi] = *(const s16x8*)&As[swz(wm * 64 + mi * 16 + li, kk + g * 8)];
#pragma unroll
            for (int ni = 0; ni < 2; ni++) {
                bg2[ni] = *(const s16x8*)&Bgs[wn * 32 + ni * 16 + li][kk + g * 8];
                bu2[ni] = *(const s16x8*)&Bus[wn * 32 + ni * 16 + li][kk + g * 8];
            }
#pragma unroll
            for (int mi = 0; mi < 4; mi++)
#pragma unroll
                for (int ni = 0; ni < 2; ni++) {
                    accg[mi][ni] = __builtin_amdgcn_mfma_f32_16x16x32_bf16(a[mi], bg2[ni], accg[mi][ni], 0, 0, 0);
                    accu[mi][ni] = __builtin_amdgcn_mfma_f32_16x16x32_bf16(a[mi], bu2[ni], accu[mi][ni], 0, 0, 0);
                }
        }
        __syncthreads();
    }
#pragma unroll
    for (int mi = 0; mi < 4; mi++)
#pragma unroll
        for (int ni = 0; ni < 2; ni++) {
            int gc = col0 + wn * 32 + ni * 16 + li;
#pragma unroll
            for (int r = 0; r < 4; r++) {
                int gr = wm * 64 + mi * 16 + g * 4 + r;
                if (gr < nrows) {
                    float x = accg[mi][ni][r], u = accu[mi][ni][r];
                    Cact[(size_t)(tm.y + gr) * N + gc] = f2bf((x / (1.f + expf(-x))) * u);
                }
            }
        }
}

// =====================================================================
// MoE down GEMM; BM=256, 512 threads; out md bf16 (post-routing budget).
// =====================================================================
__global__ __launch_bounds__(512) void moe_down(const short* __restrict__ Abase, const float* __restrict__ Wall,
                                                const float* __restrict__ Sd, short* __restrict__ Cbase,
                                                const int4* __restrict__ tilemap, int K, int N) {
    int4 tm = tilemap[blockIdx.y];
    int nrows = tm.z;
    if (nrows == 0) return;
    const short* A = Abase + (size_t)tm.y * K;
    short* C = Cbase + (size_t)tm.y * N;
    const float* B = (tm.x < 8) ? Wall + (size_t)tm.x * K * N : Sd;

    __shared__ short As[256 * 64];
    alignas(16) __shared__ short Bs[64][72];
    const int tid = threadIdx.x;
    const int lane = tid & 63, wid = tid >> 6;
    const int g = lane >> 4, li = lane & 15;
    const int wm = wid >> 1, wn = wid & 1;
    const int col0 = blockIdx.x * 64;

    f32x4 acc[4][2];
#pragma unroll
    for (int mi = 0; mi < 4; mi++)
#pragma unroll
        for (int ni = 0; ni < 2; ni++)
#pragma unroll
            for (int r = 0; r < 4; r++) acc[mi][ni][r] = 0.f;

    const int skb = (tid >> 4) << 2, snb = (tid & 15) << 2;

    for (int k0 = 0; k0 < K; k0 += 64) {
#pragma unroll
        for (int j = 0; j < 4; j++) {
            int blkI = wid * 4 + j;
            int cid = blkI * 64 + lane;
            int r = cid >> 3, c = (cid & 7) ^ (r & 7);
            gload16(&A[(size_t)r * K + k0 + c * 8], &As[blkI * 512]);
        }
        if (tid < 256) {
            float4 r4[4];
#pragma unroll
            for (int kk = 0; kk < 4; kk++)
                r4[kk] = *(const float4*)(B + (size_t)(k0 + skb + kk) * N + col0 + snb);
#pragma unroll
            for (int n = 0; n < 4; n++) {
                s16x4 w4;
                w4[0] = f2bf((&r4[0].x)[n]); w4[1] = f2bf((&r4[1].x)[n]);
                w4[2] = f2bf((&r4[2].x)[n]); w4[3] = f2bf((&r4[3].x)[n]);
                *(s16x4*)&Bs[snb + n][skb] = w4;
            }
        }
        __syncthreads();
#pragma unroll
        for (int kk = 0; kk < 64; kk += 32) {
            s16x8 a[4], b[2];
#pragma unroll
            for (int mi = 0; mi < 4; mi++) a[mi] = *(const s16x8*)&As[swz(wm * 64 + mi * 16 + li, kk + g * 8)];
#pragma unroll
            for (int ni = 0; ni < 2; ni++) b[ni] = *(const s16x8*)&Bs[wn * 32 + ni * 16 + li][kk + g * 8];
#pragma unroll
            for (int mi = 0; mi < 4; mi++)
#pragma unroll
                for (int ni = 0; ni < 2; ni++)
                    acc[mi][ni] = __builtin_amdgcn_mfma_f32_16x16x32_bf16(a[mi], b[ni], acc[mi][ni], 0, 0, 0);
        }
        __syncthreads();
    }
#pragma unroll
    for (int mi = 0; mi < 4; mi++)
#pragma unroll
        for (int ni = 0; ni < 2; ni++) {
            int gc = col0 + wn * 32 + ni * 16 + li;
#pragma unroll
            for (int r = 0; r < 4; r++) {
                int gr = wm * 64 + mi * 16 + g * 4 + r;
                if (gr < nrows) C[(size_t)gr * N + gc] = f2bf(acc[mi][ni][r]);
            }
        }
}

// ---------------- RoPE + build qf/kf/v as split planes ----------------
__global__ void prep_qkv_kernel(const float* __restrict__ q, const float* __restrict__ qkraw,
                                const float* __restrict__ kv, const int* __restrict__ positions,
                                short* __restrict__ qfh, short* __restrict__ qfl,
                                short* __restrict__ kfh, short* __restrict__ kfl,
                                short* __restrict__ vbh, short* __restrict__ vbl) {
    int t = blockIdx.x;
    __shared__ float cs[16], sn[16];
    if (threadIdx.x < 16) {
        float invf = powf(10000.f, -(float)(2 * threadIdx.x) / 32.f);
        float fr = (float)positions[t] * invf;
        cs[threadIdx.x] = cosf(fr);
        sn[threadIdx.x] = sinf(fr);
    }
    __syncthreads();
    for (int i = threadIdx.x; i < NH * QKD; i += blockDim.x) {
        int h = i / QKD, d = i % QKD;
        float val;
        if (d < 64) val = q[(size_t)t * 1536 + h * QKD + d];
        else {
            int r = d - 64, pr = r >> 1;
            float x1 = q[(size_t)t * 1536 + h * QKD + 64 + 2 * pr];
            float x2 = q[(size_t)t * 1536 + h * QKD + 64 + 2 * pr + 1];
            val = (r & 1) ? (x1 * sn[pr] + x2 * cs[pr]) : (x1 * cs[pr] - x2 * sn[pr]);
        }
        short hh = f2bf(val);
        qfh[(size_t)t * 1536 + i] = hh;
        qfl[(size_t)t * 1536 + i] = f2bf(val - bf2f(hh));
    }
    for (int i = threadIdx.x; i < NH * QKD; i += blockDim.x) {
        int h = i / QKD, d = i % QKD;
        float val;
        if (d < 64) val = kv[(size_t)t * 2048 + h * 128 + d];
        else {
            int r = d - 64, pr = r >> 1;
            float x1 = qkraw[(size_t)t * 800 + 768 + 2 * pr];
            float x2 = qkraw[(size_t)t * 800 + 768 + 2 * pr + 1];
            val = (r & 1) ? (x1 * sn[pr] + x2 * cs[pr]) : (x1 * cs[pr] - x2 * sn[pr]);
        }
        short hh = f2bf(val);
        kfh[(size_t)t * 1536 + i] = hh;
        kfl[(size_t)t * 1536 + i] = f2bf(val - bf2f(hh));
    }
    for (int i = threadIdx.x; i < NH * VD; i += blockDim.x) {
        int h = i / VD, d = i % VD;
        float val = kv[(size_t)t * 2048 + h * 128 + 64 + d];
        short hh = f2bf(val);
        vbh[(size_t)t * 1024 + i] = hh;
        vbl[(size_t)t * 1024 + i] = f2bf(val - bf2f(hh));
    }
}

// =====================================================================
// MFMA flash attention; blockIdx.x = work item (full q-tile, or one of
// two kt-range partials for qt>=8). Partials write unnormalized O+(m,l).
// =====================================================================
__global__ __launch_bounds__(256) void attn_mfma_kernel(const short* __restrict__ qfh, const short* __restrict__ qfl,
                                                        const short* __restrict__ kfh, const short* __restrict__ kfl,
                                                        const short* __restrict__ vbh, const short* __restrict__ vbl,
                                                        short* __restrict__ obh, short* __restrict__ obl,
                                                        float* __restrict__ o_part, float* __restrict__ ml_part) {
    __shared__ short K_hi[64][104], K_lo[64][104];
    __shared__ short Vt_hi[64][72], Vt_lo[64][72];
    __shared__ short P_hi[4][16][72], P_lo[4][16][72];
    const int item = blockIdx.x, h = blockIdx.y;
    int qt, kt0, kt1, part;
    bool full;
    if (item < 8) { qt = item; kt0 = 0; kt1 = qt + 1; full = true; part = 0; }
    else {
        int i = item - 8;
        qt = 8 + (i >> 1);
        part = i & 1;
        int mid = (qt + 1) >> 1;
        full = false;
        kt0 = part ? mid : 0;
        kt1 = part ? (qt + 1) : mid;
    }
    const int tid = threadIdx.x, lane = tid & 63, w = tid >> 6;
    const int g = lane >> 4, li = lane & 15;

    s16x8 q_hi[3], q_lo[3];
    {
        const short* qb_h = qfh + (size_t)(qt * 64 + w * 16 + li) * 1536 + h * QKD;
        const short* qb_l = qfl + (size_t)(qt * 64 + w * 16 + li) * 1536 + h * QKD;
#pragma unroll
        for (int ks = 0; ks < 3; ks++) {
            q_hi[ks] = *(const s16x8*)(qb_h + ks * 32 + g * 8);
            q_lo[ks] = *(const s16x8*)(qb_l + ks * 32 + g * 8);
        }
    }

    f32x4 acc_o[4];
#pragma unroll
    for (int nc = 0; nc < 4; nc++)
#pragma unroll
        for (int r = 0; r < 4; r++) acc_o[nc][r] = 0.f;
    float m4[4] = {-1e30f, -1e30f, -1e30f, -1e30f};
    float l4[4] = {0.f, 0.f, 0.f, 0.f};
    const float scale = 0.102062072616f;

    for (int kt = kt0; kt < kt1; kt++) {
#pragma unroll
        for (int it = 0; it < 3; it++) {
            int cid = it * 256 + tid;
            int key = cid / 12, c = cid % 12;
            *(s16x8*)&K_hi[key][c * 8] = *(const s16x8*)&kfh[(size_t)(kt * 64 + key) * 1536 + h * QKD + c * 8];
            *(s16x8*)&K_lo[key][c * 8] = *(const s16x8*)&kfl[(size_t)(kt * 64 + key) * 1536 + h * QKD + c * 8];
        }
#pragma unroll
        for (int it = 0; it < 2; it++) {
            int cid = it * 256 + tid;
            int key = cid >> 3, vc = cid & 7;
            s16x8 vh = *(const s16x8*)&vbh[(size_t)(kt * 64 + key) * 1024 + h * VD + vc * 8];
            s16x8 vl = *(const s16x8*)&vbl[(size_t)(kt * 64 + key) * 1024 + h * VD + vc * 8];
#pragma unroll
            for (int j = 0; j < 8; j++) {
                Vt_hi[vc * 8 + j][key] = vh[j];
                Vt_lo[vc * 8 + j][key] = vl[j];
            }
        }
        __syncthreads();

        f32x4 acc_s[4];
#pragma unroll
        for (int kc = 0; kc < 4; kc++)
#pragma unroll
            for (int r = 0; r < 4; r++) acc_s[kc][r] = 0.f;
#pragma unroll
        for (int ks = 0; ks < 3; ks++) {
#pragma unroll
            for (int kc = 0; kc < 4; kc++) {
                s16x8 kh = *(const s16x8*)&K_hi[kc * 16 + li][ks * 32 + g * 8];
                s16x8 kl = *(const s16x8*)&K_lo[kc * 16 + li][ks * 32 + g * 8];
                acc_s[kc] = __builtin_amdgcn_mfma_f32_16x16x32_bf16(q_hi[ks], kh, acc_s[kc], 0, 0, 0);
                acc_s[kc] = __builtin_amdgcn_mfma_f32_16x16x32_bf16(q_lo[ks], kh, acc_s[kc], 0, 0, 0);
                acc_s[kc] = __builtin_amdgcn_mfma_f32_16x16x32_bf16(q_hi[ks], kl, acc_s[kc], 0, 0, 0);
            }
        }
#pragma unroll
        for (int kc = 0; kc < 4; kc++)
#pragma unroll
            for (int r = 0; r < 4; r++) acc_s[kc][r] *= scale;
        if (kt == qt) {
#pragma unroll
            for (int kc = 0; kc < 4; kc++) {
                int key = kt * 64 + kc * 16 + li;
#pragma unroll
                for (int r = 0; r < 4; r++) {
                    int qr = qt * 64 + w * 16 + g * 4 + r;
                    if (key > qr) acc_s[kc][r] = -1e30f;
                }
            }
        }
        float tm4[4];
#pragma unroll
        for (int r = 0; r < 4; r++)
            tm4[r] = fmaxf(fmaxf(acc_s[0][r], acc_s[1][r]), fmaxf(acc_s[2][r], acc_s[3][r]));
#pragma unroll
        for (int off = 1; off < 16; off <<= 1)
#pragma unroll
            for (int r = 0; r < 4; r++) tm4[r] = fmaxf(tm4[r], __shfl_xor(tm4[r], off));
        float alpha[4];
#pragma unroll
        for (int r = 0; r < 4; r++) {
            float mn = fmaxf(m4[r], tm4[r]);
            alpha[r] = __expf(m4[r] - mn);
            m4[r] = mn;
        }
        float rs[4] = {0.f, 0.f, 0.f, 0.f};
#pragma unroll
        for (int kc = 0; kc < 4; kc++)
#pragma unroll
            for (int r = 0; r < 4; r++) {
                float p = __expf(acc_s[kc][r] - m4[r]);
                rs[r] += p;
                short hh = f2bf(p);
                P_hi[w][g * 4 + r][kc * 16 + li] = hh;
                P_lo[w][g * 4 + r][kc * 16 + li] = f2bf(p - bf2f(hh));
            }
#pragma unroll
        for (int off = 1; off < 16; off <<= 1)
#pragma unroll
            for (int r = 0; r < 4; r++) rs[r] += __shfl_xor(rs[r], off);
#pragma unroll
        for (int r = 0; r < 4; r++) l4[r] = l4[r] * alpha[r] + rs[r];
#pragma unroll
        for (int nc = 0; nc < 4; nc++)
#pragma unroll
            for (int r = 0; r < 4; r++) acc_o[nc][r] *= alpha[r];
#pragma unroll
        for (int ks = 0; ks < 2; ks++) {
            s16x8 ph = *(const s16x8*)&P_hi[w][li][ks * 32 + g * 8];
            s16x8 pl = *(const s16x8*)&P_lo[w][li][ks * 32 + g * 8];
#pragma unroll
            for (int nc = 0; nc < 4; nc++) {
                s16x8 vh = *(const s16x8*)&Vt_hi[nc * 16 + li][ks * 32 + g * 8];
                s16x8 vl = *(const s16x8*)&Vt_lo[nc * 16 + li][ks * 32 + g * 8];
                acc_o[nc] = __builtin_amdgcn_mfma_f32_16x16x32_bf16(ph, vh, acc_o[nc], 0, 0, 0);
                acc_o[nc] = __builtin_amdgcn_mfma_f32_16x16x32_bf16(pl, vh, acc_o[nc], 0, 0, 0);
                acc_o[nc] = __builtin_amdgcn_mfma_f32_16x16x32_bf16(ph, vl, acc_o[nc], 0, 0, 0);
            }
        }
        __syncthreads();
    }
    if (full) {
        float inv[4];
#pragma unroll
        for (int r = 0; r < 4; r++) inv[r] = 1.f / l4[r];
#pragma unroll
        for (int nc = 0; nc < 4; nc++)
#pragma unroll
            for (int r = 0; r < 4; r++) {
                float o = acc_o[nc][r] * inv[r];
                size_t idx = (size_t)(qt * 64 + w * 16 + g * 4 + r) * 1024 + h * VD + nc * 16 + li;
                short hh = f2bf(o);
                obh[idx] = hh;
                obl[idx] = f2bf(o - bf2f(hh));
            }
    } else {
#pragma unroll
        for (int nc = 0; nc < 4; nc++)
#pragma unroll
            for (int r = 0; r < 4; r++) {
                int t = qt * 64 + w * 16 + g * 4 + r;
                o_part[(((size_t)part * 1024 + t) * 16 + h) * 64 + nc * 16 + li] = acc_o[nc][r];
            }
        if (li == 0) {
#pragma unroll
            for (int r = 0; r < 4; r++) {
                int t = qt * 64 + w * 16 + g * 4 + r;
                size_t o = (((size_t)part * 1024 + t) * 16 + h) * 2;
                ml_part[o] = m4[r];
                ml_part[o + 1] = l4[r];
            }
        }
    }
}

// ---------------- merge two attention partials (rows 512..1023) ----------------
__global__ __launch_bounds__(256) void attn_combine_kernel(const float* __restrict__ o_part,
                                                           const float* __restrict__ ml_part,
                                                           short* __restrict__ obh, short* __restrict__ obl) {
    int t = 512 + blockIdx.x;
    int idx4 = threadIdx.x * 4;
    int h = idx4 >> 6;
    int vd = idx4 & 63;
    size_t mb0 = (((size_t)0 * 1024 + t) * 16 + h) * 2;
    size_t mb1 = (((size_t)1 * 1024 + t) * 16 + h) * 2;
    float m0 = ml_part[mb0], l0 = ml_part[mb0 + 1];
    float m1 = ml_part[mb1], l1 = ml_part[mb1 + 1];
    float ms = fmaxf(m0, m1);
    float a0 = __expf(m0 - ms), a1 = __expf(m1 - ms);
    float inv = 1.f / (l0 * a0 + l1 * a1);
    size_t b0 = (((size_t)0 * 1024 + t) * 16 + h) * 64 + vd;
    size_t b1 = (((size_t)1 * 1024 + t) * 16 + h) * 64 + vd;
#pragma unroll
    for (int j = 0; j < 4; j++) {
        float o = (o_part[b0 + j] * a0 + o_part[b1 + j] * a1) * inv;
        size_t oi = (size_t)t * 1024 + h * VD + vd + j;
        short hh = f2bf(o);
        obh[oi] = hh;
        obl[oi] = f2bf(o - bf2f(hh));
    }
}

// ---------------- fused resid-add + post-rmsnorm + routing ----------------
__global__ __launch_bounds__(256) void fused_post_attn(float* __restrict__ x0, const float* __restrict__ att,
                                                       const float* __restrict__ w, const float* __restrict__ gate_w,
                                                       const float* __restrict__ gate_bias,
                                                       short* __restrict__ h2bf, int* __restrict__ topidx,
                                                       float* __restrict__ topw) {
    int t = blockIdx.x;
    float resid[8];
    float ss = 0.f;
#pragma unroll
    for (int j = 0; j < 8; j++) {
        int i = threadIdx.x + j * 256;
        float v = x0[(size_t)t * HDIM + i] + att[(size_t)t * HDIM + i];
        resid[j] = v;
        x0[(size_t)t * HDIM + i] = v;
        ss += v * v;
    }
    float r = rsqrtf(block_sum(ss) / HDIM + EPSF);
    float acc[8] = {0.f, 0.f, 0.f, 0.f, 0.f, 0.f, 0.f, 0.f};
#pragma unroll
    for (int j = 0; j < 8; j++) {
        int i = threadIdx.x + j * 256;
        float v = resid[j] * r * w[i];
        h2bf[(size_t)t * HDIM + i] = f2bf(v);
        const float* gw = gate_w + (size_t)i * 8;
        float4 g0 = *(const float4*)gw;
        float4 g1 = *(const float4*)(gw + 4);
        acc[0] = fmaf(v, g0.x, acc[0]); acc[1] = fmaf(v, g0.y, acc[1]);
        acc[2] = fmaf(v, g0.z, acc[2]); acc[3] = fmaf(v, g0.w, acc[3]);
        acc[4] = fmaf(v, g1.x, acc[4]); acc[5] = fmaf(v, g1.y, acc[5]);
        acc[6] = fmaf(v, g1.z, acc[6]); acc[7] = fmaf(v, g1.w, acc[7]);
    }
    __shared__ float logits[8];
    for (int e = 0; e < 8; e++) {
        float s = block_sum(acc[e]);
        if (threadIdx.x == 0) logits[e] = s;
    }
    __syncthreads();
    if (threadIdx.x == 0) {
        float sig[8], sc[8];
        for (int e = 0; e < 8; e++) {
            sig[e] = 1.f / (1.f + expf(-logits[e]));
            sc[e] = sig[e] + gate_bias[e];
        }
        int i0 = 0;
        for (int e = 1; e < 8; e++) if (sc[e] > sc[i0]) i0 = e;
        int i1 = -1;
        for (int e = 0; e < 8; e++) if (e != i0 && (i1 < 0 || sc[e] > sc[i1])) i1 = e;
        float w0 = sig[i0], w1 = sig[i1], s = w0 + w1 + 1e-20f;
        topidx[t * 2 + 0] = i0; topidx[t * 2 + 1] = i1;
        topw[t * 2 + 0] = w0 / s; topw[t * 2 + 1] = w1 / s;
    }
}

// ---------------- counting sort + 256-row tile map (+4 shared tiles) ----------------
__global__ void sort_kernel(const int* __restrict__ topidx, int* __restrict__ sorted_t,
                            int* __restrict__ slotpos, int4* __restrict__ tilemap) {
    __shared__ int counts[8], offs[9];
    int wid = threadIdx.x >> 6, lane = threadIdx.x & 63;
    int cnt = 0;
    for (int base = 0; base < 2 * T_; base += 64) {
        int e = topidx[base + lane];
        unsigned long long m = __ballot(e == wid);
        cnt += __popcll(m);
    }
    if (lane == 0) counts[wid] = cnt;
    __syncthreads();
    if (threadIdx.x == 0) {
        offs[0] = 0;
        for (int e = 0; e < 8; e++) offs[e + 1] = offs[e] + counts[e];
    }
    __syncthreads();
    int pos = offs[wid];
    for (int base = 0; base < 2 * T_; base += 64) {
        int sl = base + lane;
        int e = topidx[sl];
        bool match = (e == wid);
        unsigned long long m = __ballot(match);
        if (match) {
            int before = __popcll(m & ((1ull << lane) - 1ull));
            int pp = pos + before;
            sorted_t[pp] = sl >> 1;
            slotpos[sl] = pp;
        }
        pos += __popcll(m);
    }
    __syncthreads();
    if (threadIdx.x == 0) {
        int nt = 0;
        for (int e = 0; e < 8; e++) {
            int c = counts[e], o = offs[e];
            for (int r = 0; r < c; r += 256) {
                tilemap[nt] = make_int4(e, o + r, min(256, c - r), 0);
                nt++;
            }
        }
        for (int r = 0; r < 4; r++) {
            tilemap[nt] = make_int4(8, 2048 + r * 256, 256, 0);
            nt++;
        }
        for (int i = nt; i < MAXTILES; i++) tilemap[i] = make_int4(0, 0, 0, 0);
    }
}

// ---------------- final combine (md bf16) -> f32 out ----------------
__global__ void final_kernel(const float* __restrict__ resid, const short* __restrict__ md,
                             const int* __restrict__ slotpos, const float* __restrict__ topw,
                             float* __restrict__ out) {
    int t = blockIdx.x;
    int p0 = slotpos[t * 2 + 0], p1 = slotpos[t * 2 + 1];
    float w0 = topw[t * 2 + 0] * 2.5f, w1 = topw[t * 2 + 1] * 2.5f;
    const short* mds = md + (size_t)(2048 + t) * HDIM;
    const short* md0 = md + (size_t)p0 * HDIM;
    const short* md1 = md + (size_t)p1 * HDIM;
    for (int c = threadIdx.x; c < HDIM; c += blockDim.x) {
        float v = resid[(size_t)t * HDIM + c] + bf2f(mds[c])
                + w0 * bf2f(md0[c]) + w1 * bf2f(md1[c]);
        out[(size_t)t * HDIM + c] = v;
    }
}

// ---------------- launcher ----------------
extern "C" void kernel_launch(void* const* d_in, const int* in_sizes, int n_in,
                              void* d_out, int out_size, void* d_ws, size_t ws_size,
                              hipStream_t stream) {
    (void)in_sizes; (void)n_in; (void)out_size; (void)ws_size;
    const int*   input_ids = (const int*)d_in[0];
    const int*   positions = (const int*)d_in[1];
    const float* prev      = (const float*)d_in[2];
    const float* embed     = (const float*)d_in[3];
    const float* enorm_w   = (const float*)d_in[4];
    const float* hnorm_w   = (const float*)d_in[5];
    const float* eh_proj_w = (const float*)d_in[6];
    const float* in_ln_w   = (const float*)d_in[7];
    const float* post_ln_w = (const float*)d_in[8];
    const float* q_a_w     = (const float*)d_in[9];
    const float* q_a_ln_w  = (const float*)d_in[10];
    const float* q_b_w     = (const float*)d_in[11];
    const float* kv_a_w    = (const float*)d_in[12];
    const float* kv_a_ln_w = (const float*)d_in[13];
    const float* kv_b_w    = (const float*)d_in[14];
    const float* o_w       = (const float*)d_in[15];
    const float* gate_w    = (const float*)d_in[16];
    const float* gate_bias = (const float*)d_in[17];
    const float* exp_g     = (const float*)d_in[18];
    const float* exp_u     = (const float*)d_in[19];
    const float* exp_d     = (const float*)d_in[20];
    const float* sh_g      = (const float*)d_in[21];
    const float* sh_u      = (const float*)d_in[22];
    const float* sh_d      = (const float*)d_in[23];
    float* out = (float*)d_out;

    float* ws = (float*)d_ws;
    short* catH  = (short*)(ws + OF_CATH);
    short* catL  = (short*)(ws + OF_CATL);
    float* x0    = ws + OF_X0;
    short* mact  = (short*)(ws + OF_MACT);
    short* hH    = (short*)(ws + OF_HH);
    short* hL    = (short*)(ws + OF_HL);
    float* qbuf  = ws + OF_QBUF;
    float* kvbuf = ws + OF_KVBUF;
    short* qaH   = (short*)(ws + OF_QAH);
    short* qaL   = (short*)(ws + OF_QAL);
    short* kvcnH = (short*)(ws + OF_KVCNH);
    short* kvcnL = (short*)(ws + OF_KVCNL);
    short* qfH   = (short*)(ws + OF_QFH);
    short* qfL   = (short*)(ws + OF_QFL);
    short* kfH   = (short*)(ws + OF_KFH);
    short* kfL   = (short*)(ws + OF_KFL);
    short* vbH   = (short*)(ws + OF_VBH);
    short* vbL   = (short*)(ws + OF_VBL);
    short* obH   = (short*)(ws + OF_OBH);
    short* obL   = (short*)(ws + OF_OBL);
    float* att   = ws + OF_ATT;
    short* h2bf  = (short*)(ws + OF_H2BF);
    short* md    = (short*)(ws + OF_MD);
    float* qkraw = ws + OF_QKRAW;
    short* batH  = (short*)(ws + OF_BATH);
    short* batL  = (short*)(ws + OF_BATL);
    float* opart = ws + OF_OPART;
    float* mlpart= ws + OF_MLPART;
    int*   ri       = (int*)(ws + OF_ROUT);
    int*   topidx   = ri;
    int*   sorted_t = ri + 2048;
    int*   slotpos  = ri + 4096;
    int4*  tilemap  = (int4*)(ri + 6144);
    float* topw     = (float*)(ri + 6144 + 4 * MAXTILES);
    short* ehTH  = (short*)(ws + OF_EHTH);
    short* ehTL  = (short*)(ws + OF_EHTL);
    short* qbTH  = (short*)(ws + OF_QBTH);
    short* qbTL  = (short*)(ws + OF_QBTL);
    short* kvbTH = (short*)(ws + OF_KVBTH);
    short* kvbTL = (short*)(ws + OF_KVBTL);
    short* owTH  = (short*)(ws + OF_OWTH);
    short* owTL  = (short*)(ws + OF_OWTL);

    dim3 blk(256);

    // 0. one-launch weight transpose+split (6 jobs)
    TJobs J;
    J.W[0] = eh_proj_w; J.Whi[0] = ehTH; J.Wlo[0] = ehTL; J.K[0] = 4096; J.N[0] = 2048; J.nbx[0] = 64;
    J.W[1] = q_a_w; J.Whi[1] = batH; J.Wlo[1] = batL; J.K[1] = 2048; J.N[1] = 512; J.nbx[1] = 32;
    J.W[2] = kv_a_w; J.Whi[2] = batH + (size_t)512 * 2048; J.Wlo[2] = batL + (size_t)512 * 2048;
    J.K[2] = 2048; J.N[2] = 288; J.nbx[2] = 32;
    J.W[3] = q_b_w; J.Whi[3] = qbTH; J.Wlo[3] = qbTL; J.K[3] = 512; J.N[3] = 1536; J.nbx[3] = 8;
    J.W[4] = kv_b_w; J.Whi[4] = kvbTH; J.Wlo[4] = kvbTL; J.K[4] = 256; J.N[4] = 2048; J.nbx[4] = 4;
    J.W[5] = o_w; J.Whi[5] = owTH; J.Wlo[5] = owTL; J.K[5] = 1024; J.N[5] = 2048; J.nbx[5] = 16;
    int nby[6] = {32, 8, 5, 24, 32, 32};
    J.base[0] = 0;
    for (int i = 0; i < 6; i++) J.base[i + 1] = J.base[i] + J.nbx[i] * nby[i];
    transpose_multi_kernel<<<J.base[6], blk, 0, stream>>>(J);

    // 1. embed + rmsnorm + concat
    embed_cat_kernel<<<T_, blk, 0, stream>>>(input_ids, embed, enorm_w, prev, hnorm_w, catH, catL);
    // 2. x0 = cat @ eh_proj
    gemm_planes<true><<<dim3(32, 8), blk, 0, stream>>>(catH, catL, ehTH, ehTL, x0, T_, 2048, 4096);
    // 3. h = rmsnorm(x0)
    rmsnorm_kernel<<<T_, blk, 0, stream>>>(x0, 2048, 2048, in_ln_w, nullptr, hH, hL, 2048);
    // 4. qkraw = h @ [q_a | kv_a]  (N=800)
    gemm_planes<true><<<dim3(13, 8), blk, 0, stream>>>(hH, hL, batH, batL, qkraw, T_, 800, 2048);
    // 5. fused rmsnorms (q_a_ln + kv_a_ln)
    rmsnorm_qkv_kernel<<<T_, blk, 0, stream>>>(qkraw, q_a_ln_w, kv_a_ln_w, qaH, qaL, kvcnH, kvcnL);
    // 6+7. q = qa @ q_b  ||  kv = kvcn @ kv_b  (one launch, z-jobs)
    gemm_planes_dual<<<dim3(32, 8, 2), blk, 0, stream>>>(
        qaH, qaL, qbTH, qbTL, qbuf, 1536, 512, 24,
        kvcnH, kvcnL, kvbTH, kvbTL, kvbuf, 2048, 256, 32);
    // 8. rope + planes (k_pe from qkraw cols 768-799)
    prep_qkv_kernel<<<T_, blk, 0, stream>>>(qbuf, qkraw, kvbuf, positions, qfH, qfL, kfH, kfL, vbH, vbL);
    // 9. flash attention (balanced items)
    attn_mfma_kernel<<<dim3(NITEMS, NH), blk, 0, stream>>>(qfH, qfL, kfH, kfL, vbH, vbL, obH, obL, opart, mlpart);
    // 9b. merge partials for rows 512..1023
    attn_combine_kernel<<<512, blk, 0, stream>>>(opart, mlpart, obH, obL);
    // 10. attn_out = ob @ o_w
    gemm_planes<true><<<dim3(32, 8), blk, 0, stream>>>(obH, obL, owTH, owTL, att, T_, 2048, 1024);
    // 11. fused resid + rmsnorm + routing
    fused_post_attn<<<T_, blk, 0, stream>>>(x0, att, post_ln_w, gate_w, gate_bias, h2bf, topidx, topw);
    // 12. sort (256-row tiles + 4 shared tiles)
    sort_kernel<<<1, 512, 0, stream>>>(topidx, sorted_t, slotpos, tilemap);
    // 13. MoE gate+up fused with silu -> mact (BM=256, inline gather)
    moe_gateup<<<dim3(16, MAXTILES), dim3(512), 0, stream>>>(h2bf, sorted_t, exp_g, exp_u, sh_g, sh_u, mact, tilemap, 2048, 1024);
    // 14. MoE down (BM=256, bf16 out)
    moe_down<<<dim3(32, MAXTILES), dim3(512), 0, stream>>>(mact, exp_d, sh_d, md, tilemap, 1024, 2048);
    // 15. final combine (md bf16)
    final_kernel<<<T_, blk, 0, stream>>>(x0, md, slotpos, topw, out);
}